// Round 3
// baseline (1740.280 us; speedup 1.0000x reference)
//
#include <hip/hip_runtime.h>

#define D 128
#define NH 4
#define DKH 32

__device__ __forceinline__ float bf2f(unsigned int u) {
    return __uint_as_float((u & 0xffffu) << 16);
}
__device__ __forceinline__ float bf2f_hi(unsigned int u) {
    return __uint_as_float(u & 0xffff0000u);
}
__device__ __forceinline__ unsigned short f2bf(float f) {
    unsigned int x = __float_as_uint(f);
    x += 0x7fffu + ((x >> 16) & 1u);
    return (unsigned short)(x >> 16);
}

// ---------------------------------------------------------------------------
// Fold rel_{k,q,v} into W,b:  W'[i, h*32+f] = sum_d W[i, h*32+d] * rel[h,d,f]
// grid (129, 3): x<128 -> weight row, x==128 -> bias; block 128
// ---------------------------------------------------------------------------
__global__ void prep_weights_kernel(
    const float* __restrict__ Wk, const float* __restrict__ bk,
    const float* __restrict__ Wq, const float* __restrict__ bq,
    const float* __restrict__ Wv, const float* __restrict__ bv,
    const float* __restrict__ rk, const float* __restrict__ rq,
    const float* __restrict__ rv,
    float* __restrict__ Wp, float* __restrict__ bp)
{
    int w = blockIdx.y;
    const float* W   = (w == 0) ? Wk : (w == 1) ? Wq : Wv;
    const float* b   = (w == 0) ? bk : (w == 1) ? bq : bv;
    const float* rel = (w == 0) ? rk : (w == 1) ? rq : rv;
    int j = threadIdx.x;            // output column 0..127
    int h = j >> 5, f = j & 31;
    int i = blockIdx.x;
    float acc = 0.f;
    if (i < D) {
        for (int dd = 0; dd < DKH; dd++)
            acc += W[i * D + h * DKH + dd] * rel[h * 1024 + dd * DKH + f];
        Wp[w * D * D + i * D + j] = acc;
    } else {
        for (int dd = 0; dd < DKH; dd++)
            acc += b[h * DKH + dd] * rel[h * 1024 + dd * DKH + f];
        bp[w * D + j] = acc;
    }
}

// ---------------------------------------------------------------------------
// inv_norm[n] = 1 / max(||h_n||, 1e-12).  1 wave per row.
// ---------------------------------------------------------------------------
__global__ void row_norm_kernel(const float* __restrict__ h,
                                float* __restrict__ inv_norm, int N)
{
    int wave = (blockIdx.x * blockDim.x + threadIdx.x) >> 6;
    int lane = threadIdx.x & 63;
    if (wave >= N) return;
    float2 v = *(const float2*)(h + (size_t)wave * D + lane * 2);
    float s = v.x * v.x + v.y * v.y;
    for (int off = 1; off < 64; off <<= 1) s += __shfl_xor(s, off);
    if (lane == 0)
        inv_norm[wave] = 1.0f / fmaxf(sqrtf(s), 1e-12f);
}

// ---------------------------------------------------------------------------
// kt/qt/vt = h @ W'{k,q,v} + b' (stored bf16).  16 rows per block, 256 thr.
// ---------------------------------------------------------------------------
__global__ __launch_bounds__(256) void gemm_kqv_kernel(
    const float* __restrict__ h,
    const float* __restrict__ Wp, const float* __restrict__ bp,
    unsigned short* __restrict__ kt, unsigned short* __restrict__ qt,
    unsigned short* __restrict__ vt, int N)
{
    __shared__ float hs[16][D];
    int block_row = blockIdx.x * 16;
    int tid = threadIdx.x;
    for (int i = tid; i < 16 * D; i += 256) {
        int r = i >> 7, c = i & 127;
        int n = block_row + r;
        hs[r][c] = (n < N) ? h[(size_t)n * D + c] : 0.f;
    }
    __syncthreads();
    int j = tid & 127;
    int half = tid >> 7;
    const float* Wkp = Wp;
    const float* Wqp = Wp + D * D;
    const float* Wvp = Wp + 2 * D * D;
    float ak[8], aq[8], av[8];
#pragma unroll
    for (int r = 0; r < 8; r++) { ak[r] = 0.f; aq[r] = 0.f; av[r] = 0.f; }
    for (int d = 0; d < D; d++) {
        float wk = Wkp[d * D + j], wq = Wqp[d * D + j], wv = Wvp[d * D + j];
#pragma unroll
        for (int r = 0; r < 8; r++) {
            float hval = hs[half + r * 2][d];
            ak[r] += hval * wk; aq[r] += hval * wq; av[r] += hval * wv;
        }
    }
    float bk = bp[j], bq = bp[D + j], bv = bp[2 * D + j];
#pragma unroll
    for (int r = 0; r < 8; r++) {
        int n = block_row + half + r * 2;
        if (n < N) {
            kt[(size_t)n * D + j] = f2bf(ak[r] + bk);
            qt[(size_t)n * D + j] = f2bf(aq[r] + bq);
            vt[(size_t)n * D + j] = f2bf(av[r] + bv);
        }
    }
}

// ---------------------------------------------------------------------------
__global__ void deg_kernel(const int* __restrict__ src, const int* __restrict__ dst,
                           float* __restrict__ deg, int E)
{
    int e = blockIdx.x * blockDim.x + threadIdx.x;
    if (e >= E) return;
    atomicAdd(&deg[src[e]], 1.f);
    atomicAdd(&deg[dst[e]], 1.f);
}

__global__ void count_zero_kernel(const float* __restrict__ deg,
                                  float* __restrict__ zcount, int N)
{
    int idx = blockIdx.x * blockDim.x + threadIdx.x;
    int stride = gridDim.x * blockDim.x;
    int cnt = 0;
    for (int i = idx; i < N; i += stride) cnt += (deg[i] == 0.f) ? 1 : 0;
    for (int off = 1; off < 64; off <<= 1) cnt += __shfl_xor(cnt, off);
    __shared__ int wsum[4];
    int lane = threadIdx.x & 63, wv = threadIdx.x >> 6;
    if (lane == 0) wsum[wv] = cnt;
    __syncthreads();
    if (threadIdx.x == 0) {
        int t = 0;
        for (int i = 0; i < (int)(blockDim.x >> 6); i++) t += wsum[i];
        if (t) atomicAdd(zcount, (float)t);
    }
}

__global__ void finalize_kernel(const float* __restrict__ zcount,
                                const float* __restrict__ fsb,
                                float* __restrict__ flags, int N)
{
    float z = zcount[0];
    float sparsity = z / (float)N;
    flags[0] = (sparsity > 0.3f) ? fsb[0] : 0.f;   // boost value
    flags[1] = fmaxf((float)N - z, 1.f);           // cnt of non-zero-deg nodes
}

// ---------------------------------------------------------------------------
// Per edge (32 lanes): att[h] = <qt[dst,h,:], kt[src,h,:]>/sqrt(32) (+ boost),
// p = exp(att); atomicAdd into denom[dst,h].  2 edges per wave.
// ---------------------------------------------------------------------------
__global__ __launch_bounds__(256) void edge_att_kernel(
    const unsigned short* __restrict__ kt, const unsigned short* __restrict__ qt,
    const float* __restrict__ h, const float* __restrict__ inv_norm,
    const int* __restrict__ src_idx, const int* __restrict__ dst_idx,
    const float* __restrict__ flags,
    float* __restrict__ pbuf, float* __restrict__ denom, int E)
{
    int wave = (blockIdx.x * blockDim.x + threadIdx.x) >> 6;
    int lane = threadIdx.x & 63;
    int sub = lane >> 5, l = lane & 31;
    int e = wave * 2 + sub;
    if (e >= E) return;
    int s = src_idx[e], d = dst_idx[e];
    uint2 a = *(const uint2*)(kt + (size_t)s * D + l * 4);
    uint2 b = *(const uint2*)(qt + (size_t)d * D + l * 4);
    float part = bf2f(a.x) * bf2f(b.x) + bf2f_hi(a.x) * bf2f_hi(b.x)
               + bf2f(a.y) * bf2f(b.y) + bf2f_hi(a.y) * bf2f_hi(b.y);
    part += __shfl_xor(part, 1);
    part += __shfl_xor(part, 2);
    part += __shfl_xor(part, 4);
    float boost = flags[0];
    float fs = 0.f;
    if (boost != 0.f) {   // wave-uniform branch; off when sparsity <= 0.3
        float4 hu = *(const float4*)(h + (size_t)s * D + l * 4);
        float4 hv = *(const float4*)(h + (size_t)d * D + l * 4);
        float fp = hu.x * hv.x + hu.y * hv.y + hu.z * hv.z + hu.w * hv.w;
        fp += __shfl_xor(fp, 1);  fp += __shfl_xor(fp, 2);  fp += __shfl_xor(fp, 4);
        fp += __shfl_xor(fp, 8);  fp += __shfl_xor(fp, 16);
        fs = fp * inv_norm[s] * inv_norm[d] * boost;
    }
    if ((l & 7) == 0) {
        int hh = l >> 3;
        // exp without max-subtraction: att is O(0.3); clamp keeps any upstream
        // garbage finite so failures stay diagnosable (never inf/NaN).
        float att = part * 0.17677669529663687f + fs;   // 1/sqrt(32)
        att = fminf(fmaxf(att, -60.f), 60.f);
        float p = __expf(att);
        pbuf[(size_t)e * NH + hh] = p;
        atomicAdd(&denom[(size_t)d * NH + hh], p);
    }
}

// ---------------------------------------------------------------------------
// agg[dst] += vt[src] * attn ;  32 lanes per edge, 4 atomics per lane.
// ---------------------------------------------------------------------------
__global__ __launch_bounds__(256) void edge_agg_kernel(
    const unsigned short* __restrict__ vt, const float* __restrict__ pbuf,
    const float* __restrict__ denom,
    const int* __restrict__ src_idx, const int* __restrict__ dst_idx,
    float* __restrict__ agg, int E)
{
    int wave = (blockIdx.x * blockDim.x + threadIdx.x) >> 6;
    int lane = threadIdx.x & 63;
    int sub = lane >> 5, l = lane & 31;
    int e = wave * 2 + sub;
    if (e >= E) return;
    int s = src_idx[e], d = dst_idx[e];
    int hh = l >> 3;
    float attn = pbuf[(size_t)e * NH + hh] / fmaxf(denom[(size_t)d * NH + hh], 1e-38f);
    uint2 vv = *(const uint2*)(vt + (size_t)s * D + l * 4);
    float* o = agg + (size_t)d * D + l * 4;
    atomicAdd(o + 0, bf2f(vv.x) * attn);
    atomicAdd(o + 1, bf2f_hi(vv.x) * attn);
    atomicAdd(o + 2, bf2f(vv.y) * attn);
    atomicAdd(o + 3, bf2f_hi(vv.y) * attn);
}

// ---------------------------------------------------------------------------
// out = LN(agg @ Wa + ba); one wave per row, 2 columns per lane.
// Also accumulates gc partials (256-slot hierarchy) for non-zero-deg rows.
// ---------------------------------------------------------------------------
__global__ __launch_bounds__(64) void out_ln_kernel(
    const float* __restrict__ agg,
    const float* __restrict__ Wa, const float* __restrict__ ba,
    const float* __restrict__ ln_g, const float* __restrict__ ln_b,
    const float* __restrict__ deg, float* __restrict__ out,
    float* __restrict__ gcpart, int N)
{
    int n = blockIdx.x;
    if (n >= N) return;
    __shared__ float arow[D];
    int t = threadIdx.x;
    *(float2*)&arow[t * 2] = *(const float2*)&agg[(size_t)n * D + t * 2];
    __syncthreads();
    float acc0 = 0.f, acc1 = 0.f;
    for (int dd = 0; dd < D; dd++) {
        float2 w2 = *(const float2*)(Wa + dd * D + t * 2);
        float a = arow[dd];
        acc0 += a * w2.x;
        acc1 += a * w2.y;
    }
    acc0 += ba[t * 2];
    acc1 += ba[t * 2 + 1];
    float s = acc0 + acc1;
    for (int off = 1; off < 64; off <<= 1) s += __shfl_xor(s, off);
    float mu = s * (1.f / 128.f);
    float d0 = acc0 - mu, d1 = acc1 - mu;
    float v2 = d0 * d0 + d1 * d1;
    for (int off = 1; off < 64; off <<= 1) v2 += __shfl_xor(v2, off);
    float rstd = rsqrtf(v2 * (1.f / 128.f) + 1e-5f);
    float y0 = d0 * rstd * ln_g[t * 2]     + ln_b[t * 2];
    float y1 = d1 * rstd * ln_g[t * 2 + 1] + ln_b[t * 2 + 1];
    *(float2*)(out + (size_t)n * D + t * 2) = make_float2(y0, y1);
    if (deg[n] != 0.f) {
        atomicAdd(&gcpart[(n & 255) * D + t * 2],     y0);
        atomicAdd(&gcpart[(n & 255) * D + t * 2 + 1], y1);
    }
}

__global__ void gc_final_kernel(const float* __restrict__ gcpart,
                                const float* __restrict__ flags,
                                float* __restrict__ gc)
{
    int j = threadIdx.x;  // 128
    float s = 0.f;
    for (int i = 0; i < 256; i++) s += gcpart[i * D + j];
    gc[j] = s / flags[1];
}

__global__ void fixup_kernel(const float* __restrict__ h,
                             const float* __restrict__ deg,
                             const float* __restrict__ gc,
                             float* __restrict__ out, int N)
{
    int idx = blockIdx.x * blockDim.x + threadIdx.x;
    if (idx >= N * D) return;
    int n = idx >> 7, j = idx & 127;
    if (deg[n] == 0.f)
        out[idx] = 0.9f * h[idx] + 0.1f * gc[j];
}

// ---------------------------------------------------------------------------
extern "C" void kernel_launch(void* const* d_in, const int* in_sizes, int n_in,
                              void* d_out, int out_size, void* d_ws, size_t ws_size,
                              hipStream_t stream)
{
    const float* h       = (const float*)d_in[0];
    const int* src_idx   = (const int*)d_in[1];
    const int* dst_idx   = (const int*)d_in[2];
    const float* Wk      = (const float*)d_in[3];
    const float* bk      = (const float*)d_in[4];
    const float* Wq      = (const float*)d_in[5];
    const float* bq      = (const float*)d_in[6];
    const float* Wv      = (const float*)d_in[7];
    const float* bv      = (const float*)d_in[8];
    const float* rk      = (const float*)d_in[9];
    const float* rq      = (const float*)d_in[10];
    const float* rv      = (const float*)d_in[11];
    const float* Wa      = (const float*)d_in[12];
    const float* ba      = (const float*)d_in[13];
    const float* ln_g    = (const float*)d_in[14];
    const float* ln_b    = (const float*)d_in[15];
    const float* fsb     = (const float*)d_in[16];
    float* out           = (float*)d_out;

    int N = in_sizes[0] / D;
    int E = in_sizes[1];

    // ---- compact workspace (~51 MB): small control buffers FIRST ----------
    char* p = (char*)d_ws;
    auto alloc = [&](size_t bytes) { char* q = p; p += (bytes + 15) & ~(size_t)15; return q; };

    float* Wp       = (float*)alloc(3 * D * D * 4);
    float* bp       = (float*)alloc(3 * D * 4);
    float* gc       = (float*)alloc(D * 4);
    float* flags    = (float*)alloc(2 * 4);
    float* inv_norm = (float*)alloc((size_t)N * 4);
    // zero-region 1: deg, denom, gcpart, zcount (contiguous)
    char* z1 = p;
    float* deg    = (float*)alloc((size_t)N * 4);
    float* denom  = (float*)alloc((size_t)N * NH * 4);
    float* gcpart = (float*)alloc(256 * D * 4);
    float* zcount = (float*)alloc(4);
    size_t z1_bytes = (size_t)(p - z1);
    // big arrays (bf16): agg (fp32, N*D) aliases kt+qt after edge_att
    unsigned short* kt = (unsigned short*)alloc((size_t)N * D * 2);
    unsigned short* qt = (unsigned short*)alloc((size_t)N * D * 2);
    unsigned short* vt = (unsigned short*)alloc((size_t)N * D * 2);
    float* pbuf        = (float*)alloc((size_t)E * NH * 4);
    float* agg = (float*)kt;   // 25.6 MB alias over dead kt+qt

    hipMemsetAsync(z1, 0, z1_bytes, stream);

    prep_weights_kernel<<<dim3(129, 3), 128, 0, stream>>>(Wk, bk, Wq, bq, Wv, bv,
                                                          rk, rq, rv, Wp, bp);
    row_norm_kernel<<<(N + 3) / 4, 256, 0, stream>>>(h, inv_norm, N);
    gemm_kqv_kernel<<<(N + 15) / 16, 256, 0, stream>>>(h, Wp, bp, kt, qt, vt, N);
    deg_kernel<<<(E + 255) / 256, 256, 0, stream>>>(src_idx, dst_idx, deg, E);
    count_zero_kernel<<<196, 256, 0, stream>>>(deg, zcount, N);
    finalize_kernel<<<1, 1, 0, stream>>>(zcount, fsb, flags, N);
    edge_att_kernel<<<(E + 7) / 8, 256, 0, stream>>>(kt, qt, h, inv_norm,
                                                     src_idx, dst_idx, flags,
                                                     pbuf, denom, E);
    // kt/qt now dead; zero the aliased agg region before aggregation
    hipMemsetAsync(agg, 0, (size_t)N * D * 4, stream);
    edge_agg_kernel<<<(E + 7) / 8, 256, 0, stream>>>(vt, pbuf, denom,
                                                     src_idx, dst_idx, agg, E);
    out_ln_kernel<<<N, 64, 0, stream>>>(agg, Wa, ba, ln_g, ln_b, deg, out, gcpart, N);
    gc_final_kernel<<<1, D, 0, stream>>>(gcpart, flags, gc);
    fixup_kernel<<<(N * D + 255) / 256, 256, 0, stream>>>(h, deg, gc, out, N);
}

// Round 4
// 529.310 us; speedup vs baseline: 3.2878x; 3.2878x over previous
//
#include <hip/hip_runtime.h>

#define D 128
#define NH 4
#define DKH 32

__device__ __forceinline__ float bf2f(unsigned int u) {
    return __uint_as_float((u & 0xffffu) << 16);
}
__device__ __forceinline__ float bf2f_hi(unsigned int u) {
    return __uint_as_float(u & 0xffff0000u);
}
__device__ __forceinline__ unsigned short f2bf(float f) {
    unsigned int x = __float_as_uint(f);
    x += 0x7fffu + ((x >> 16) & 1u);
    return (unsigned short)(x >> 16);
}

// ---------------------------------------------------------------------------
// Fold rel_{k,q,v} into W,b:  W'[i, h*32+f] = sum_d W[i, h*32+d] * rel[h,d,f]
// ---------------------------------------------------------------------------
__global__ void prep_weights_kernel(
    const float* __restrict__ Wk, const float* __restrict__ bk,
    const float* __restrict__ Wq, const float* __restrict__ bq,
    const float* __restrict__ Wv, const float* __restrict__ bv,
    const float* __restrict__ rk, const float* __restrict__ rq,
    const float* __restrict__ rv,
    float* __restrict__ Wp, float* __restrict__ bp)
{
    int w = blockIdx.y;
    const float* W   = (w == 0) ? Wk : (w == 1) ? Wq : Wv;
    const float* b   = (w == 0) ? bk : (w == 1) ? bq : bv;
    const float* rel = (w == 0) ? rk : (w == 1) ? rq : rv;
    int j = threadIdx.x;            // output column 0..127
    int h = j >> 5, f = j & 31;
    int i = blockIdx.x;
    float acc = 0.f;
    if (i < D) {
        for (int dd = 0; dd < DKH; dd++)
            acc += W[i * D + h * DKH + dd] * rel[h * 1024 + dd * DKH + f];
        Wp[w * D * D + i * D + j] = acc;
    } else {
        for (int dd = 0; dd < DKH; dd++)
            acc += b[h * DKH + dd] * rel[h * 1024 + dd * DKH + f];
        bp[w * D + j] = acc;
    }
}

// ---------------------------------------------------------------------------
__global__ void row_norm_kernel(const float* __restrict__ h,
                                float* __restrict__ inv_norm, int N)
{
    int wave = (blockIdx.x * blockDim.x + threadIdx.x) >> 6;
    int lane = threadIdx.x & 63;
    if (wave >= N) return;
    float2 v = *(const float2*)(h + (size_t)wave * D + lane * 2);
    float s = v.x * v.x + v.y * v.y;
    for (int off = 1; off < 64; off <<= 1) s += __shfl_xor(s, off);
    if (lane == 0)
        inv_norm[wave] = 1.0f / fmaxf(sqrtf(s), 1e-12f);
}

// ---------------------------------------------------------------------------
// kt/qt/vt = h @ W'{k,q,v} + b' (stored bf16).  16 rows per block, 256 thr.
// ---------------------------------------------------------------------------
__global__ __launch_bounds__(256) void gemm_kqv_kernel(
    const float* __restrict__ h,
    const float* __restrict__ Wp, const float* __restrict__ bp,
    unsigned short* __restrict__ kt, unsigned short* __restrict__ qt,
    unsigned short* __restrict__ vt, int N)
{
    __shared__ float hs[16][D];
    int block_row = blockIdx.x * 16;
    int tid = threadIdx.x;
    for (int i = tid; i < 16 * D; i += 256) {
        int r = i >> 7, c = i & 127;
        int n = block_row + r;
        hs[r][c] = (n < N) ? h[(size_t)n * D + c] : 0.f;
    }
    __syncthreads();
    int j = tid & 127;
    int half = tid >> 7;
    const float* Wkp = Wp;
    const float* Wqp = Wp + D * D;
    const float* Wvp = Wp + 2 * D * D;
    float ak[8], aq[8], av[8];
#pragma unroll
    for (int r = 0; r < 8; r++) { ak[r] = 0.f; aq[r] = 0.f; av[r] = 0.f; }
    for (int d = 0; d < D; d++) {
        float wk = Wkp[d * D + j], wq = Wqp[d * D + j], wv = Wvp[d * D + j];
#pragma unroll
        for (int r = 0; r < 8; r++) {
            float hval = hs[half + r * 2][d];
            ak[r] += hval * wk; aq[r] += hval * wq; av[r] += hval * wv;
        }
    }
    float bk = bp[j], bq = bp[D + j], bv = bp[2 * D + j];
#pragma unroll
    for (int r = 0; r < 8; r++) {
        int n = block_row + half + r * 2;
        if (n < N) {
            kt[(size_t)n * D + j] = f2bf(ak[r] + bk);
            qt[(size_t)n * D + j] = f2bf(aq[r] + bq);
            vt[(size_t)n * D + j] = f2bf(av[r] + bv);
        }
    }
}

// ---------------------------------------------------------------------------
// Degree (src+dst incidence, int) + dst-only histogram for CSR.
// ---------------------------------------------------------------------------
__global__ void deg_hist_kernel(const int* __restrict__ src, const int* __restrict__ dst,
                                int* __restrict__ deg, int* __restrict__ cnt_dst, int E)
{
    int e = blockIdx.x * blockDim.x + threadIdx.x;
    if (e >= E) return;
    int s = src[e], d = dst[e];
    atomicAdd(&deg[s], 1);
    atomicAdd(&deg[d], 1);
    atomicAdd(&cnt_dst[d], 1);
}

// ---------------------------------------------------------------------------
// Exclusive scan of cnt_dst -> rowptr[0..N], one 1024-thread block.
// ---------------------------------------------------------------------------
__global__ __launch_bounds__(1024) void scan_kernel(const int* __restrict__ cnt,
                                                    int* __restrict__ rowptr, int N)
{
    __shared__ int part[1024];
    int tid = threadIdx.x;
    int chunk = (N + 1023) >> 10;
    int start = tid * chunk;
    int end = min(start + chunk, N);
    int s = 0;
    for (int i = start; i < end; i++) s += cnt[i];
    part[tid] = s;
    __syncthreads();
    for (int off = 1; off < 1024; off <<= 1) {
        int v = (tid >= off) ? part[tid - off] : 0;
        __syncthreads();
        part[tid] += v;
        __syncthreads();
    }
    int run = part[tid] - s;   // exclusive prefix of this chunk
    for (int i = start; i < end; i++) { rowptr[i] = run; run += cnt[i]; }
    if (tid == 1023) rowptr[N] = part[1023];
}

// ---------------------------------------------------------------------------
// Scatter src ids into CSR order by dst.
// ---------------------------------------------------------------------------
__global__ void scatter_kernel(const int* __restrict__ src, const int* __restrict__ dst,
                               const int* __restrict__ rowptr, int* __restrict__ cursor,
                               int* __restrict__ esrc, int E)
{
    int e = blockIdx.x * blockDim.x + threadIdx.x;
    if (e >= E) return;
    int d = dst[e];
    int pos = rowptr[d] + atomicAdd(&cursor[d], 1);
    esrc[pos] = src[e];
}

// ---------------------------------------------------------------------------
__global__ void count_zero_kernel(const int* __restrict__ deg,
                                  int* __restrict__ zcount, int N)
{
    int idx = blockIdx.x * blockDim.x + threadIdx.x;
    int stride = gridDim.x * blockDim.x;
    int cnt = 0;
    for (int i = idx; i < N; i += stride) cnt += (deg[i] == 0) ? 1 : 0;
    for (int off = 1; off < 64; off <<= 1) cnt += __shfl_xor(cnt, off);
    __shared__ int wsum[4];
    int lane = threadIdx.x & 63, wv = threadIdx.x >> 6;
    if (lane == 0) wsum[wv] = cnt;
    __syncthreads();
    if (threadIdx.x == 0) {
        int t = 0;
        for (int i = 0; i < (int)(blockDim.x >> 6); i++) t += wsum[i];
        if (t) atomicAdd(zcount, t);
    }
}

__global__ void finalize_kernel(const int* __restrict__ zcount,
                                const float* __restrict__ fsb,
                                float* __restrict__ flags, int N)
{
    float z = (float)zcount[0];
    float sparsity = z / (float)N;
    flags[0] = (sparsity > 0.3f) ? fsb[0] : 0.f;   // boost value
    flags[1] = fmaxf((float)N - z, 1.f);           // cnt of non-zero-deg nodes
}

// ---------------------------------------------------------------------------
// Fused softmax + aggregation, gather-based, ZERO atomics.
// One wave per dst node; lane l holds elements {2l, 2l+1} (head = l>>4).
// agg[n] = (sum_e exp(att_e) * vt[src_e]) / (sum_e exp(att_e))
// ---------------------------------------------------------------------------
__global__ __launch_bounds__(256) void dst_agg_kernel(
    const unsigned short* __restrict__ kt, const unsigned short* __restrict__ qt,
    const unsigned short* __restrict__ vt,
    const float* __restrict__ h, const float* __restrict__ inv_norm,
    const int* __restrict__ rowptr, const int* __restrict__ esrc,
    const float* __restrict__ flags,
    float* __restrict__ agg, int N)
{
    int n = (blockIdx.x * blockDim.x + threadIdx.x) >> 6;
    int lane = threadIdx.x & 63;
    if (n >= N) return;
    int beg = rowptr[n], end = rowptr[n + 1];
    unsigned int q2 = *(const unsigned int*)(qt + (size_t)n * D + lane * 2);
    float q0 = bf2f(q2), q1 = bf2f_hi(q2);
    float boost = flags[0];
    float hn0 = 0.f, hn1 = 0.f, innd = 0.f;
    if (boost != 0.f) {
        float2 hh = *(const float2*)(h + (size_t)n * D + lane * 2);
        hn0 = hh.x; hn1 = hh.y; innd = inv_norm[n];
    }
    float acc0 = 0.f, acc1 = 0.f, den = 0.f;
    for (int i = beg; i < end; i++) {
        int s = esrc[i];
        unsigned int k2 = *(const unsigned int*)(kt + (size_t)s * D + lane * 2);
        unsigned int v2 = *(const unsigned int*)(vt + (size_t)s * D + lane * 2);
        float dot = q0 * bf2f(k2) + q1 * bf2f_hi(k2);
        // reduce within 16-lane head group (covers 32 elements)
        dot += __shfl_xor(dot, 1);
        dot += __shfl_xor(dot, 2);
        dot += __shfl_xor(dot, 4);
        dot += __shfl_xor(dot, 8);
        float att = dot * 0.17677669529663687f;   // 1/sqrt(32)
        if (boost != 0.f) {   // wave-uniform
            float2 hs2 = *(const float2*)(h + (size_t)s * D + lane * 2);
            float fp = hn0 * hs2.x + hn1 * hs2.y;
            fp += __shfl_xor(fp, 1);  fp += __shfl_xor(fp, 2);
            fp += __shfl_xor(fp, 4);  fp += __shfl_xor(fp, 8);
            fp += __shfl_xor(fp, 16); fp += __shfl_xor(fp, 32);
            att += fp * inv_norm[s] * innd * boost;
        }
        att = fminf(fmaxf(att, -60.f), 60.f);
        float p = __expf(att);
        den += p;
        acc0 += p * bf2f(v2);
        acc1 += p * bf2f_hi(v2);
    }
    float r = 1.0f / fmaxf(den, 1e-38f);
    *(float2*)(agg + (size_t)n * D + lane * 2) = make_float2(acc0 * r, acc1 * r);
}

// ---------------------------------------------------------------------------
// out = LN(agg @ Wa + ba), 16 rows per 256-thread block (Wa reuse x16).
// gc partials accumulated per-wave in registers, one atomicAdd set per wave.
// ---------------------------------------------------------------------------
__global__ __launch_bounds__(256) void out_ln_kernel(
    const float* __restrict__ agg,
    const float* __restrict__ Wa, const float* __restrict__ ba,
    const float* __restrict__ ln_g, const float* __restrict__ ln_b,
    const int* __restrict__ deg, float* __restrict__ out,
    float* __restrict__ gcpart, int N)
{
    __shared__ float as[16][D];
    __shared__ float os[16][D + 2];
    int row0 = blockIdx.x * 16;
    int tid = threadIdx.x;
    for (int i = tid; i < 16 * D; i += 256) {
        int r = i >> 7, c = i & 127;
        int n = row0 + r;
        as[r][c] = (n < N) ? agg[(size_t)n * D + c] : 0.f;
    }
    __syncthreads();
    int j = tid & 127;
    int half = tid >> 7;
    float acc[8];
#pragma unroll
    for (int r = 0; r < 8; r++) acc[r] = 0.f;
    for (int d = 0; d < D; d++) {
        float w = Wa[d * D + j];
#pragma unroll
        for (int r = 0; r < 8; r++) acc[r] += as[half + r * 2][d] * w;
    }
    float bj = ba[j];
#pragma unroll
    for (int r = 0; r < 8; r++) os[half + r * 2][j] = acc[r] + bj;
    __syncthreads();
    // LN phase: 4 waves x 4 rows each; lane covers columns {2l, 2l+1}
    int wv = tid >> 6, lane = tid & 63;
    float g0 = ln_g[lane * 2], g1 = ln_g[lane * 2 + 1];
    float b0 = ln_b[lane * 2], b1 = ln_b[lane * 2 + 1];
    float gcs0 = 0.f, gcs1 = 0.f;
    for (int rr = 0; rr < 4; rr++) {
        int r = wv * 4 + rr;
        int n = row0 + r;
        if (n >= N) break;
        float x0 = os[r][lane * 2], x1 = os[r][lane * 2 + 1];
        float s = x0 + x1, s2 = x0 * x0 + x1 * x1;
        for (int off = 1; off < 64; off <<= 1) {
            s  += __shfl_xor(s, off);
            s2 += __shfl_xor(s2, off);
        }
        float mu = s * (1.f / 128.f);
        float var = s2 * (1.f / 128.f) - mu * mu;
        float rstd = rsqrtf(fmaxf(var, 0.f) + 1e-5f);
        float y0 = (x0 - mu) * rstd * g0 + b0;
        float y1 = (x1 - mu) * rstd * g1 + b1;
        *(float2*)(out + (size_t)n * D + lane * 2) = make_float2(y0, y1);
        if (deg[n] != 0) { gcs0 += y0; gcs1 += y1; }
    }
    int slot = blockIdx.x & 63;
    if (gcs0 != 0.f || gcs1 != 0.f) {
        atomicAdd(&gcpart[slot * D + lane * 2],     gcs0);
        atomicAdd(&gcpart[slot * D + lane * 2 + 1], gcs1);
    }
}

__global__ void gc_final_kernel(const float* __restrict__ gcpart,
                                const float* __restrict__ flags,
                                float* __restrict__ gc)
{
    int j = threadIdx.x;  // 128
    float s = 0.f;
    for (int i = 0; i < 64; i++) s += gcpart[i * D + j];
    gc[j] = s / flags[1];
}

__global__ void fixup_kernel(const float* __restrict__ h,
                             const int* __restrict__ deg,
                             const float* __restrict__ gc,
                             float* __restrict__ out, int N)
{
    int idx = blockIdx.x * blockDim.x + threadIdx.x;
    if (idx >= N * D) return;
    int n = idx >> 7, j = idx & 127;
    if (deg[n] == 0)
        out[idx] = 0.9f * h[idx] + 0.1f * gc[j];
}

// ---------------------------------------------------------------------------
extern "C" void kernel_launch(void* const* d_in, const int* in_sizes, int n_in,
                              void* d_out, int out_size, void* d_ws, size_t ws_size,
                              hipStream_t stream)
{
    const float* h       = (const float*)d_in[0];
    const int* src_idx   = (const int*)d_in[1];
    const int* dst_idx   = (const int*)d_in[2];
    const float* Wk      = (const float*)d_in[3];
    const float* bk      = (const float*)d_in[4];
    const float* Wq      = (const float*)d_in[5];
    const float* bq      = (const float*)d_in[6];
    const float* Wv      = (const float*)d_in[7];
    const float* bv      = (const float*)d_in[8];
    const float* rk      = (const float*)d_in[9];
    const float* rq      = (const float*)d_in[10];
    const float* rv      = (const float*)d_in[11];
    const float* Wa      = (const float*)d_in[12];
    const float* ba      = (const float*)d_in[13];
    const float* ln_g    = (const float*)d_in[14];
    const float* ln_b    = (const float*)d_in[15];
    const float* fsb     = (const float*)d_in[16];
    float* out           = (float*)d_out;

    int N = in_sizes[0] / D;
    int E = in_sizes[1];

    // ---- workspace (~68 MB) ----------------------------------------------
    char* p = (char*)d_ws;
    auto alloc = [&](size_t bytes) { char* q = p; p += (bytes + 15) & ~(size_t)15; return q; };

    float* Wp       = (float*)alloc(3 * D * D * 4);
    float* bp       = (float*)alloc(3 * D * 4);
    float* gc       = (float*)alloc(D * 4);
    float* flags    = (float*)alloc(2 * 4);
    float* inv_norm = (float*)alloc((size_t)N * 4);
    int*   rowptr   = (int*)alloc(((size_t)N + 1) * 4);
    // zero region: deg, cnt_dst, cursor, zcount, gcpart (contiguous)
    char* z1 = p;
    int*   deg     = (int*)alloc((size_t)N * 4);
    int*   cnt_dst = (int*)alloc((size_t)N * 4);
    int*   cursor  = (int*)alloc((size_t)N * 4);
    int*   zcount  = (int*)alloc(4);
    float* gcpart  = (float*)alloc(64 * D * 4);
    size_t z1_bytes = (size_t)(p - z1);
    // big arrays
    unsigned short* kt = (unsigned short*)alloc((size_t)N * D * 2);
    unsigned short* qt = (unsigned short*)alloc((size_t)N * D * 2);
    unsigned short* vt = (unsigned short*)alloc((size_t)N * D * 2);
    int*   esrc        = (int*)alloc((size_t)E * 4);
    float* agg         = (float*)alloc((size_t)N * D * 4);

    hipMemsetAsync(z1, 0, z1_bytes, stream);

    prep_weights_kernel<<<dim3(129, 3), 128, 0, stream>>>(Wk, bk, Wq, bq, Wv, bv,
                                                          rk, rq, rv, Wp, bp);
    row_norm_kernel<<<(N + 3) / 4, 256, 0, stream>>>(h, inv_norm, N);
    gemm_kqv_kernel<<<(N + 15) / 16, 256, 0, stream>>>(h, Wp, bp, kt, qt, vt, N);
    deg_hist_kernel<<<(E + 255) / 256, 256, 0, stream>>>(src_idx, dst_idx, deg, cnt_dst, E);
    scan_kernel<<<1, 1024, 0, stream>>>(cnt_dst, rowptr, N);
    scatter_kernel<<<(E + 255) / 256, 256, 0, stream>>>(src_idx, dst_idx, rowptr,
                                                        cursor, esrc, E);
    count_zero_kernel<<<196, 256, 0, stream>>>(deg, zcount, N);
    finalize_kernel<<<1, 1, 0, stream>>>(zcount, fsb, flags, N);
    dst_agg_kernel<<<(N + 3) / 4, 256, 0, stream>>>(kt, qt, vt, h, inv_norm,
                                                    rowptr, esrc, flags, agg, N);
    out_ln_kernel<<<(N + 15) / 16, 256, 0, stream>>>(agg, Wa, ba, ln_g, ln_b,
                                                     deg, out, gcpart, N);
    gc_final_kernel<<<1, D, 0, stream>>>(gcpart, flags, gc);
    fixup_kernel<<<(N * D + 255) / 256, 256, 0, stream>>>(h, deg, gc, out, N);
}

// Round 5
// 522.893 us; speedup vs baseline: 3.3282x; 1.0123x over previous
//
#include <hip/hip_runtime.h>

#define D 128
#define NH 4
#define DKH 32

__device__ __forceinline__ float bf2f(unsigned int u) {
    return __uint_as_float((u & 0xffffu) << 16);
}
__device__ __forceinline__ float bf2f_hi(unsigned int u) {
    return __uint_as_float(u & 0xffff0000u);
}
__device__ __forceinline__ unsigned short f2bf(float f) {
    unsigned int x = __float_as_uint(f);
    x += 0x7fffu + ((x >> 16) & 1u);
    return (unsigned short)(x >> 16);
}

// ---------------------------------------------------------------------------
// Fold rel_{k,q,v} into W,b:  W'[i, h*32+f] = sum_d W[i, h*32+d] * rel[h,d,f]
// ---------------------------------------------------------------------------
__global__ void prep_weights_kernel(
    const float* __restrict__ Wk, const float* __restrict__ bk,
    const float* __restrict__ Wq, const float* __restrict__ bq,
    const float* __restrict__ Wv, const float* __restrict__ bv,
    const float* __restrict__ rk, const float* __restrict__ rq,
    const float* __restrict__ rv,
    float* __restrict__ Wp, float* __restrict__ bp)
{
    int w = blockIdx.y;
    const float* W   = (w == 0) ? Wk : (w == 1) ? Wq : Wv;
    const float* b   = (w == 0) ? bk : (w == 1) ? bq : bv;
    const float* rel = (w == 0) ? rk : (w == 1) ? rq : rv;
    int j = threadIdx.x;            // output column 0..127
    int h = j >> 5, f = j & 31;
    int i = blockIdx.x;
    float acc = 0.f;
    if (i < D) {
        for (int dd = 0; dd < DKH; dd++)
            acc += W[i * D + h * DKH + dd] * rel[h * 1024 + dd * DKH + f];
        Wp[w * D * D + i * D + j] = acc;
    } else {
        for (int dd = 0; dd < DKH; dd++)
            acc += b[h * DKH + dd] * rel[h * 1024 + dd * DKH + f];
        bp[w * D + j] = acc;
    }
}

// ---------------------------------------------------------------------------
// Fused: inv_norm + (qt bf16, kv packed bf16x2) = h @ W'{k,q,v} + b'.
// 16 rows/block, 256 threads: thread owns 2 cols x 4 rows x 3 mats.
// kv word j of node n: low16 = kt[j], high16 = vt[j]  (512 B per node row).
// ---------------------------------------------------------------------------
__global__ __launch_bounds__(256) void gemm_kqv_kernel(
    const float* __restrict__ h,
    const float* __restrict__ Wp, const float* __restrict__ bp,
    unsigned short* __restrict__ qt, unsigned int* __restrict__ kv,
    float* __restrict__ inv_norm, int N)
{
    __shared__ float hs[16][D];
    int row0 = blockIdx.x * 16;
    int tid = threadIdx.x;
    for (int i = tid; i < 16 * D; i += 256) {
        int r = i >> 7, c = i & 127;
        int n = row0 + r;
        hs[r][c] = (n < N) ? h[(size_t)n * D + c] : 0.f;
    }
    __syncthreads();
    int lane = tid & 63, wv = tid >> 6;
    // row norms: wave wv covers rows wv*4..wv*4+3
    for (int rr = 0; rr < 4; rr++) {
        int r = wv * 4 + rr, n = row0 + r;
        float x0 = hs[r][lane * 2], x1 = hs[r][lane * 2 + 1];
        float s = x0 * x0 + x1 * x1;
        for (int off = 1; off < 64; off <<= 1) s += __shfl_xor(s, off);
        if (lane == 0 && n < N)
            inv_norm[n] = 1.0f / fmaxf(sqrtf(s), 1e-12f);
    }
    int j2 = lane * 2, rg = wv;
    const float* Wkp = Wp;
    const float* Wqp = Wp + D * D;
    const float* Wvp = Wp + 2 * D * D;
    float ak[4][2], aq[4][2], av[4][2];
#pragma unroll
    for (int r = 0; r < 4; r++) {
        ak[r][0] = ak[r][1] = 0.f;
        aq[r][0] = aq[r][1] = 0.f;
        av[r][0] = av[r][1] = 0.f;
    }
    for (int d = 0; d < D; d++) {
        float2 wk = *(const float2*)(Wkp + d * D + j2);
        float2 wq = *(const float2*)(Wqp + d * D + j2);
        float2 wvv = *(const float2*)(Wvp + d * D + j2);
#pragma unroll
        for (int r = 0; r < 4; r++) {
            float a = hs[rg * 4 + r][d];
            ak[r][0] += a * wk.x;  ak[r][1] += a * wk.y;
            aq[r][0] += a * wq.x;  aq[r][1] += a * wq.y;
            av[r][0] += a * wvv.x; av[r][1] += a * wvv.y;
        }
    }
    float2 bk = *(const float2*)(bp + j2);
    float2 bq = *(const float2*)(bp + D + j2);
    float2 bv = *(const float2*)(bp + 2 * D + j2);
#pragma unroll
    for (int r = 0; r < 4; r++) {
        int n = row0 + rg * 4 + r;
        if (n < N) {
            unsigned int qw = (unsigned int)f2bf(aq[r][0] + bq.x)
                            | ((unsigned int)f2bf(aq[r][1] + bq.y) << 16);
            *(unsigned int*)(qt + (size_t)n * D + j2) = qw;
            uint2 kw;
            kw.x = (unsigned int)f2bf(ak[r][0] + bk.x)
                 | ((unsigned int)f2bf(av[r][0] + bv.x) << 16);
            kw.y = (unsigned int)f2bf(ak[r][1] + bk.y)
                 | ((unsigned int)f2bf(av[r][1] + bv.y) << 16);
            *(uint2*)(kv + (size_t)n * D + j2) = kw;
        }
    }
}

// ---------------------------------------------------------------------------
// Histograms: cnt_src (src incidence), cnt_dst (dst incidence / CSR sizes).
// ---------------------------------------------------------------------------
__global__ void deg_hist_kernel(const int* __restrict__ src, const int* __restrict__ dst,
                                int* __restrict__ cnt_src, int* __restrict__ cnt_dst, int E)
{
    int e = blockIdx.x * blockDim.x + threadIdx.x;
    if (e >= E) return;
    atomicAdd(&cnt_src[src[e]], 1);
    atomicAdd(&cnt_dst[dst[e]], 1);
}

// ---------------------------------------------------------------------------
// Coalesced single-block scan: rowptr = exclusive_scan(cnt_dst); also emits
// deg[i] = cnt_src[i]+cnt_dst[i], zero-degree count -> flags.
// ---------------------------------------------------------------------------
__global__ __launch_bounds__(1024) void scan_kernel(
    const int* __restrict__ cnt_src, const int* __restrict__ cnt_dst,
    int* __restrict__ rowptr, int* __restrict__ deg,
    const float* __restrict__ fsb, float* __restrict__ flags, int N)
{
    __shared__ int wtot[16];
    __shared__ int wscan[16];
    int tid = threadIdx.x, lane = tid & 63, wv = tid >> 6;
    int running = 0, zc = 0;
    for (int base = 0; base < N; base += 1024) {
        int i = base + tid;
        int cs = 0, cd = 0;
        if (i < N) { cs = cnt_src[i]; cd = cnt_dst[i]; }
        int x = cd;
        for (int off = 1; off < 64; off <<= 1) {
            int y = __shfl_up(x, off);
            if (lane >= off) x += y;
        }
        if (lane == 63) wtot[wv] = x;
        __syncthreads();
        if (wv == 0) {
            int t = (lane < 16) ? wtot[lane] : 0;
            for (int off = 1; off < 16; off <<= 1) {
                int y = __shfl_up(t, off);
                if (lane >= off) t += y;
            }
            if (lane < 16) wscan[lane] = t;
        }
        __syncthreads();
        int woff = (wv == 0) ? 0 : wscan[wv - 1];
        if (i < N) {
            rowptr[i] = running + woff + x - cd;
            int ds = cs + cd;
            deg[i] = ds;
            zc += (ds == 0) ? 1 : 0;
        }
        running += wscan[15];
        __syncthreads();   // protect wtot/wscan for next iteration
    }
    if (tid == 0) rowptr[N] = running;
    for (int off = 1; off < 64; off <<= 1) zc += __shfl_xor(zc, off);
    if (lane == 0) wtot[wv] = zc;
    __syncthreads();
    if (tid == 0) {
        int z = 0;
        for (int k = 0; k < 16; k++) z += wtot[k];
        float sparsity = (float)z / (float)N;
        flags[0] = (sparsity > 0.3f) ? fsb[0] : 0.f;   // boost value
        flags[1] = fmaxf((float)(N - z), 1.f);         // non-zero-deg node count
    }
}

// ---------------------------------------------------------------------------
// Scatter src ids into CSR order by dst.
// ---------------------------------------------------------------------------
__global__ void scatter_kernel(const int* __restrict__ src, const int* __restrict__ dst,
                               const int* __restrict__ rowptr, int* __restrict__ cursor,
                               int* __restrict__ esrc, int E)
{
    int e = blockIdx.x * blockDim.x + threadIdx.x;
    if (e >= E) return;
    int d = dst[e];
    int pos = rowptr[d] + atomicAdd(&cursor[d], 1);
    esrc[pos] = src[e];
}

// ---------------------------------------------------------------------------
// Fused softmax + aggregation, gather-based, ZERO atomics, unroll-2.
// One wave per dst node; lane l holds elements {2l, 2l+1} (head = l>>4).
// One dwordx2 gather per lane per edge fetches both k and v (packed).
// ---------------------------------------------------------------------------
__global__ __launch_bounds__(256) void dst_agg_kernel(
    const unsigned int* __restrict__ kv, const unsigned short* __restrict__ qt,
    const float* __restrict__ h, const float* __restrict__ inv_norm,
    const int* __restrict__ rowptr, const int* __restrict__ esrc,
    const float* __restrict__ flags,
    float* __restrict__ agg, int N)
{
    int n = (blockIdx.x * blockDim.x + threadIdx.x) >> 6;
    int lane = threadIdx.x & 63;
    if (n >= N) return;
    int beg = rowptr[n], end = rowptr[n + 1];
    unsigned int q2 = *(const unsigned int*)(qt + (size_t)n * D + lane * 2);
    float q0 = bf2f(q2), q1 = bf2f_hi(q2);
    float boost = flags[0];
    float hn0 = 0.f, hn1 = 0.f, innd = 0.f;
    if (boost != 0.f) {
        float2 hh = *(const float2*)(h + (size_t)n * D + lane * 2);
        hn0 = hh.x; hn1 = hh.y; innd = inv_norm[n];
    }
    const float SC = 0.17677669529663687f;   // 1/sqrt(32)
    float acc0 = 0.f, acc1 = 0.f, den = 0.f;
    int i = beg;
    for (; i + 1 < end; i += 2) {
        int s0 = esrc[i], s1 = esrc[i + 1];
        uint2 w0 = *(const uint2*)(kv + (size_t)s0 * D + lane * 2);
        uint2 w1 = *(const uint2*)(kv + (size_t)s1 * D + lane * 2);
        float dot0 = q0 * bf2f(w0.x) + q1 * bf2f(w0.y);
        float dot1 = q0 * bf2f(w1.x) + q1 * bf2f(w1.y);
        dot0 += __shfl_xor(dot0, 1);  dot1 += __shfl_xor(dot1, 1);
        dot0 += __shfl_xor(dot0, 2);  dot1 += __shfl_xor(dot1, 2);
        dot0 += __shfl_xor(dot0, 4);  dot1 += __shfl_xor(dot1, 4);
        dot0 += __shfl_xor(dot0, 8);  dot1 += __shfl_xor(dot1, 8);
        float att0 = dot0 * SC, att1 = dot1 * SC;
        if (boost != 0.f) {   // wave-uniform, off when sparsity <= 0.3
            float2 a0 = *(const float2*)(h + (size_t)s0 * D + lane * 2);
            float2 a1 = *(const float2*)(h + (size_t)s1 * D + lane * 2);
            float f0 = hn0 * a0.x + hn1 * a0.y;
            float f1 = hn0 * a1.x + hn1 * a1.y;
            for (int off = 1; off < 64; off <<= 1) {
                f0 += __shfl_xor(f0, off);
                f1 += __shfl_xor(f1, off);
            }
            att0 += f0 * inv_norm[s0] * innd * boost;
            att1 += f1 * inv_norm[s1] * innd * boost;
        }
        att0 = fminf(fmaxf(att0, -60.f), 60.f);
        att1 = fminf(fmaxf(att1, -60.f), 60.f);
        float p0 = __expf(att0), p1 = __expf(att1);
        den  += p0 + p1;
        acc0 += p0 * bf2f_hi(w0.x) + p1 * bf2f_hi(w1.x);
        acc1 += p0 * bf2f_hi(w0.y) + p1 * bf2f_hi(w1.y);
    }
    if (i < end) {
        int s0 = esrc[i];
        uint2 w0 = *(const uint2*)(kv + (size_t)s0 * D + lane * 2);
        float dot0 = q0 * bf2f(w0.x) + q1 * bf2f(w0.y);
        dot0 += __shfl_xor(dot0, 1);
        dot0 += __shfl_xor(dot0, 2);
        dot0 += __shfl_xor(dot0, 4);
        dot0 += __shfl_xor(dot0, 8);
        float att0 = dot0 * SC;
        if (boost != 0.f) {
            float2 a0 = *(const float2*)(h + (size_t)s0 * D + lane * 2);
            float f0 = hn0 * a0.x + hn1 * a0.y;
            for (int off = 1; off < 64; off <<= 1) f0 += __shfl_xor(f0, off);
            att0 += f0 * inv_norm[s0] * innd * boost;
        }
        att0 = fminf(fmaxf(att0, -60.f), 60.f);
        float p0 = __expf(att0);
        den  += p0;
        acc0 += p0 * bf2f_hi(w0.x);
        acc1 += p0 * bf2f_hi(w0.y);
    }
    float r = 1.0f / fmaxf(den, 1e-38f);
    *(float2*)(agg + (size_t)n * D + lane * 2) = make_float2(acc0 * r, acc1 * r);
}

// ---------------------------------------------------------------------------
// out = LN(agg @ Wa + ba), 16 rows per 256-thread block; thread owns
// 2 cols x 4 rows.  gc partials: per-wave registers -> one atomic set/wave.
// ---------------------------------------------------------------------------
__global__ __launch_bounds__(256) void out_ln_kernel(
    const float* __restrict__ agg,
    const float* __restrict__ Wa, const float* __restrict__ ba,
    const float* __restrict__ ln_g, const float* __restrict__ ln_b,
    const int* __restrict__ deg, float* __restrict__ out,
    float* __restrict__ gcpart, int N)
{
    __shared__ float as[16][D];
    __shared__ float os[16][D + 2];
    int row0 = blockIdx.x * 16;
    int tid = threadIdx.x;
    for (int i = tid; i < 16 * D; i += 256) {
        int r = i >> 7, c = i & 127;
        int n = row0 + r;
        as[r][c] = (n < N) ? agg[(size_t)n * D + c] : 0.f;
    }
    __syncthreads();
    int lane = tid & 63, wv = tid >> 6;
    int j2 = lane * 2;
    float acc[4][2];
#pragma unroll
    for (int r = 0; r < 4; r++) { acc[r][0] = 0.f; acc[r][1] = 0.f; }
    for (int d = 0; d < D; d++) {
        float2 w = *(const float2*)(Wa + d * D + j2);
#pragma unroll
        for (int r = 0; r < 4; r++) {
            float a = as[wv * 4 + r][d];
            acc[r][0] += a * w.x;
            acc[r][1] += a * w.y;
        }
    }
    float2 bb = *(const float2*)(ba + j2);
#pragma unroll
    for (int r = 0; r < 4; r++) {
        os[wv * 4 + r][j2]     = acc[r][0] + bb.x;
        os[wv * 4 + r][j2 + 1] = acc[r][1] + bb.y;
    }
    __syncthreads();
    float g0 = ln_g[j2], g1 = ln_g[j2 + 1];
    float b0 = ln_b[j2], b1 = ln_b[j2 + 1];
    float gcs0 = 0.f, gcs1 = 0.f;
    for (int rr = 0; rr < 4; rr++) {
        int r = wv * 4 + rr;
        int n = row0 + r;
        if (n >= N) break;
        float x0 = os[r][j2], x1 = os[r][j2 + 1];
        float s = x0 + x1, s2 = x0 * x0 + x1 * x1;
        for (int off = 1; off < 64; off <<= 1) {
            s  += __shfl_xor(s, off);
            s2 += __shfl_xor(s2, off);
        }
        float mu = s * (1.f / 128.f);
        float var = s2 * (1.f / 128.f) - mu * mu;
        float rstd = rsqrtf(fmaxf(var, 0.f) + 1e-5f);
        float y0 = (x0 - mu) * rstd * g0 + b0;
        float y1 = (x1 - mu) * rstd * g1 + b1;
        *(float2*)(out + (size_t)n * D + j2) = make_float2(y0, y1);
        if (deg[n] != 0) { gcs0 += y0; gcs1 += y1; }
    }
    int slot = blockIdx.x & 63;
    if (gcs0 != 0.f || gcs1 != 0.f) {
        atomicAdd(&gcpart[slot * D + j2],     gcs0);
        atomicAdd(&gcpart[slot * D + j2 + 1], gcs1);
    }
}

__global__ void gc_final_kernel(const float* __restrict__ gcpart,
                                const float* __restrict__ flags,
                                float* __restrict__ gc)
{
    int j = threadIdx.x;  // 128
    float s = 0.f;
    for (int i = 0; i < 64; i++) s += gcpart[i * D + j];
    gc[j] = s / flags[1];
}

__global__ void fixup_kernel(const float* __restrict__ h,
                             const int* __restrict__ deg,
                             const float* __restrict__ gc,
                             float* __restrict__ out, int N)
{
    int idx = blockIdx.x * blockDim.x + threadIdx.x;
    if (idx >= N * D) return;
    int n = idx >> 7, j = idx & 127;
    if (deg[n] == 0)
        out[idx] = 0.9f * h[idx] + 0.1f * gc[j];
}

// ---------------------------------------------------------------------------
extern "C" void kernel_launch(void* const* d_in, const int* in_sizes, int n_in,
                              void* d_out, int out_size, void* d_ws, size_t ws_size,
                              hipStream_t stream)
{
    const float* h       = (const float*)d_in[0];
    const int* src_idx   = (const int*)d_in[1];
    const int* dst_idx   = (const int*)d_in[2];
    const float* Wk      = (const float*)d_in[3];
    const float* bk      = (const float*)d_in[4];
    const float* Wq      = (const float*)d_in[5];
    const float* bq      = (const float*)d_in[6];
    const float* Wv      = (const float*)d_in[7];
    const float* bv      = (const float*)d_in[8];
    const float* rk      = (const float*)d_in[9];
    const float* rq      = (const float*)d_in[10];
    const float* rv      = (const float*)d_in[11];
    const float* Wa      = (const float*)d_in[12];
    const float* ba      = (const float*)d_in[13];
    const float* ln_g    = (const float*)d_in[14];
    const float* ln_b    = (const float*)d_in[15];
    const float* fsb     = (const float*)d_in[16];
    float* out           = (float*)d_out;

    int N = in_sizes[0] / D;
    int E = in_sizes[1];

    // ---- workspace (~68 MB): small control buffers first ------------------
    char* p = (char*)d_ws;
    auto alloc = [&](size_t bytes) { char* q = p; p += (bytes + 15) & ~(size_t)15; return q; };

    float* Wp       = (float*)alloc(3 * D * D * 4);
    float* bp       = (float*)alloc(3 * D * 4);
    float* gc       = (float*)alloc(D * 4);
    float* flags    = (float*)alloc(2 * 4);
    float* inv_norm = (float*)alloc((size_t)N * 4);
    int*   rowptr   = (int*)alloc(((size_t)N + 1) * 4);
    int*   deg      = (int*)alloc((size_t)N * 4);       // written by scan (no memset)
    // zero region: cnt_src, cnt_dst, cursor, gcpart (contiguous)
    char* z1 = p;
    int*   cnt_src = (int*)alloc((size_t)N * 4);
    int*   cnt_dst = (int*)alloc((size_t)N * 4);
    int*   cursor  = (int*)alloc((size_t)N * 4);
    float* gcpart  = (float*)alloc(64 * D * 4);
    size_t z1_bytes = (size_t)(p - z1);
    // big arrays
    unsigned short* qt = (unsigned short*)alloc((size_t)N * D * 2);
    unsigned int*   kv = (unsigned int*)alloc((size_t)N * D * 4);   // packed k|v
    int*   esrc        = (int*)alloc((size_t)E * 4);
    float* agg         = (float*)alloc((size_t)N * D * 4);

    hipMemsetAsync(z1, 0, z1_bytes, stream);

    prep_weights_kernel<<<dim3(129, 3), 128, 0, stream>>>(Wk, bk, Wq, bq, Wv, bv,
                                                          rk, rq, rv, Wp, bp);
    gemm_kqv_kernel<<<(N + 15) / 16, 256, 0, stream>>>(h, Wp, bp, qt, kv, inv_norm, N);
    deg_hist_kernel<<<(E + 255) / 256, 256, 0, stream>>>(src_idx, dst_idx,
                                                         cnt_src, cnt_dst, E);
    scan_kernel<<<1, 1024, 0, stream>>>(cnt_src, cnt_dst, rowptr, deg, fsb, flags, N);
    scatter_kernel<<<(E + 255) / 256, 256, 0, stream>>>(src_idx, dst_idx, rowptr,
                                                        cursor, esrc, E);
    dst_agg_kernel<<<(N + 3) / 4, 256, 0, stream>>>(kv, qt, h, inv_norm,
                                                    rowptr, esrc, flags, agg, N);
    out_ln_kernel<<<(N + 15) / 16, 256, 0, stream>>>(agg, Wa, ba, ln_g, ln_b,
                                                     deg, out, gcpart, N);
    gc_final_kernel<<<1, D, 0, stream>>>(gcpart, flags, gc);
    fixup_kernel<<<(N * D + 255) / 256, 256, 0, stream>>>(h, deg, gc, out, N);
}

// Round 6
// 448.276 us; speedup vs baseline: 3.8822x; 1.1665x over previous
//
#include <hip/hip_runtime.h>

#define D 128
#define NH 4
#define DKH 32

typedef __attribute__((ext_vector_type(8))) short short8;
typedef __attribute__((ext_vector_type(4))) float floatx4;

__device__ __forceinline__ float bf2f(unsigned int u) {
    return __uint_as_float((u & 0xffffu) << 16);
}
__device__ __forceinline__ float bf2f_hi(unsigned int u) {
    return __uint_as_float(u & 0xffff0000u);
}
__device__ __forceinline__ unsigned short f2bf(float f) {
    unsigned int x = __float_as_uint(f);
    x += 0x7fffu + ((x >> 16) & 1u);
    return (unsigned short)(x >> 16);
}

// ---------------------------------------------------------------------------
// Fold rel_{k,q,v} into W,b.  Emits WpT: bf16, TRANSPOSED (row = out col j,
// col = in dim i) so MFMA B-fragments are contiguous 16B reads.
// grid (129, 3): x<128 -> weight row i, x==128 -> bias; block 128 (j).
// ---------------------------------------------------------------------------
__global__ void prep_weights_kernel(
    const float* __restrict__ Wk, const float* __restrict__ bk,
    const float* __restrict__ Wq, const float* __restrict__ bq,
    const float* __restrict__ Wv, const float* __restrict__ bv,
    const float* __restrict__ rk, const float* __restrict__ rq,
    const float* __restrict__ rv,
    unsigned short* __restrict__ WpT, float* __restrict__ bp)
{
    int w = blockIdx.y;
    const float* W   = (w == 0) ? Wk : (w == 1) ? Wq : Wv;
    const float* b   = (w == 0) ? bk : (w == 1) ? bq : bv;
    const float* rel = (w == 0) ? rk : (w == 1) ? rq : rv;
    int j = threadIdx.x;            // output column 0..127
    int h = j >> 5, f = j & 31;
    int i = blockIdx.x;
    float acc = 0.f;
    if (i < D) {
        for (int dd = 0; dd < DKH; dd++)
            acc += W[i * D + h * DKH + dd] * rel[h * 1024 + dd * DKH + f];
        WpT[((size_t)(w * D + j)) * D + i] = f2bf(acc);
    } else {
        for (int dd = 0; dd < DKH; dd++)
            acc += b[h * DKH + dd] * rel[h * 1024 + dd * DKH + f];
        bp[w * D + j] = acc;
    }
}

// ---------------------------------------------------------------------------
// MFMA GEMM: [qt | kv] = h @ W'{k,q,v} + b', plus fused row norms.
// 64 rows/block, 256 threads = 4 waves; wave w owns rows w*16..w*16+15.
// A (h, bf16) staged in LDS with +8 padded stride (2-way bank alias = free).
// B = WpT bf16 from global (96 KB, L2-resident, reused by all blocks).
// Layouts (verified, learn_hip m89/m120): A[m=lane&15][k=quad*8+j],
// B[k=quad*8+j][n=lane&15], C col=lane&15 row=quad*4+reg.
// ---------------------------------------------------------------------------
#define ASTR 136
__global__ __launch_bounds__(256) void gemm_mfma_kernel(
    const float* __restrict__ h, const unsigned short* __restrict__ WpT,
    const float* __restrict__ bp,
    unsigned short* __restrict__ qt, unsigned int* __restrict__ kv,
    float* __restrict__ inv_norm, int N)
{
    __shared__ unsigned short hA[64 * ASTR];
    int row0 = blockIdx.x * 64;
    int tid = threadIdx.x;
    for (int i = tid; i < 64 * 32; i += 256) {
        int r = i >> 5, c4 = (i & 31) << 2;
        int n = row0 + r;
        float4 v = make_float4(0.f, 0.f, 0.f, 0.f);
        if (n < N) v = *(const float4*)(h + (size_t)n * D + c4);
        ushort4 bv4;
        bv4.x = f2bf(v.x); bv4.y = f2bf(v.y); bv4.z = f2bf(v.z); bv4.w = f2bf(v.w);
        *(ushort4*)&hA[r * ASTR + c4] = bv4;
    }
    __syncthreads();
    int lane = tid & 63, w = tid >> 6;
    int m = lane & 15, quad = lane >> 4;
    // fused row norms (only feeds the boost branch, which is data-disabled)
    for (int r = 0; r < 16; r++) {
        int row = w * 16 + r;
        unsigned int u = *(const unsigned int*)&hA[row * ASTR + lane * 2];
        float a = bf2f(u), b = bf2f_hi(u);
        float s = a * a + b * b;
        for (int off = 1; off < 64; off <<= 1) s += __shfl_xor(s, off);
        int n = row0 + row;
        if (lane == 0 && n < N) inv_norm[n] = 1.0f / fmaxf(sqrtf(s), 1e-12f);
    }
    // A fragments: 4 K-chunks for this wave's 16 rows
    short8 afrag[4];
    const unsigned short* ab = &hA[(w * 16 + m) * ASTR + quad * 8];
#pragma unroll
    for (int c = 0; c < 4; c++)
        afrag[c] = *(const short8*)(ab + c * 32);

    floatx4 acc[24];
#pragma unroll
    for (int t = 0; t < 24; t++) acc[t] = (floatx4){0.f, 0.f, 0.f, 0.f};
#pragma unroll
    for (int t = 0; t < 24; t++) {
        const unsigned short* bb = WpT + ((size_t)(t * 16 + m)) * D + quad * 8;
        short8 b0 = *(const short8*)(bb);
        short8 b1 = *(const short8*)(bb + 32);
        short8 b2 = *(const short8*)(bb + 64);
        short8 b3 = *(const short8*)(bb + 96);
        acc[t] = __builtin_amdgcn_mfma_f32_16x16x32_bf16(afrag[0], b0, acc[t], 0, 0, 0);
        acc[t] = __builtin_amdgcn_mfma_f32_16x16x32_bf16(afrag[1], b1, acc[t], 0, 0, 0);
        acc[t] = __builtin_amdgcn_mfma_f32_16x16x32_bf16(afrag[2], b2, acc[t], 0, 0, 0);
        acc[t] = __builtin_amdgcn_mfma_f32_16x16x32_bf16(afrag[3], b3, acc[t], 0, 0, 0);
    }
    // epilogue: bias, pack kv dword (k|v) and qt pairs, store
#pragma unroll
    for (int t = 0; t < 8; t++) {
        int j = t * 16 + m;
        float bk = bp[j], bq = bp[D + j], bvs = bp[2 * D + j];
#pragma unroll
        for (int r = 0; r < 4; r++) {
            int n = row0 + w * 16 + quad * 4 + r;
            float kval = acc[t][r] + bk;
            float qval = acc[8 + t][r] + bq;
            float vval = acc[16 + t][r] + bvs;
            float qpart = __shfl_xor(qval, 1);
            if (n < N) {
                kv[(size_t)n * D + j] = (unsigned int)f2bf(kval)
                                      | ((unsigned int)f2bf(vval) << 16);
                if (!(lane & 1)) {
                    unsigned int qw = (unsigned int)f2bf(qval)
                                    | ((unsigned int)f2bf(qpart) << 16);
                    *(unsigned int*)(qt + (size_t)n * D + j) = qw;
                }
            }
        }
    }
}

// ---------------------------------------------------------------------------
// Histograms: cnt_src (src incidence), cnt_dst (dst incidence / CSR sizes).
// ---------------------------------------------------------------------------
__global__ void deg_hist_kernel(const int* __restrict__ src, const int* __restrict__ dst,
                                int* __restrict__ cnt_src, int* __restrict__ cnt_dst, int E)
{
    int e = blockIdx.x * blockDim.x + threadIdx.x;
    if (e >= E) return;
    atomicAdd(&cnt_src[src[e]], 1);
    atomicAdd(&cnt_dst[dst[e]], 1);
}

// ---------------------------------------------------------------------------
// Coalesced single-block scan: rowptr = exclusive_scan(cnt_dst); also emits
// deg[i] = cnt_src[i]+cnt_dst[i], zero-degree count -> flags.
// ---------------------------------------------------------------------------
__global__ __launch_bounds__(1024) void scan_kernel(
    const int* __restrict__ cnt_src, const int* __restrict__ cnt_dst,
    int* __restrict__ rowptr, int* __restrict__ deg,
    const float* __restrict__ fsb, float* __restrict__ flags, int N)
{
    __shared__ int wtot[16];
    __shared__ int wscan[16];
    int tid = threadIdx.x, lane = tid & 63, wv = tid >> 6;
    int running = 0, zc = 0;
    for (int base = 0; base < N; base += 1024) {
        int i = base + tid;
        int cs = 0, cd = 0;
        if (i < N) { cs = cnt_src[i]; cd = cnt_dst[i]; }
        int x = cd;
        for (int off = 1; off < 64; off <<= 1) {
            int y = __shfl_up(x, off);
            if (lane >= off) x += y;
        }
        if (lane == 63) wtot[wv] = x;
        __syncthreads();
        if (wv == 0) {
            int t = (lane < 16) ? wtot[lane] : 0;
            for (int off = 1; off < 16; off <<= 1) {
                int y = __shfl_up(t, off);
                if (lane >= off) t += y;
            }
            if (lane < 16) wscan[lane] = t;
        }
        __syncthreads();
        int woff = (wv == 0) ? 0 : wscan[wv - 1];
        if (i < N) {
            rowptr[i] = running + woff + x - cd;
            int ds = cs + cd;
            deg[i] = ds;
            zc += (ds == 0) ? 1 : 0;
        }
        running += wscan[15];
        __syncthreads();   // protect wtot/wscan for next iteration
    }
    if (tid == 0) rowptr[N] = running;
    for (int off = 1; off < 64; off <<= 1) zc += __shfl_xor(zc, off);
    if (lane == 0) wtot[wv] = zc;
    __syncthreads();
    if (tid == 0) {
        int z = 0;
        for (int k = 0; k < 16; k++) z += wtot[k];
        float sparsity = (float)z / (float)N;
        flags[0] = (sparsity > 0.3f) ? fsb[0] : 0.f;   // boost value
        flags[1] = fmaxf((float)(N - z), 1.f);         // non-zero-deg node count
    }
}

// ---------------------------------------------------------------------------
__global__ void scatter_kernel(const int* __restrict__ src, const int* __restrict__ dst,
                               const int* __restrict__ rowptr, int* __restrict__ cursor,
                               int* __restrict__ esrc, int E)
{
    int e = blockIdx.x * blockDim.x + threadIdx.x;
    if (e >= E) return;
    int d = dst[e];
    int pos = rowptr[d] + atomicAdd(&cursor[d], 1);
    esrc[pos] = src[e];
}

// ---------------------------------------------------------------------------
// Fused softmax + aggregation, gather-based, ZERO atomics, unroll-2.
// One wave per dst node; lane l holds elements {2l, 2l+1} (head = l>>4).
// ---------------------------------------------------------------------------
__global__ __launch_bounds__(256) void dst_agg_kernel(
    const unsigned int* __restrict__ kv, const unsigned short* __restrict__ qt,
    const float* __restrict__ h, const float* __restrict__ inv_norm,
    const int* __restrict__ rowptr, const int* __restrict__ esrc,
    const float* __restrict__ flags,
    float* __restrict__ agg, int N)
{
    int n = (blockIdx.x * blockDim.x + threadIdx.x) >> 6;
    int lane = threadIdx.x & 63;
    if (n >= N) return;
    int beg = rowptr[n], end = rowptr[n + 1];
    unsigned int q2 = *(const unsigned int*)(qt + (size_t)n * D + lane * 2);
    float q0 = bf2f(q2), q1 = bf2f_hi(q2);
    float boost = flags[0];
    float hn0 = 0.f, hn1 = 0.f, innd = 0.f;
    if (boost != 0.f) {
        float2 hh = *(const float2*)(h + (size_t)n * D + lane * 2);
        hn0 = hh.x; hn1 = hh.y; innd = inv_norm[n];
    }
    const float SC = 0.17677669529663687f;   // 1/sqrt(32)
    float acc0 = 0.f, acc1 = 0.f, den = 0.f;
    int i = beg;
    for (; i + 1 < end; i += 2) {
        int s0 = esrc[i], s1 = esrc[i + 1];
        uint2 w0 = *(const uint2*)(kv + (size_t)s0 * D + lane * 2);
        uint2 w1 = *(const uint2*)(kv + (size_t)s1 * D + lane * 2);
        float dot0 = q0 * bf2f(w0.x) + q1 * bf2f(w0.y);
        float dot1 = q0 * bf2f(w1.x) + q1 * bf2f(w1.y);
        dot0 += __shfl_xor(dot0, 1);  dot1 += __shfl_xor(dot1, 1);
        dot0 += __shfl_xor(dot0, 2);  dot1 += __shfl_xor(dot1, 2);
        dot0 += __shfl_xor(dot0, 4);  dot1 += __shfl_xor(dot1, 4);
        dot0 += __shfl_xor(dot0, 8);  dot1 += __shfl_xor(dot1, 8);
        float att0 = dot0 * SC, att1 = dot1 * SC;
        if (boost != 0.f) {   // wave-uniform, off when sparsity <= 0.3
            float2 a0 = *(const float2*)(h + (size_t)s0 * D + lane * 2);
            float2 a1 = *(const float2*)(h + (size_t)s1 * D + lane * 2);
            float f0 = hn0 * a0.x + hn1 * a0.y;
            float f1 = hn0 * a1.x + hn1 * a1.y;
            for (int off = 1; off < 64; off <<= 1) {
                f0 += __shfl_xor(f0, off);
                f1 += __shfl_xor(f1, off);
            }
            att0 += f0 * inv_norm[s0] * innd * boost;
            att1 += f1 * inv_norm[s1] * innd * boost;
        }
        att0 = fminf(fmaxf(att0, -60.f), 60.f);
        att1 = fminf(fmaxf(att1, -60.f), 60.f);
        float p0 = __expf(att0), p1 = __expf(att1);
        den  += p0 + p1;
        acc0 += p0 * bf2f_hi(w0.x) + p1 * bf2f_hi(w1.x);
        acc1 += p0 * bf2f_hi(w0.y) + p1 * bf2f_hi(w1.y);
    }
    if (i < end) {
        int s0 = esrc[i];
        uint2 w0 = *(const uint2*)(kv + (size_t)s0 * D + lane * 2);
        float dot0 = q0 * bf2f(w0.x) + q1 * bf2f(w0.y);
        dot0 += __shfl_xor(dot0, 1);
        dot0 += __shfl_xor(dot0, 2);
        dot0 += __shfl_xor(dot0, 4);
        dot0 += __shfl_xor(dot0, 8);
        float att0 = dot0 * SC;
        if (boost != 0.f) {
            float2 a0 = *(const float2*)(h + (size_t)s0 * D + lane * 2);
            float f0 = hn0 * a0.x + hn1 * a0.y;
            for (int off = 1; off < 64; off <<= 1) f0 += __shfl_xor(f0, off);
            att0 += f0 * inv_norm[s0] * innd * boost;
        }
        att0 = fminf(fmaxf(att0, -60.f), 60.f);
        float p0 = __expf(att0);
        den  += p0;
        acc0 += p0 * bf2f_hi(w0.x);
        acc1 += p0 * bf2f_hi(w0.y);
    }
    float r = 1.0f / fmaxf(den, 1e-38f);
    *(float2*)(agg + (size_t)n * D + lane * 2) = make_float2(acc0 * r, acc1 * r);
}

// ---------------------------------------------------------------------------
// out = LN(agg @ Wa + ba), 16 rows per 256-thread block; unroll-4 K loop
// with hoisted independent weight loads (force vmcnt pipelining).
// ---------------------------------------------------------------------------
__global__ __launch_bounds__(256) void out_ln_kernel(
    const float* __restrict__ agg,
    const float* __restrict__ Wa, const float* __restrict__ ba,
    const float* __restrict__ ln_g, const float* __restrict__ ln_b,
    const int* __restrict__ deg, float* __restrict__ out,
    float* __restrict__ gcpart, int N)
{
    __shared__ float as[16][D];
    __shared__ float os[16][D + 2];
    int row0 = blockIdx.x * 16;
    int tid = threadIdx.x;
    for (int i = tid; i < 16 * D; i += 256) {
        int r = i >> 7, c = i & 127;
        int n = row0 + r;
        as[r][c] = (n < N) ? agg[(size_t)n * D + c] : 0.f;
    }
    __syncthreads();
    int lane = tid & 63, wv = tid >> 6;
    int j2 = lane * 2;
    float acc[4][2];
#pragma unroll
    for (int r = 0; r < 4; r++) { acc[r][0] = 0.f; acc[r][1] = 0.f; }
    for (int d = 0; d < D; d += 4) {
        float2 w0 = *(const float2*)(Wa + (d + 0) * D + j2);
        float2 w1 = *(const float2*)(Wa + (d + 1) * D + j2);
        float2 w2 = *(const float2*)(Wa + (d + 2) * D + j2);
        float2 w3 = *(const float2*)(Wa + (d + 3) * D + j2);
#pragma unroll
        for (int r = 0; r < 4; r++) {
            float a0 = as[wv * 4 + r][d],     a1 = as[wv * 4 + r][d + 1];
            float a2 = as[wv * 4 + r][d + 2], a3 = as[wv * 4 + r][d + 3];
            acc[r][0] += a0 * w0.x + a1 * w1.x + a2 * w2.x + a3 * w3.x;
            acc[r][1] += a0 * w0.y + a1 * w1.y + a2 * w2.y + a3 * w3.y;
        }
    }
    float2 bb = *(const float2*)(ba + j2);
#pragma unroll
    for (int r = 0; r < 4; r++) {
        os[wv * 4 + r][j2]     = acc[r][0] + bb.x;
        os[wv * 4 + r][j2 + 1] = acc[r][1] + bb.y;
    }
    __syncthreads();
    float g0 = ln_g[j2], g1 = ln_g[j2 + 1];
    float b0 = ln_b[j2], b1 = ln_b[j2 + 1];
    float gcs0 = 0.f, gcs1 = 0.f;
    for (int rr = 0; rr < 4; rr++) {
        int r = wv * 4 + rr;
        int n = row0 + r;
        if (n >= N) break;
        float x0 = os[r][j2], x1 = os[r][j2 + 1];
        float s = x0 + x1, s2 = x0 * x0 + x1 * x1;
        for (int off = 1; off < 64; off <<= 1) {
            s  += __shfl_xor(s, off);
            s2 += __shfl_xor(s2, off);
        }
        float mu = s * (1.f / 128.f);
        float var = s2 * (1.f / 128.f) - mu * mu;
        float rstd = rsqrtf(fmaxf(var, 0.f) + 1e-5f);
        float y0 = (x0 - mu) * rstd * g0 + b0;
        float y1 = (x1 - mu) * rstd * g1 + b1;
        *(float2*)(out + (size_t)n * D + j2) = make_float2(y0, y1);
        if (deg[n] != 0) { gcs0 += y0; gcs1 += y1; }
    }
    int slot = blockIdx.x & 63;
    if (gcs0 != 0.f || gcs1 != 0.f) {
        atomicAdd(&gcpart[slot * D + j2],     gcs0);
        atomicAdd(&gcpart[slot * D + j2 + 1], gcs1);
    }
}

__global__ void gc_final_kernel(const float* __restrict__ gcpart,
                                const float* __restrict__ flags,
                                float* __restrict__ gc)
{
    int j = threadIdx.x;  // 128
    float s = 0.f;
    for (int i = 0; i < 64; i++) s += gcpart[i * D + j];
    gc[j] = s / flags[1];
}

__global__ void fixup_kernel(const float* __restrict__ h,
                             const int* __restrict__ deg,
                             const float* __restrict__ gc,
                             float* __restrict__ out, int N)
{
    int idx = blockIdx.x * blockDim.x + threadIdx.x;
    if (idx >= N * D) return;
    int n = idx >> 7, j = idx & 127;
    if (deg[n] == 0)
        out[idx] = 0.9f * h[idx] + 0.1f * gc[j];
}

// ---------------------------------------------------------------------------
extern "C" void kernel_launch(void* const* d_in, const int* in_sizes, int n_in,
                              void* d_out, int out_size, void* d_ws, size_t ws_size,
                              hipStream_t stream)
{
    const float* h       = (const float*)d_in[0];
    const int* src_idx   = (const int*)d_in[1];
    const int* dst_idx   = (const int*)d_in[2];
    const float* Wk      = (const float*)d_in[3];
    const float* bk      = (const float*)d_in[4];
    const float* Wq      = (const float*)d_in[5];
    const float* bq      = (const float*)d_in[6];
    const float* Wv      = (const float*)d_in[7];
    const float* bv      = (const float*)d_in[8];
    const float* rk      = (const float*)d_in[9];
    const float* rq      = (const float*)d_in[10];
    const float* rv      = (const float*)d_in[11];
    const float* Wa      = (const float*)d_in[12];
    const float* ba      = (const float*)d_in[13];
    const float* ln_g    = (const float*)d_in[14];
    const float* ln_b    = (const float*)d_in[15];
    const float* fsb     = (const float*)d_in[16];
    float* out           = (float*)d_out;

    int N = in_sizes[0] / D;
    int E = in_sizes[1];

    // ---- workspace: small control buffers first ---------------------------
    char* p = (char*)d_ws;
    auto alloc = [&](size_t bytes) { char* q = p; p += (bytes + 15) & ~(size_t)15; return q; };

    unsigned short* WpT = (unsigned short*)alloc(3 * D * D * 2);   // bf16 transposed
    float* bp       = (float*)alloc(3 * D * 4);
    float* gc       = (float*)alloc(D * 4);
    float* flags    = (float*)alloc(2 * 4);
    float* inv_norm = (float*)alloc((size_t)N * 4);
    int*   rowptr   = (int*)alloc(((size_t)N + 1) * 4);
    int*   deg      = (int*)alloc((size_t)N * 4);       // written by scan (no memset)
    // zero region: cnt_src, cnt_dst, cursor, gcpart (contiguous)
    char* z1 = p;
    int*   cnt_src = (int*)alloc((size_t)N * 4);
    int*   cnt_dst = (int*)alloc((size_t)N * 4);
    int*   cursor  = (int*)alloc((size_t)N * 4);
    float* gcpart  = (float*)alloc(64 * D * 4);
    size_t z1_bytes = (size_t)(p - z1);
    // big arrays
    unsigned short* qt = (unsigned short*)alloc((size_t)N * D * 2);
    unsigned int*   kv = (unsigned int*)alloc((size_t)N * D * 4);   // packed k|v
    int*   esrc        = (int*)alloc((size_t)E * 4);
    float* agg         = (float*)alloc((size_t)N * D * 4);

    hipMemsetAsync(z1, 0, z1_bytes, stream);

    prep_weights_kernel<<<dim3(129, 3), 128, 0, stream>>>(Wk, bk, Wq, bq, Wv, bv,
                                                          rk, rq, rv, WpT, bp);
    gemm_mfma_kernel<<<(N + 63) / 64, 256, 0, stream>>>(h, WpT, bp, qt, kv,
                                                        inv_norm, N);
    deg_hist_kernel<<<(E + 255) / 256, 256, 0, stream>>>(src_idx, dst_idx,
                                                         cnt_src, cnt_dst, E);
    scan_kernel<<<1, 1024, 0, stream>>>(cnt_src, cnt_dst, rowptr, deg, fsb, flags, N);
    scatter_kernel<<<(E + 255) / 256, 256, 0, stream>>>(src_idx, dst_idx, rowptr,
                                                        cursor, esrc, E);
    dst_agg_kernel<<<(N + 3) / 4, 256, 0, stream>>>(kv, qt, h, inv_norm,
                                                    rowptr, esrc, flags, agg, N);
    out_ln_kernel<<<(N + 15) / 16, 256, 0, stream>>>(agg, Wa, ba, ln_g, ln_b,
                                                     deg, out, gcpart, N);
    gc_final_kernel<<<1, D, 0, stream>>>(gcpart, flags, gc);
    fixup_kernel<<<(N * D + 255) / 256, 256, 0, stream>>>(h, deg, gc, out, N);
}

// Round 7
// 426.477 us; speedup vs baseline: 4.0806x; 1.0511x over previous
//
#include <hip/hip_runtime.h>

#define D 128
#define NH 4
#define DKH 32

typedef __attribute__((ext_vector_type(8))) short short8;
typedef __attribute__((ext_vector_type(4))) float floatx4;

__device__ __forceinline__ float bf2f(unsigned int u) {
    return __uint_as_float((u & 0xffffu) << 16);
}
__device__ __forceinline__ float bf2f_hi(unsigned int u) {
    return __uint_as_float(u & 0xffff0000u);
}
__device__ __forceinline__ unsigned short f2bf(float f) {
    unsigned int x = __float_as_uint(f);
    x += 0x7fffu + ((x >> 16) & 1u);
    return (unsigned short)(x >> 16);
}

// ---------------------------------------------------------------------------
// Fold rel_{k,q,v} into W,b.  Emits WpT: bf16, TRANSPOSED (row = out col j,
// col = in dim i) so MFMA B-fragments are contiguous 16B reads.
// ---------------------------------------------------------------------------
__global__ void prep_weights_kernel(
    const float* __restrict__ Wk, const float* __restrict__ bk,
    const float* __restrict__ Wq, const float* __restrict__ bq,
    const float* __restrict__ Wv, const float* __restrict__ bv,
    const float* __restrict__ rk, const float* __restrict__ rq,
    const float* __restrict__ rv,
    unsigned short* __restrict__ WpT, float* __restrict__ bp)
{
    int w = blockIdx.y;
    const float* W   = (w == 0) ? Wk : (w == 1) ? Wq : Wv;
    const float* b   = (w == 0) ? bk : (w == 1) ? bq : bv;
    const float* rel = (w == 0) ? rk : (w == 1) ? rq : rv;
    int j = threadIdx.x;            // output column 0..127
    int h = j >> 5, f = j & 31;
    int i = blockIdx.x;
    float acc = 0.f;
    if (i < D) {
        for (int dd = 0; dd < DKH; dd++)
            acc += W[i * D + h * DKH + dd] * rel[h * 1024 + dd * DKH + f];
        WpT[((size_t)(w * D + j)) * D + i] = f2bf(acc);
    } else {
        for (int dd = 0; dd < DKH; dd++)
            acc += b[h * DKH + dd] * rel[h * 1024 + dd * DKH + f];
        bp[w * D + j] = acc;
    }
}

// ---------------------------------------------------------------------------
// MFMA GEMM: [qt | kv] = h @ W'{k,q,v} + b', plus fused row norms.
// 64 rows/block, 4 waves; wave w owns rows w*16..w*16+15.
// K-loop restructured as 8 NON-UNROLLED triplet iterations (k/q/v tile for
// one 16-col group): live accs = 12 regs, 12 independent B loads per iter.
// Layouts (verified r6): A[m=lane&15][k=quad*8+j], B row = out col,
// C/D col=lane&15, row=quad*4+reg.
// ---------------------------------------------------------------------------
#define ASTR 136
__global__ __launch_bounds__(256) void gemm_mfma_kernel(
    const float* __restrict__ h, const unsigned short* __restrict__ WpT,
    const float* __restrict__ bp,
    unsigned short* __restrict__ qt, unsigned int* __restrict__ kv,
    float* __restrict__ inv_norm, int N)
{
    __shared__ unsigned short hA[64 * ASTR];
    int row0 = blockIdx.x * 64;
    int tid = threadIdx.x;
    for (int i = tid; i < 64 * 32; i += 256) {
        int r = i >> 5, c4 = (i & 31) << 2;
        int n = row0 + r;
        float4 v = make_float4(0.f, 0.f, 0.f, 0.f);
        if (n < N) v = *(const float4*)(h + (size_t)n * D + c4);
        ushort4 bv4;
        bv4.x = f2bf(v.x); bv4.y = f2bf(v.y); bv4.z = f2bf(v.z); bv4.w = f2bf(v.w);
        *(ushort4*)&hA[r * ASTR + c4] = bv4;
    }
    __syncthreads();
    int lane = tid & 63, w = tid >> 6;
    int m = lane & 15, quad = lane >> 4;

    // A fragments: this wave's 16 rows, 4 K-chunks (LDS, +8 pad = 2-way free)
    short8 afrag[4];
    const unsigned short* ab = &hA[(w * 16 + m) * ASTR + quad * 8];
#pragma unroll
    for (int c = 0; c < 4; c++)
        afrag[c] = *(const short8*)(ab + c * 32);

#pragma unroll 1
    for (int t = 0; t < 8; t++) {
        const unsigned short* kb = WpT + ((size_t)(t * 16 + m)) * D + quad * 8;
        const unsigned short* qb = kb + (size_t)D * D;
        const unsigned short* vb = kb + (size_t)2 * D * D;
        short8 k0 = *(const short8*)(kb);
        short8 k1 = *(const short8*)(kb + 32);
        short8 k2 = *(const short8*)(kb + 64);
        short8 k3 = *(const short8*)(kb + 96);
        short8 q0 = *(const short8*)(qb);
        short8 q1 = *(const short8*)(qb + 32);
        short8 q2 = *(const short8*)(qb + 64);
        short8 q3 = *(const short8*)(qb + 96);
        short8 v0 = *(const short8*)(vb);
        short8 v1 = *(const short8*)(vb + 32);
        short8 v2 = *(const short8*)(vb + 64);
        short8 v3 = *(const short8*)(vb + 96);
        floatx4 aK = (floatx4){0.f, 0.f, 0.f, 0.f};
        floatx4 aQ = (floatx4){0.f, 0.f, 0.f, 0.f};
        floatx4 aV = (floatx4){0.f, 0.f, 0.f, 0.f};
        aK = __builtin_amdgcn_mfma_f32_16x16x32_bf16(afrag[0], k0, aK, 0, 0, 0);
        aQ = __builtin_amdgcn_mfma_f32_16x16x32_bf16(afrag[0], q0, aQ, 0, 0, 0);
        aV = __builtin_amdgcn_mfma_f32_16x16x32_bf16(afrag[0], v0, aV, 0, 0, 0);
        aK = __builtin_amdgcn_mfma_f32_16x16x32_bf16(afrag[1], k1, aK, 0, 0, 0);
        aQ = __builtin_amdgcn_mfma_f32_16x16x32_bf16(afrag[1], q1, aQ, 0, 0, 0);
        aV = __builtin_amdgcn_mfma_f32_16x16x32_bf16(afrag[1], v1, aV, 0, 0, 0);
        aK = __builtin_amdgcn_mfma_f32_16x16x32_bf16(afrag[2], k2, aK, 0, 0, 0);
        aQ = __builtin_amdgcn_mfma_f32_16x16x32_bf16(afrag[2], q2, aQ, 0, 0, 0);
        aV = __builtin_amdgcn_mfma_f32_16x16x32_bf16(afrag[2], v2, aV, 0, 0, 0);
        aK = __builtin_amdgcn_mfma_f32_16x16x32_bf16(afrag[3], k3, aK, 0, 0, 0);
        aQ = __builtin_amdgcn_mfma_f32_16x16x32_bf16(afrag[3], q3, aQ, 0, 0, 0);
        aV = __builtin_amdgcn_mfma_f32_16x16x32_bf16(afrag[3], v3, aV, 0, 0, 0);
        // epilogue for this 16-col group
        int j = t * 16 + m;
        float bk = bp[j], bq = bp[D + j], bvs = bp[2 * D + j];
#pragma unroll
        for (int r = 0; r < 4; r++) {
            int n = row0 + w * 16 + quad * 4 + r;
            float kval = aK[r] + bk;
            float qval = aQ[r] + bq;
            float vval = aV[r] + bvs;
            float qpart = __shfl_xor(qval, 1);
            if (n < N) {
                kv[(size_t)n * D + j] = (unsigned int)f2bf(kval)
                                      | ((unsigned int)f2bf(vval) << 16);
                if (!(lane & 1)) {
                    unsigned int qw = (unsigned int)f2bf(qval)
                                    | ((unsigned int)f2bf(qpart) << 16);
                    *(unsigned int*)(qt + (size_t)n * D + j) = qw;
                }
            }
        }
    }

    // fused row norms: 4 independent shuffle chains interleaved
    for (int rr = 0; rr < 16; rr += 4) {
        float s0, s1, s2, s3;
        {
            unsigned int u0 = *(const unsigned int*)&hA[(w * 16 + rr + 0) * ASTR + lane * 2];
            unsigned int u1 = *(const unsigned int*)&hA[(w * 16 + rr + 1) * ASTR + lane * 2];
            unsigned int u2 = *(const unsigned int*)&hA[(w * 16 + rr + 2) * ASTR + lane * 2];
            unsigned int u3 = *(const unsigned int*)&hA[(w * 16 + rr + 3) * ASTR + lane * 2];
            float a, b;
            a = bf2f(u0); b = bf2f_hi(u0); s0 = a * a + b * b;
            a = bf2f(u1); b = bf2f_hi(u1); s1 = a * a + b * b;
            a = bf2f(u2); b = bf2f_hi(u2); s2 = a * a + b * b;
            a = bf2f(u3); b = bf2f_hi(u3); s3 = a * a + b * b;
        }
#pragma unroll
        for (int off = 1; off < 64; off <<= 1) {
            s0 += __shfl_xor(s0, off);
            s1 += __shfl_xor(s1, off);
            s2 += __shfl_xor(s2, off);
            s3 += __shfl_xor(s3, off);
        }
        if (lane < 4) {
            float sv = (lane == 0) ? s0 : (lane == 1) ? s1 : (lane == 2) ? s2 : s3;
            int n = row0 + w * 16 + rr + lane;
            if (n < N) inv_norm[n] = 1.0f / fmaxf(sqrtf(sv), 1e-12f);
        }
    }
}

// ---------------------------------------------------------------------------
__global__ void deg_hist_kernel(const int* __restrict__ src, const int* __restrict__ dst,
                                int* __restrict__ cnt_src, int* __restrict__ cnt_dst, int E)
{
    int e = blockIdx.x * blockDim.x + threadIdx.x;
    if (e >= E) return;
    atomicAdd(&cnt_src[src[e]], 1);
    atomicAdd(&cnt_dst[dst[e]], 1);
}

// ---------------------------------------------------------------------------
// Coalesced single-block scan: rowptr = exclusive_scan(cnt_dst); also emits
// deg[i] = cnt_src[i]+cnt_dst[i], zero-degree count -> flags.
// ---------------------------------------------------------------------------
__global__ __launch_bounds__(1024) void scan_kernel(
    const int* __restrict__ cnt_src, const int* __restrict__ cnt_dst,
    int* __restrict__ rowptr, int* __restrict__ deg,
    const float* __restrict__ fsb, float* __restrict__ flags, int N)
{
    __shared__ int wtot[16];
    __shared__ int wscan[16];
    int tid = threadIdx.x, lane = tid & 63, wv = tid >> 6;
    int running = 0, zc = 0;
    for (int base = 0; base < N; base += 1024) {
        int i = base + tid;
        int cs = 0, cd = 0;
        if (i < N) { cs = cnt_src[i]; cd = cnt_dst[i]; }
        int x = cd;
        for (int off = 1; off < 64; off <<= 1) {
            int y = __shfl_up(x, off);
            if (lane >= off) x += y;
        }
        if (lane == 63) wtot[wv] = x;
        __syncthreads();
        if (wv == 0) {
            int t = (lane < 16) ? wtot[lane] : 0;
            for (int off = 1; off < 16; off <<= 1) {
                int y = __shfl_up(t, off);
                if (lane >= off) t += y;
            }
            if (lane < 16) wscan[lane] = t;
        }
        __syncthreads();
        int woff = (wv == 0) ? 0 : wscan[wv - 1];
        if (i < N) {
            rowptr[i] = running + woff + x - cd;
            int ds = cs + cd;
            deg[i] = ds;
            zc += (ds == 0) ? 1 : 0;
        }
        running += wscan[15];
        __syncthreads();   // protect wtot/wscan for next iteration
    }
    if (tid == 0) rowptr[N] = running;
    for (int off = 1; off < 64; off <<= 1) zc += __shfl_xor(zc, off);
    if (lane == 0) wtot[wv] = zc;
    __syncthreads();
    if (tid == 0) {
        int z = 0;
        for (int k = 0; k < 16; k++) z += wtot[k];
        float sparsity = (float)z / (float)N;
        flags[0] = (sparsity > 0.3f) ? fsb[0] : 0.f;   // boost value
        flags[1] = fmaxf((float)(N - z), 1.f);         // non-zero-deg node count
    }
}

// ---------------------------------------------------------------------------
__global__ void scatter_kernel(const int* __restrict__ src, const int* __restrict__ dst,
                               const int* __restrict__ rowptr, int* __restrict__ cursor,
                               int* __restrict__ esrc, int E)
{
    int e = blockIdx.x * blockDim.x + threadIdx.x;
    if (e >= E) return;
    int d = dst[e];
    int pos = rowptr[d] + atomicAdd(&cursor[d], 1);
    esrc[pos] = src[e];
}

// ---------------------------------------------------------------------------
// Fused softmax + aggregation, gather-based, ZERO atomics, unroll-2.
// One wave per dst node; lane l holds elements {2l, 2l+1} (head = l>>4).
// ---------------------------------------------------------------------------
__global__ __launch_bounds__(256) void dst_agg_kernel(
    const unsigned int* __restrict__ kv, const unsigned short* __restrict__ qt,
    const float* __restrict__ h, const float* __restrict__ inv_norm,
    const int* __restrict__ rowptr, const int* __restrict__ esrc,
    const float* __restrict__ flags,
    float* __restrict__ agg, int N)
{
    int n = (blockIdx.x * blockDim.x + threadIdx.x) >> 6;
    int lane = threadIdx.x & 63;
    if (n >= N) return;
    int beg = rowptr[n], end = rowptr[n + 1];
    unsigned int q2 = *(const unsigned int*)(qt + (size_t)n * D + lane * 2);
    float q0 = bf2f(q2), q1 = bf2f_hi(q2);
    float boost = flags[0];
    float hn0 = 0.f, hn1 = 0.f, innd = 0.f;
    if (boost != 0.f) {
        float2 hh = *(const float2*)(h + (size_t)n * D + lane * 2);
        hn0 = hh.x; hn1 = hh.y; innd = inv_norm[n];
    }
    const float SC = 0.17677669529663687f;   // 1/sqrt(32)
    float acc0 = 0.f, acc1 = 0.f, den = 0.f;
    int i = beg;
    for (; i + 1 < end; i += 2) {
        int s0 = esrc[i], s1 = esrc[i + 1];
        uint2 w0 = *(const uint2*)(kv + (size_t)s0 * D + lane * 2);
        uint2 w1 = *(const uint2*)(kv + (size_t)s1 * D + lane * 2);
        float dot0 = q0 * bf2f(w0.x) + q1 * bf2f(w0.y);
        float dot1 = q0 * bf2f(w1.x) + q1 * bf2f(w1.y);
        dot0 += __shfl_xor(dot0, 1);  dot1 += __shfl_xor(dot1, 1);
        dot0 += __shfl_xor(dot0, 2);  dot1 += __shfl_xor(dot1, 2);
        dot0 += __shfl_xor(dot0, 4);  dot1 += __shfl_xor(dot1, 4);
        dot0 += __shfl_xor(dot0, 8);  dot1 += __shfl_xor(dot1, 8);
        float att0 = dot0 * SC, att1 = dot1 * SC;
        if (boost != 0.f) {   // wave-uniform, off when sparsity <= 0.3
            float2 a0 = *(const float2*)(h + (size_t)s0 * D + lane * 2);
            float2 a1 = *(const float2*)(h + (size_t)s1 * D + lane * 2);
            float f0 = hn0 * a0.x + hn1 * a0.y;
            float f1 = hn0 * a1.x + hn1 * a1.y;
            for (int off = 1; off < 64; off <<= 1) {
                f0 += __shfl_xor(f0, off);
                f1 += __shfl_xor(f1, off);
            }
            att0 += f0 * inv_norm[s0] * innd * boost;
            att1 += f1 * inv_norm[s1] * innd * boost;
        }
        att0 = fminf(fmaxf(att0, -60.f), 60.f);
        att1 = fminf(fmaxf(att1, -60.f), 60.f);
        float p0 = __expf(att0), p1 = __expf(att1);
        den  += p0 + p1;
        acc0 += p0 * bf2f_hi(w0.x) + p1 * bf2f_hi(w1.x);
        acc1 += p0 * bf2f_hi(w0.y) + p1 * bf2f_hi(w1.y);
    }
    if (i < end) {
        int s0 = esrc[i];
        uint2 w0 = *(const uint2*)(kv + (size_t)s0 * D + lane * 2);
        float dot0 = q0 * bf2f(w0.x) + q1 * bf2f(w0.y);
        dot0 += __shfl_xor(dot0, 1);
        dot0 += __shfl_xor(dot0, 2);
        dot0 += __shfl_xor(dot0, 4);
        dot0 += __shfl_xor(dot0, 8);
        float att0 = dot0 * SC;
        if (boost != 0.f) {
            float2 a0 = *(const float2*)(h + (size_t)s0 * D + lane * 2);
            float f0 = hn0 * a0.x + hn1 * a0.y;
            for (int off = 1; off < 64; off <<= 1) f0 += __shfl_xor(f0, off);
            att0 += f0 * inv_norm[s0] * innd * boost;
        }
        att0 = fminf(fmaxf(att0, -60.f), 60.f);
        float p0 = __expf(att0);
        den  += p0;
        acc0 += p0 * bf2f_hi(w0.x);
        acc1 += p0 * bf2f_hi(w0.y);
    }
    float r = 1.0f / fmaxf(den, 1e-38f);
    *(float2*)(agg + (size_t)n * D + lane * 2) = make_float2(acc0 * r, acc1 * r);
}

// ---------------------------------------------------------------------------
// out = LN(agg @ Wa + ba), 16 rows per 256-thread block; unroll-4 K loop.
// ---------------------------------------------------------------------------
__global__ __launch_bounds__(256) void out_ln_kernel(
    const float* __restrict__ agg,
    const float* __restrict__ Wa, const float* __restrict__ ba,
    const float* __restrict__ ln_g, const float* __restrict__ ln_b,
    const int* __restrict__ deg, float* __restrict__ out,
    float* __restrict__ gcpart, int N)
{
    __shared__ float as[16][D];
    __shared__ float os[16][D + 2];
    int row0 = blockIdx.x * 16;
    int tid = threadIdx.x;
    for (int i = tid; i < 16 * D; i += 256) {
        int r = i >> 7, c = i & 127;
        int n = row0 + r;
        as[r][c] = (n < N) ? agg[(size_t)n * D + c] : 0.f;
    }
    __syncthreads();
    int lane = tid & 63, wv = tid >> 6;
    int j2 = lane * 2;
    float acc[4][2];
#pragma unroll
    for (int r = 0; r < 4; r++) { acc[r][0] = 0.f; acc[r][1] = 0.f; }
    for (int d = 0; d < D; d += 4) {
        float2 w0 = *(const float2*)(Wa + (d + 0) * D + j2);
        float2 w1 = *(const float2*)(Wa + (d + 1) * D + j2);
        float2 w2 = *(const float2*)(Wa + (d + 2) * D + j2);
        float2 w3 = *(const float2*)(Wa + (d + 3) * D + j2);
#pragma unroll
        for (int r = 0; r < 4; r++) {
            float a0 = as[wv * 4 + r][d],     a1 = as[wv * 4 + r][d + 1];
            float a2 = as[wv * 4 + r][d + 2], a3 = as[wv * 4 + r][d + 3];
            acc[r][0] += a0 * w0.x + a1 * w1.x + a2 * w2.x + a3 * w3.x;
            acc[r][1] += a0 * w0.y + a1 * w1.y + a2 * w2.y + a3 * w3.y;
        }
    }
    float2 bb = *(const float2*)(ba + j2);
#pragma unroll
    for (int r = 0; r < 4; r++) {
        os[wv * 4 + r][j2]     = acc[r][0] + bb.x;
        os[wv * 4 + r][j2 + 1] = acc[r][1] + bb.y;
    }
    __syncthreads();
    float g0 = ln_g[j2], g1 = ln_g[j2 + 1];
    float b0 = ln_b[j2], b1 = ln_b[j2 + 1];
    float gcs0 = 0.f, gcs1 = 0.f;
    for (int rr = 0; rr < 4; rr++) {
        int r = wv * 4 + rr;
        int n = row0 + r;
        if (n >= N) break;
        float x0 = os[r][j2], x1 = os[r][j2 + 1];
        float s = x0 + x1, s2 = x0 * x0 + x1 * x1;
        for (int off = 1; off < 64; off <<= 1) {
            s  += __shfl_xor(s, off);
            s2 += __shfl_xor(s2, off);
        }
        float mu = s * (1.f / 128.f);
        float var = s2 * (1.f / 128.f) - mu * mu;
        float rstd = rsqrtf(fmaxf(var, 0.f) + 1e-5f);
        float y0 = (x0 - mu) * rstd * g0 + b0;
        float y1 = (x1 - mu) * rstd * g1 + b1;
        *(float2*)(out + (size_t)n * D + j2) = make_float2(y0, y1);
        if (deg[n] != 0) { gcs0 += y0; gcs1 += y1; }
    }
    int slot = blockIdx.x & 63;
    if (gcs0 != 0.f || gcs1 != 0.f) {
        atomicAdd(&gcpart[slot * D + j2],     gcs0);
        atomicAdd(&gcpart[slot * D + j2 + 1], gcs1);
    }
}

__global__ void gc_final_kernel(const float* __restrict__ gcpart,
                                const float* __restrict__ flags,
                                float* __restrict__ gc)
{
    int j = threadIdx.x;  // 128
    float s = 0.f;
    for (int i = 0; i < 64; i++) s += gcpart[i * D + j];
    gc[j] = s / flags[1];
}

// ---------------------------------------------------------------------------
// Zero-degree fixup: one thread per NODE (zero-deg set is typically empty).
// ---------------------------------------------------------------------------
__global__ void fixup_kernel(const float* __restrict__ h,
                             const int* __restrict__ deg,
                             const float* __restrict__ gc,
                             float* __restrict__ out, int N)
{
    int n = blockIdx.x * blockDim.x + threadIdx.x;
    if (n >= N) return;
    if (deg[n] != 0) return;
    for (int j = 0; j < D; j += 4) {
        float4 hv = *(const float4*)(h + (size_t)n * D + j);
        float4 gv = *(const float4*)(gc + j);
        float4 o;
        o.x = 0.9f * hv.x + 0.1f * gv.x;
        o.y = 0.9f * hv.y + 0.1f * gv.y;
        o.z = 0.9f * hv.z + 0.1f * gv.z;
        o.w = 0.9f * hv.w + 0.1f * gv.w;
        *(float4*)(out + (size_t)n * D + j) = o;
    }
}

// ---------------------------------------------------------------------------
extern "C" void kernel_launch(void* const* d_in, const int* in_sizes, int n_in,
                              void* d_out, int out_size, void* d_ws, size_t ws_size,
                              hipStream_t stream)
{
    const float* h       = (const float*)d_in[0];
    const int* src_idx   = (const int*)d_in[1];
    const int* dst_idx   = (const int*)d_in[2];
    const float* Wk      = (const float*)d_in[3];
    const float* bk      = (const float*)d_in[4];
    const float* Wq      = (const float*)d_in[5];
    const float* bq      = (const float*)d_in[6];
    const float* Wv      = (const float*)d_in[7];
    const float* bv      = (const float*)d_in[8];
    const float* rk      = (const float*)d_in[9];
    const float* rq      = (const float*)d_in[10];
    const float* rv      = (const float*)d_in[11];
    const float* Wa      = (const float*)d_in[12];
    const float* ba      = (const float*)d_in[13];
    const float* ln_g    = (const float*)d_in[14];
    const float* ln_b    = (const float*)d_in[15];
    const float* fsb     = (const float*)d_in[16];
    float* out           = (float*)d_out;

    int N = in_sizes[0] / D;
    int E = in_sizes[1];

    // ---- workspace: small control buffers first ---------------------------
    char* p = (char*)d_ws;
    auto alloc = [&](size_t bytes) { char* q = p; p += (bytes + 15) & ~(size_t)15; return q; };

    unsigned short* WpT = (unsigned short*)alloc(3 * D * D * 2);   // bf16 transposed
    float* bp       = (float*)alloc(3 * D * 4);
    float* gc       = (float*)alloc(D * 4);
    float* flags    = (float*)alloc(2 * 4);
    float* inv_norm = (float*)alloc((size_t)N * 4);
    int*   rowptr   = (int*)alloc(((size_t)N + 1) * 4);
    int*   deg      = (int*)alloc((size_t)N * 4);       // written by scan (no memset)
    // zero region: cnt_src, cnt_dst, cursor, gcpart (contiguous)
    char* z1 = p;
    int*   cnt_src = (int*)alloc((size_t)N * 4);
    int*   cnt_dst = (int*)alloc((size_t)N * 4);
    int*   cursor  = (int*)alloc((size_t)N * 4);
    float* gcpart  = (float*)alloc(64 * D * 4);
    size_t z1_bytes = (size_t)(p - z1);
    // big arrays
    unsigned short* qt = (unsigned short*)alloc((size_t)N * D * 2);
    unsigned int*   kv = (unsigned int*)alloc((size_t)N * D * 4);   // packed k|v
    int*   esrc        = (int*)alloc((size_t)E * 4);
    float* agg         = (float*)alloc((size_t)N * D * 4);

    hipMemsetAsync(z1, 0, z1_bytes, stream);

    prep_weights_kernel<<<dim3(129, 3), 128, 0, stream>>>(Wk, bk, Wq, bq, Wv, bv,
                                                          rk, rq, rv, WpT, bp);
    gemm_mfma_kernel<<<(N + 63) / 64, 256, 0, stream>>>(h, WpT, bp, qt, kv,
                                                        inv_norm, N);
    deg_hist_kernel<<<(E + 255) / 256, 256, 0, stream>>>(src_idx, dst_idx,
                                                         cnt_src, cnt_dst, E);
    scan_kernel<<<1, 1024, 0, stream>>>(cnt_src, cnt_dst, rowptr, deg, fsb, flags, N);
    scatter_kernel<<<(E + 255) / 256, 256, 0, stream>>>(src_idx, dst_idx, rowptr,
                                                        cursor, esrc, E);
    dst_agg_kernel<<<(N + 3) / 4, 256, 0, stream>>>(kv, qt, h, inv_norm,
                                                    rowptr, esrc, flags, agg, N);
    out_ln_kernel<<<(N + 15) / 16, 256, 0, stream>>>(agg, Wa, ba, ln_g, ln_b,
                                                     deg, out, gcpart, N);
    gc_final_kernel<<<1, D, 0, stream>>>(gcpart, flags, gc);
    fixup_kernel<<<(N + 255) / 256, 256, 0, stream>>>(h, deg, gc, out, N);
}

// Round 8
// 395.492 us; speedup vs baseline: 4.4003x; 1.0783x over previous
//
#include <hip/hip_runtime.h>

#define D 128
#define NH 4
#define DKH 32

typedef __attribute__((ext_vector_type(8))) short short8;
typedef __attribute__((ext_vector_type(4))) float floatx4;

__device__ __forceinline__ float bf2f(unsigned int u) {
    return __uint_as_float((u & 0xffffu) << 16);
}
__device__ __forceinline__ float bf2f_hi(unsigned int u) {
    return __uint_as_float(u & 0xffff0000u);
}
__device__ __forceinline__ unsigned short f2bf(float f) {
    unsigned int x = __float_as_uint(f);
    x += 0x7fffu + ((x >> 16) & 1u);
    return (unsigned short)(x >> 16);
}

// ---------------------------------------------------------------------------
// Fold rel_{k,q,v} into W,b.  Emits WpT: bf16, TRANSPOSED (row = out col j,
// col = in dim i) so MFMA B-fragments are contiguous 16B reads.
// ---------------------------------------------------------------------------
__global__ void prep_weights_kernel(
    const float* __restrict__ Wk, const float* __restrict__ bk,
    const float* __restrict__ Wq, const float* __restrict__ bq,
    const float* __restrict__ Wv, const float* __restrict__ bv,
    const float* __restrict__ rk, const float* __restrict__ rq,
    const float* __restrict__ rv,
    unsigned short* __restrict__ WpT, float* __restrict__ bp)
{
    int w = blockIdx.y;
    const float* W   = (w == 0) ? Wk : (w == 1) ? Wq : Wv;
    const float* b   = (w == 0) ? bk : (w == 1) ? bq : bv;
    const float* rel = (w == 0) ? rk : (w == 1) ? rq : rv;
    int j = threadIdx.x;            // output column 0..127
    int h = j >> 5, f = j & 31;
    int i = blockIdx.x;
    float acc = 0.f;
    if (i < D) {
        for (int dd = 0; dd < DKH; dd++)
            acc += W[i * D + h * DKH + dd] * rel[h * 1024 + dd * DKH + f];
        WpT[((size_t)(w * D + j)) * D + i] = f2bf(acc);
    } else {
        for (int dd = 0; dd < DKH; dd++)
            acc += b[h * DKH + dd] * rel[h * 1024 + dd * DKH + f];
        bp[w * D + j] = acc;
    }
}

// WaT[j][i] = bf16(Wa[i][j])
__global__ void prep_wa_kernel(const float* __restrict__ Wa,
                               unsigned short* __restrict__ WaT)
{
    int j = blockIdx.x, i = threadIdx.x;
    WaT[(size_t)j * D + i] = f2bf(Wa[(size_t)i * D + j]);
}

// ---------------------------------------------------------------------------
// MFMA GEMM: [qt | kv] = h @ W'{k,q,v} + b', plus fused row norms.
// 64 rows/block, 4 waves; wave w owns rows w*16..w*16+15.
// 8 non-unrolled triplet iterations; live accs = 12 regs.
// Layouts (verified r6): A[m=lane&15][k=quad*8+j], B row = out col,
// C/D col=lane&15, row=quad*4+reg.
// ---------------------------------------------------------------------------
#define ASTR 136
__global__ __launch_bounds__(256) void gemm_mfma_kernel(
    const float* __restrict__ h, const unsigned short* __restrict__ WpT,
    const float* __restrict__ bp,
    unsigned short* __restrict__ qt, unsigned int* __restrict__ kv,
    float* __restrict__ inv_norm, int N)
{
    __shared__ unsigned short hA[64 * ASTR];
    int row0 = blockIdx.x * 64;
    int tid = threadIdx.x;
    for (int i = tid; i < 64 * 32; i += 256) {
        int r = i >> 5, c4 = (i & 31) << 2;
        int n = row0 + r;
        float4 v = make_float4(0.f, 0.f, 0.f, 0.f);
        if (n < N) v = *(const float4*)(h + (size_t)n * D + c4);
        ushort4 bv4;
        bv4.x = f2bf(v.x); bv4.y = f2bf(v.y); bv4.z = f2bf(v.z); bv4.w = f2bf(v.w);
        *(ushort4*)&hA[r * ASTR + c4] = bv4;
    }
    __syncthreads();
    int lane = tid & 63, w = tid >> 6;
    int m = lane & 15, quad = lane >> 4;

    short8 afrag[4];
    const unsigned short* ab = &hA[(w * 16 + m) * ASTR + quad * 8];
#pragma unroll
    for (int c = 0; c < 4; c++)
        afrag[c] = *(const short8*)(ab + c * 32);

#pragma unroll 1
    for (int t = 0; t < 8; t++) {
        const unsigned short* kb = WpT + ((size_t)(t * 16 + m)) * D + quad * 8;
        const unsigned short* qb = kb + (size_t)D * D;
        const unsigned short* vb = kb + (size_t)2 * D * D;
        short8 k0 = *(const short8*)(kb);
        short8 k1 = *(const short8*)(kb + 32);
        short8 k2 = *(const short8*)(kb + 64);
        short8 k3 = *(const short8*)(kb + 96);
        short8 q0 = *(const short8*)(qb);
        short8 q1 = *(const short8*)(qb + 32);
        short8 q2 = *(const short8*)(qb + 64);
        short8 q3 = *(const short8*)(qb + 96);
        short8 v0 = *(const short8*)(vb);
        short8 v1 = *(const short8*)(vb + 32);
        short8 v2 = *(const short8*)(vb + 64);
        short8 v3 = *(const short8*)(vb + 96);
        floatx4 aK = (floatx4){0.f, 0.f, 0.f, 0.f};
        floatx4 aQ = (floatx4){0.f, 0.f, 0.f, 0.f};
        floatx4 aV = (floatx4){0.f, 0.f, 0.f, 0.f};
        aK = __builtin_amdgcn_mfma_f32_16x16x32_bf16(afrag[0], k0, aK, 0, 0, 0);
        aQ = __builtin_amdgcn_mfma_f32_16x16x32_bf16(afrag[0], q0, aQ, 0, 0, 0);
        aV = __builtin_amdgcn_mfma_f32_16x16x32_bf16(afrag[0], v0, aV, 0, 0, 0);
        aK = __builtin_amdgcn_mfma_f32_16x16x32_bf16(afrag[1], k1, aK, 0, 0, 0);
        aQ = __builtin_amdgcn_mfma_f32_16x16x32_bf16(afrag[1], q1, aQ, 0, 0, 0);
        aV = __builtin_amdgcn_mfma_f32_16x16x32_bf16(afrag[1], v1, aV, 0, 0, 0);
        aK = __builtin_amdgcn_mfma_f32_16x16x32_bf16(afrag[2], k2, aK, 0, 0, 0);
        aQ = __builtin_amdgcn_mfma_f32_16x16x32_bf16(afrag[2], q2, aQ, 0, 0, 0);
        aV = __builtin_amdgcn_mfma_f32_16x16x32_bf16(afrag[2], v2, aV, 0, 0, 0);
        aK = __builtin_amdgcn_mfma_f32_16x16x32_bf16(afrag[3], k3, aK, 0, 0, 0);
        aQ = __builtin_amdgcn_mfma_f32_16x16x32_bf16(afrag[3], q3, aQ, 0, 0, 0);
        aV = __builtin_amdgcn_mfma_f32_16x16x32_bf16(afrag[3], v3, aV, 0, 0, 0);
        int j = t * 16 + m;
        float bk = bp[j], bq = bp[D + j], bvs = bp[2 * D + j];
#pragma unroll
        for (int r = 0; r < 4; r++) {
            int n = row0 + w * 16 + quad * 4 + r;
            float kval = aK[r] + bk;
            float qval = aQ[r] + bq;
            float vval = aV[r] + bvs;
            float qpart = __shfl_xor(qval, 1);
            if (n < N) {
                kv[(size_t)n * D + j] = (unsigned int)f2bf(kval)
                                      | ((unsigned int)f2bf(vval) << 16);
                if (!(lane & 1)) {
                    unsigned int qw = (unsigned int)f2bf(qval)
                                    | ((unsigned int)f2bf(qpart) << 16);
                    *(unsigned int*)(qt + (size_t)n * D + j) = qw;
                }
            }
        }
    }

    // fused row norms: 4 independent shuffle chains interleaved
    for (int rr = 0; rr < 16; rr += 4) {
        float s0, s1, s2, s3;
        {
            unsigned int u0 = *(const unsigned int*)&hA[(w * 16 + rr + 0) * ASTR + lane * 2];
            unsigned int u1 = *(const unsigned int*)&hA[(w * 16 + rr + 1) * ASTR + lane * 2];
            unsigned int u2 = *(const unsigned int*)&hA[(w * 16 + rr + 2) * ASTR + lane * 2];
            unsigned int u3 = *(const unsigned int*)&hA[(w * 16 + rr + 3) * ASTR + lane * 2];
            float a, b;
            a = bf2f(u0); b = bf2f_hi(u0); s0 = a * a + b * b;
            a = bf2f(u1); b = bf2f_hi(u1); s1 = a * a + b * b;
            a = bf2f(u2); b = bf2f_hi(u2); s2 = a * a + b * b;
            a = bf2f(u3); b = bf2f_hi(u3); s3 = a * a + b * b;
        }
#pragma unroll
        for (int off = 1; off < 64; off <<= 1) {
            s0 += __shfl_xor(s0, off);
            s1 += __shfl_xor(s1, off);
            s2 += __shfl_xor(s2, off);
            s3 += __shfl_xor(s3, off);
        }
        if (lane < 4) {
            float sv = (lane == 0) ? s0 : (lane == 1) ? s1 : (lane == 2) ? s2 : s3;
            int n = row0 + w * 16 + rr + lane;
            if (n < N) inv_norm[n] = 1.0f / fmaxf(sqrtf(sv), 1e-12f);
        }
    }
}

// ---------------------------------------------------------------------------
__global__ void deg_hist_kernel(const int* __restrict__ src, const int* __restrict__ dst,
                                int* __restrict__ cnt_src, int* __restrict__ cnt_dst, int E)
{
    int e = blockIdx.x * blockDim.x + threadIdx.x;
    if (e >= E) return;
    atomicAdd(&cnt_src[src[e]], 1);
    atomicAdd(&cnt_dst[dst[e]], 1);
}

// ---------------------------------------------------------------------------
// Coalesced single-block scan: rowptr = exclusive_scan(cnt_dst); also emits
// deg[i] = cnt_src[i]+cnt_dst[i], zero-degree count -> flags.
// ---------------------------------------------------------------------------
__global__ __launch_bounds__(1024) void scan_kernel(
    const int* __restrict__ cnt_src, const int* __restrict__ cnt_dst,
    int* __restrict__ rowptr, int* __restrict__ deg,
    const float* __restrict__ fsb, float* __restrict__ flags, int N)
{
    __shared__ int wtot[16];
    __shared__ int wscan[16];
    int tid = threadIdx.x, lane = tid & 63, wv = tid >> 6;
    int running = 0, zc = 0;
    for (int base = 0; base < N; base += 1024) {
        int i = base + tid;
        int cs = 0, cd = 0;
        if (i < N) { cs = cnt_src[i]; cd = cnt_dst[i]; }
        int x = cd;
        for (int off = 1; off < 64; off <<= 1) {
            int y = __shfl_up(x, off);
            if (lane >= off) x += y;
        }
        if (lane == 63) wtot[wv] = x;
        __syncthreads();
        if (wv == 0) {
            int t = (lane < 16) ? wtot[lane] : 0;
            for (int off = 1; off < 16; off <<= 1) {
                int y = __shfl_up(t, off);
                if (lane >= off) t += y;
            }
            if (lane < 16) wscan[lane] = t;
        }
        __syncthreads();
        int woff = (wv == 0) ? 0 : wscan[wv - 1];
        if (i < N) {
            rowptr[i] = running + woff + x - cd;
            int ds = cs + cd;
            deg[i] = ds;
            zc += (ds == 0) ? 1 : 0;
        }
        running += wscan[15];
        __syncthreads();
    }
    if (tid == 0) rowptr[N] = running;
    for (int off = 1; off < 64; off <<= 1) zc += __shfl_xor(zc, off);
    if (lane == 0) wtot[wv] = zc;
    __syncthreads();
    if (tid == 0) {
        int z = 0;
        for (int k = 0; k < 16; k++) z += wtot[k];
        float sparsity = (float)z / (float)N;
        flags[0] = (sparsity > 0.3f) ? fsb[0] : 0.f;   // boost value
        flags[1] = fmaxf((float)(N - z), 1.f);         // non-zero-deg node count
    }
}

// ---------------------------------------------------------------------------
__global__ void scatter_kernel(const int* __restrict__ src, const int* __restrict__ dst,
                               const int* __restrict__ rowptr, int* __restrict__ cursor,
                               int* __restrict__ esrc, int E)
{
    int e = blockIdx.x * blockDim.x + threadIdx.x;
    if (e >= E) return;
    int d = dst[e];
    int pos = rowptr[d] + atomicAdd(&cursor[d], 1);
    esrc[pos] = src[e];
}

// ---------------------------------------------------------------------------
// Fused softmax + aggregation, gather-based, ZERO atomics, unroll-4.
// One wave per dst node; lane l holds elements {2l, 2l+1} (head = l>>4).
// agg written as packed bf16 (low=col 2l, high=col 2l+1).
// ---------------------------------------------------------------------------
__global__ __launch_bounds__(256) void dst_agg_kernel(
    const unsigned int* __restrict__ kv, const unsigned short* __restrict__ qt,
    const float* __restrict__ h, const float* __restrict__ inv_norm,
    const int* __restrict__ rowptr, const int* __restrict__ esrc,
    const float* __restrict__ flags,
    unsigned int* __restrict__ agg, int N)
{
    int n = (blockIdx.x * blockDim.x + threadIdx.x) >> 6;
    int lane = threadIdx.x & 63;
    if (n >= N) return;
    int beg = rowptr[n], end = rowptr[n + 1];
    unsigned int q2 = *(const unsigned int*)(qt + (size_t)n * D + lane * 2);
    float q0 = bf2f(q2), q1 = bf2f_hi(q2);
    float boost = flags[0];
    float hn0 = 0.f, hn1 = 0.f, innd = 0.f;
    if (boost != 0.f) {
        float2 hh = *(const float2*)(h + (size_t)n * D + lane * 2);
        hn0 = hh.x; hn1 = hh.y; innd = inv_norm[n];
    }
    const float SC = 0.17677669529663687f;   // 1/sqrt(32)
    float acc0 = 0.f, acc1 = 0.f, den = 0.f;
    int i = beg;
    for (; i + 3 < end; i += 4) {
        int s0 = esrc[i], s1 = esrc[i + 1], s2 = esrc[i + 2], s3 = esrc[i + 3];
        uint2 w0 = *(const uint2*)(kv + (size_t)s0 * D + lane * 2);
        uint2 w1 = *(const uint2*)(kv + (size_t)s1 * D + lane * 2);
        uint2 w2 = *(const uint2*)(kv + (size_t)s2 * D + lane * 2);
        uint2 w3 = *(const uint2*)(kv + (size_t)s3 * D + lane * 2);
        float d0 = q0 * bf2f(w0.x) + q1 * bf2f(w0.y);
        float d1 = q0 * bf2f(w1.x) + q1 * bf2f(w1.y);
        float d2 = q0 * bf2f(w2.x) + q1 * bf2f(w2.y);
        float d3 = q0 * bf2f(w3.x) + q1 * bf2f(w3.y);
#pragma unroll
        for (int off = 1; off < 16; off <<= 1) {
            d0 += __shfl_xor(d0, off);
            d1 += __shfl_xor(d1, off);
            d2 += __shfl_xor(d2, off);
            d3 += __shfl_xor(d3, off);
        }
        float a0 = d0 * SC, a1 = d1 * SC, a2 = d2 * SC, a3 = d3 * SC;
        if (boost != 0.f) {   // wave-uniform, off when sparsity <= 0.3
            float2 x0 = *(const float2*)(h + (size_t)s0 * D + lane * 2);
            float2 x1 = *(const float2*)(h + (size_t)s1 * D + lane * 2);
            float2 x2 = *(const float2*)(h + (size_t)s2 * D + lane * 2);
            float2 x3 = *(const float2*)(h + (size_t)s3 * D + lane * 2);
            float f0 = hn0 * x0.x + hn1 * x0.y;
            float f1 = hn0 * x1.x + hn1 * x1.y;
            float f2 = hn0 * x2.x + hn1 * x2.y;
            float f3 = hn0 * x3.x + hn1 * x3.y;
#pragma unroll
            for (int off = 1; off < 64; off <<= 1) {
                f0 += __shfl_xor(f0, off);
                f1 += __shfl_xor(f1, off);
                f2 += __shfl_xor(f2, off);
                f3 += __shfl_xor(f3, off);
            }
            a0 += f0 * inv_norm[s0] * innd * boost;
            a1 += f1 * inv_norm[s1] * innd * boost;
            a2 += f2 * inv_norm[s2] * innd * boost;
            a3 += f3 * inv_norm[s3] * innd * boost;
        }
        a0 = fminf(fmaxf(a0, -60.f), 60.f);
        a1 = fminf(fmaxf(a1, -60.f), 60.f);
        a2 = fminf(fmaxf(a2, -60.f), 60.f);
        a3 = fminf(fmaxf(a3, -60.f), 60.f);
        float p0 = __expf(a0), p1 = __expf(a1), p2 = __expf(a2), p3 = __expf(a3);
        den  += (p0 + p1) + (p2 + p3);
        acc0 += p0 * bf2f_hi(w0.x) + p1 * bf2f_hi(w1.x)
              + p2 * bf2f_hi(w2.x) + p3 * bf2f_hi(w3.x);
        acc1 += p0 * bf2f_hi(w0.y) + p1 * bf2f_hi(w1.y)
              + p2 * bf2f_hi(w2.y) + p3 * bf2f_hi(w3.y);
    }
    for (; i < end; i++) {
        int s0 = esrc[i];
        uint2 w0 = *(const uint2*)(kv + (size_t)s0 * D + lane * 2);
        float d0 = q0 * bf2f(w0.x) + q1 * bf2f(w0.y);
#pragma unroll
        for (int off = 1; off < 16; off <<= 1) d0 += __shfl_xor(d0, off);
        float a0 = d0 * SC;
        if (boost != 0.f) {
            float2 x0 = *(const float2*)(h + (size_t)s0 * D + lane * 2);
            float f0 = hn0 * x0.x + hn1 * x0.y;
#pragma unroll
            for (int off = 1; off < 64; off <<= 1) f0 += __shfl_xor(f0, off);
            a0 += f0 * inv_norm[s0] * innd * boost;
        }
        a0 = fminf(fmaxf(a0, -60.f), 60.f);
        float p0 = __expf(a0);
        den  += p0;
        acc0 += p0 * bf2f_hi(w0.x);
        acc1 += p0 * bf2f_hi(w0.y);
    }
    float r = 1.0f / fmaxf(den, 1e-38f);
    agg[(size_t)n * D / 2 + lane] = (unsigned int)f2bf(acc0 * r)
                                  | ((unsigned int)f2bf(acc1 * r) << 16);
}

// ---------------------------------------------------------------------------
// out = LN(agg @ Wa + ba) via MFMA.  64 rows/block, 4 waves; wave w owns
// rows w*16..w*16+15 (LDS os rows are wave-exclusive -> no barrier).
// ---------------------------------------------------------------------------
#define OSTR 132
__global__ __launch_bounds__(256) void out_ln_kernel(
    const unsigned int* __restrict__ agg,      // packed bf16 pairs
    const unsigned short* __restrict__ WaT, const float* __restrict__ ba,
    const float* __restrict__ ln_g, const float* __restrict__ ln_b,
    const int* __restrict__ deg, float* __restrict__ out,
    float* __restrict__ gcpart, int N)
{
    __shared__ unsigned short aB[64 * ASTR];
    __shared__ float os[64][OSTR];
    int row0 = blockIdx.x * 64;
    int tid = threadIdx.x;
    // stage agg (already bf16-packed): pure uint4 copy, 16B per thread-iter
    for (int i = tid; i < 64 * 16; i += 256) {
        int r = i >> 4, c8 = (i & 15) << 3;   // 8 cols per iter
        int n = row0 + r;
        uint4 v = make_uint4(0u, 0u, 0u, 0u);
        if (n < N) v = *(const uint4*)(agg + (size_t)n * D / 2 + (c8 >> 1));
        *(uint4*)&aB[r * ASTR + c8] = v;
    }
    __syncthreads();
    int lane = tid & 63, w = tid >> 6;
    int m = lane & 15, quad = lane >> 4;

    short8 afrag[4];
    const unsigned short* ab = &aB[(w * 16 + m) * ASTR + quad * 8];
#pragma unroll
    for (int c = 0; c < 4; c++)
        afrag[c] = *(const short8*)(ab + c * 32);

#pragma unroll 1
    for (int t = 0; t < 8; t++) {
        const unsigned short* bb = WaT + ((size_t)(t * 16 + m)) * D + quad * 8;
        short8 b0 = *(const short8*)(bb);
        short8 b1 = *(const short8*)(bb + 32);
        short8 b2 = *(const short8*)(bb + 64);
        short8 b3 = *(const short8*)(bb + 96);
        floatx4 acc = (floatx4){0.f, 0.f, 0.f, 0.f};
        acc = __builtin_amdgcn_mfma_f32_16x16x32_bf16(afrag[0], b0, acc, 0, 0, 0);
        acc = __builtin_amdgcn_mfma_f32_16x16x32_bf16(afrag[1], b1, acc, 0, 0, 0);
        acc = __builtin_amdgcn_mfma_f32_16x16x32_bf16(afrag[2], b2, acc, 0, 0, 0);
        acc = __builtin_amdgcn_mfma_f32_16x16x32_bf16(afrag[3], b3, acc, 0, 0, 0);
        int j = t * 16 + m;
        float bj = ba[j];
#pragma unroll
        for (int r = 0; r < 4; r++)
            os[w * 16 + quad * 4 + r][j] = acc[r] + bj;
    }
    // LN phase: wave w reads only its own rows (written by itself, in order)
    int j2 = lane * 2;
    float g0 = ln_g[j2], g1 = ln_g[j2 + 1];
    float b0 = ln_b[j2], b1 = ln_b[j2 + 1];
    float gcs0 = 0.f, gcs1 = 0.f;
    for (int rr = 0; rr < 16; rr++) {
        int r = w * 16 + rr;
        int n = row0 + r;
        if (n >= N) break;
        float x0 = os[r][j2], x1 = os[r][j2 + 1];
        float s = x0 + x1, s2 = x0 * x0 + x1 * x1;
#pragma unroll
        for (int off = 1; off < 64; off <<= 1) {
            s  += __shfl_xor(s, off);
            s2 += __shfl_xor(s2, off);
        }
        float mu = s * (1.f / 128.f);
        float var = s2 * (1.f / 128.f) - mu * mu;
        float rstd = rsqrtf(fmaxf(var, 0.f) + 1e-5f);
        float y0 = (x0 - mu) * rstd * g0 + b0;
        float y1 = (x1 - mu) * rstd * g1 + b1;
        *(float2*)(out + (size_t)n * D + j2) = make_float2(y0, y1);
        if (deg[n] != 0) { gcs0 += y0; gcs1 += y1; }
    }
    int slot = blockIdx.x & 63;
    if (gcs0 != 0.f || gcs1 != 0.f) {
        atomicAdd(&gcpart[slot * D + j2],     gcs0);
        atomicAdd(&gcpart[slot * D + j2 + 1], gcs1);
    }
}

__global__ void gc_final_kernel(const float* __restrict__ gcpart,
                                const float* __restrict__ flags,
                                float* __restrict__ gc)
{
    int j = threadIdx.x;  // 128
    float s = 0.f;
    for (int i = 0; i < 64; i++) s += gcpart[i * D + j];
    gc[j] = s / flags[1];
}

// ---------------------------------------------------------------------------
// Zero-degree fixup: one thread per NODE (zero-deg set is typically empty).
// ---------------------------------------------------------------------------
__global__ void fixup_kernel(const float* __restrict__ h,
                             const int* __restrict__ deg,
                             const float* __restrict__ gc,
                             float* __restrict__ out, int N)
{
    int n = blockIdx.x * blockDim.x + threadIdx.x;
    if (n >= N) return;
    if (deg[n] != 0) return;
    for (int j = 0; j < D; j += 4) {
        float4 hv = *(const float4*)(h + (size_t)n * D + j);
        float4 gv = *(const float4*)(gc + j);
        float4 o;
        o.x = 0.9f * hv.x + 0.1f * gv.x;
        o.y = 0.9f * hv.y + 0.1f * gv.y;
        o.z = 0.9f * hv.z + 0.1f * gv.z;
        o.w = 0.9f * hv.w + 0.1f * gv.w;
        *(float4*)(out + (size_t)n * D + j) = o;
    }
}

// ---------------------------------------------------------------------------
extern "C" void kernel_launch(void* const* d_in, const int* in_sizes, int n_in,
                              void* d_out, int out_size, void* d_ws, size_t ws_size,
                              hipStream_t stream)
{
    const float* h       = (const float*)d_in[0];
    const int* src_idx   = (const int*)d_in[1];
    const int* dst_idx   = (const int*)d_in[2];
    const float* Wk      = (const float*)d_in[3];
    const float* bk      = (const float*)d_in[4];
    const float* Wq      = (const float*)d_in[5];
    const float* bq      = (const float*)d_in[6];
    const float* Wv      = (const float*)d_in[7];
    const float* bv      = (const float*)d_in[8];
    const float* rk      = (const float*)d_in[9];
    const float* rq      = (const float*)d_in[10];
    const float* rv      = (const float*)d_in[11];
    const float* Wa      = (const float*)d_in[12];
    const float* ba      = (const float*)d_in[13];
    const float* ln_g    = (const float*)d_in[14];
    const float* ln_b    = (const float*)d_in[15];
    const float* fsb     = (const float*)d_in[16];
    float* out           = (float*)d_out;

    int N = in_sizes[0] / D;
    int E = in_sizes[1];

    // ---- workspace: small control buffers first ---------------------------
    char* p = (char*)d_ws;
    auto alloc = [&](size_t bytes) { char* q = p; p += (bytes + 15) & ~(size_t)15; return q; };

    unsigned short* WpT = (unsigned short*)alloc(3 * D * D * 2);   // bf16 transposed
    unsigned short* WaT = (unsigned short*)alloc(D * D * 2);       // bf16 transposed
    float* bp       = (float*)alloc(3 * D * 4);
    float* gc       = (float*)alloc(D * 4);
    float* flags    = (float*)alloc(2 * 4);
    float* inv_norm = (float*)alloc((size_t)N * 4);
    int*   rowptr   = (int*)alloc(((size_t)N + 1) * 4);
    int*   deg      = (int*)alloc((size_t)N * 4);       // written by scan (no memset)
    // zero region: cnt_src, cnt_dst, cursor, gcpart (contiguous)
    char* z1 = p;
    int*   cnt_src = (int*)alloc((size_t)N * 4);
    int*   cnt_dst = (int*)alloc((size_t)N * 4);
    int*   cursor  = (int*)alloc((size_t)N * 4);
    float* gcpart  = (float*)alloc(64 * D * 4);
    size_t z1_bytes = (size_t)(p - z1);
    // big arrays
    unsigned short* qt = (unsigned short*)alloc((size_t)N * D * 2);
    unsigned int*   kv = (unsigned int*)alloc((size_t)N * D * 4);   // packed k|v
    int*   esrc        = (int*)alloc((size_t)E * 4);
    unsigned int* agg  = (unsigned int*)alloc((size_t)N * D * 2);   // packed bf16 pairs

    hipMemsetAsync(z1, 0, z1_bytes, stream);

    prep_weights_kernel<<<dim3(129, 3), 128, 0, stream>>>(Wk, bk, Wq, bq, Wv, bv,
                                                          rk, rq, rv, WpT, bp);
    prep_wa_kernel<<<D, D, 0, stream>>>(Wa, WaT);
    gemm_mfma_kernel<<<(N + 63) / 64, 256, 0, stream>>>(h, WpT, bp, qt, kv,
                                                        inv_norm, N);
    deg_hist_kernel<<<(E + 255) / 256, 256, 0, stream>>>(src_idx, dst_idx,
                                                         cnt_src, cnt_dst, E);
    scan_kernel<<<1, 1024, 0, stream>>>(cnt_src, cnt_dst, rowptr, deg, fsb, flags, N);
    scatter_kernel<<<(E + 255) / 256, 256, 0, stream>>>(src_idx, dst_idx, rowptr,
                                                        cursor, esrc, E);
    dst_agg_kernel<<<(N + 3) / 4, 256, 0, stream>>>(kv, qt, h, inv_norm,
                                                    rowptr, esrc, flags, agg, N);
    out_ln_kernel<<<(N + 63) / 64, 256, 0, stream>>>(agg, WaT, ba, ln_g, ln_b,
                                                     deg, out, gcpart, N);
    gc_final_kernel<<<1, D, 0, stream>>>(gcpart, flags, gc);
    fixup_kernel<<<(N + 255) / 256, 256, 0, stream>>>(h, deg, gc, out, N);
}

// Round 9
// 352.958 us; speedup vs baseline: 4.9306x; 1.1205x over previous
//
#include <hip/hip_runtime.h>

#define D 128
#define NH 4
#define DKH 32

typedef __attribute__((ext_vector_type(8))) short short8;
typedef __attribute__((ext_vector_type(4))) float floatx4;

__device__ __forceinline__ float bf2f(unsigned int u) {
    return __uint_as_float((u & 0xffffu) << 16);
}
__device__ __forceinline__ float bf2f_hi(unsigned int u) {
    return __uint_as_float(u & 0xffff0000u);
}
__device__ __forceinline__ unsigned short f2bf(float f) {
    unsigned int x = __float_as_uint(f);
    x += 0x7fffu + ((x >> 16) & 1u);
    return (unsigned short)(x >> 16);
}

// ---------------------------------------------------------------------------
// Fold rel_{k,q,v} into W,b -> WpT (bf16 transposed); w==3 transposes Wa.
// grid (129, 4): x<128 -> weight row i, x==128 -> bias; block 128 (out col j).
// ---------------------------------------------------------------------------
__global__ void prep_weights_kernel(
    const float* __restrict__ Wk, const float* __restrict__ bk,
    const float* __restrict__ Wq, const float* __restrict__ bq,
    const float* __restrict__ Wv, const float* __restrict__ bv,
    const float* __restrict__ rk, const float* __restrict__ rq,
    const float* __restrict__ rv, const float* __restrict__ Wa,
    unsigned short* __restrict__ WpT, unsigned short* __restrict__ WaT,
    float* __restrict__ bp)
{
    int w = blockIdx.y;
    int j = threadIdx.x;            // output column 0..127
    int i = blockIdx.x;
    if (w == 3) {                   // Wa transpose (no rel fold; ba stays fp32)
        if (i < D) WaT[(size_t)j * D + i] = f2bf(Wa[(size_t)i * D + j]);
        return;
    }
    const float* W   = (w == 0) ? Wk : (w == 1) ? Wq : Wv;
    const float* b   = (w == 0) ? bk : (w == 1) ? bq : bv;
    const float* rel = (w == 0) ? rk : (w == 1) ? rq : rv;
    int h = j >> 5, f = j & 31;
    float acc = 0.f;
    if (i < D) {
        for (int dd = 0; dd < DKH; dd++)
            acc += W[i * D + h * DKH + dd] * rel[h * 1024 + dd * DKH + f];
        WpT[((size_t)(w * D + j)) * D + i] = f2bf(acc);
    } else {
        for (int dd = 0; dd < DKH; dd++)
            acc += b[h * DKH + dd] * rel[h * 1024 + dd * DKH + f];
        bp[w * D + j] = acc;
    }
}

// ---------------------------------------------------------------------------
// MFMA GEMM: [qt | kv] = h @ W'{k,q,v} + b', plus fused row norms.
// 64 rows/block, 4 waves; 8 non-unrolled triplet iterations (12 live accs).
// Layouts (verified r6): A[m=lane&15][k=quad*8+j], B row = out col,
// C/D col=lane&15, row=quad*4+reg.
// ---------------------------------------------------------------------------
#define ASTR 136
__global__ __launch_bounds__(256) void gemm_mfma_kernel(
    const float* __restrict__ h, const unsigned short* __restrict__ WpT,
    const float* __restrict__ bp,
    unsigned short* __restrict__ qt, unsigned int* __restrict__ kv,
    float* __restrict__ inv_norm, int N)
{
    __shared__ unsigned short hA[64 * ASTR];
    int row0 = blockIdx.x * 64;
    int tid = threadIdx.x;
    for (int i = tid; i < 64 * 32; i += 256) {
        int r = i >> 5, c4 = (i & 31) << 2;
        int n = row0 + r;
        float4 v = make_float4(0.f, 0.f, 0.f, 0.f);
        if (n < N) v = *(const float4*)(h + (size_t)n * D + c4);
        ushort4 bv4;
        bv4.x = f2bf(v.x); bv4.y = f2bf(v.y); bv4.z = f2bf(v.z); bv4.w = f2bf(v.w);
        *(ushort4*)&hA[r * ASTR + c4] = bv4;
    }
    __syncthreads();
    int lane = tid & 63, w = tid >> 6;
    int m = lane & 15, quad = lane >> 4;

    short8 afrag[4];
    const unsigned short* ab = &hA[(w * 16 + m) * ASTR + quad * 8];
#pragma unroll
    for (int c = 0; c < 4; c++)
        afrag[c] = *(const short8*)(ab + c * 32);

#pragma unroll 1
    for (int t = 0; t < 8; t++) {
        const unsigned short* kb = WpT + ((size_t)(t * 16 + m)) * D + quad * 8;
        const unsigned short* qb = kb + (size_t)D * D;
        const unsigned short* vb = kb + (size_t)2 * D * D;
        short8 k0 = *(const short8*)(kb);
        short8 k1 = *(const short8*)(kb + 32);
        short8 k2 = *(const short8*)(kb + 64);
        short8 k3 = *(const short8*)(kb + 96);
        short8 q0 = *(const short8*)(qb);
        short8 q1 = *(const short8*)(qb + 32);
        short8 q2 = *(const short8*)(qb + 64);
        short8 q3 = *(const short8*)(qb + 96);
        short8 v0 = *(const short8*)(vb);
        short8 v1 = *(const short8*)(vb + 32);
        short8 v2 = *(const short8*)(vb + 64);
        short8 v3 = *(const short8*)(vb + 96);
        floatx4 aK = (floatx4){0.f, 0.f, 0.f, 0.f};
        floatx4 aQ = (floatx4){0.f, 0.f, 0.f, 0.f};
        floatx4 aV = (floatx4){0.f, 0.f, 0.f, 0.f};
        aK = __builtin_amdgcn_mfma_f32_16x16x32_bf16(afrag[0], k0, aK, 0, 0, 0);
        aQ = __builtin_amdgcn_mfma_f32_16x16x32_bf16(afrag[0], q0, aQ, 0, 0, 0);
        aV = __builtin_amdgcn_mfma_f32_16x16x32_bf16(afrag[0], v0, aV, 0, 0, 0);
        aK = __builtin_amdgcn_mfma_f32_16x16x32_bf16(afrag[1], k1, aK, 0, 0, 0);
        aQ = __builtin_amdgcn_mfma_f32_16x16x32_bf16(afrag[1], q1, aQ, 0, 0, 0);
        aV = __builtin_amdgcn_mfma_f32_16x16x32_bf16(afrag[1], v1, aV, 0, 0, 0);
        aK = __builtin_amdgcn_mfma_f32_16x16x32_bf16(afrag[2], k2, aK, 0, 0, 0);
        aQ = __builtin_amdgcn_mfma_f32_16x16x32_bf16(afrag[2], q2, aQ, 0, 0, 0);
        aV = __builtin_amdgcn_mfma_f32_16x16x32_bf16(afrag[2], v2, aV, 0, 0, 0);
        aK = __builtin_amdgcn_mfma_f32_16x16x32_bf16(afrag[3], k3, aK, 0, 0, 0);
        aQ = __builtin_amdgcn_mfma_f32_16x16x32_bf16(afrag[3], q3, aQ, 0, 0, 0);
        aV = __builtin_amdgcn_mfma_f32_16x16x32_bf16(afrag[3], v3, aV, 0, 0, 0);
        int j = t * 16 + m;
        float bk = bp[j], bq = bp[D + j], bvs = bp[2 * D + j];
#pragma unroll
        for (int r = 0; r < 4; r++) {
            int n = row0 + w * 16 + quad * 4 + r;
            float kval = aK[r] + bk;
            float qval = aQ[r] + bq;
            float vval = aV[r] + bvs;
            float qpart = __shfl_xor(qval, 1);
            if (n < N) {
                kv[(size_t)n * D + j] = (unsigned int)f2bf(kval)
                                      | ((unsigned int)f2bf(vval) << 16);
                if (!(lane & 1)) {
                    unsigned int qw = (unsigned int)f2bf(qval)
                                    | ((unsigned int)f2bf(qpart) << 16);
                    *(unsigned int*)(qt + (size_t)n * D + j) = qw;
                }
            }
        }
    }

    // fused row norms: 4 independent shuffle chains interleaved
    for (int rr = 0; rr < 16; rr += 4) {
        float s0, s1, s2, s3;
        {
            unsigned int u0 = *(const unsigned int*)&hA[(w * 16 + rr + 0) * ASTR + lane * 2];
            unsigned int u1 = *(const unsigned int*)&hA[(w * 16 + rr + 1) * ASTR + lane * 2];
            unsigned int u2 = *(const unsigned int*)&hA[(w * 16 + rr + 2) * ASTR + lane * 2];
            unsigned int u3 = *(const unsigned int*)&hA[(w * 16 + rr + 3) * ASTR + lane * 2];
            float a, b;
            a = bf2f(u0); b = bf2f_hi(u0); s0 = a * a + b * b;
            a = bf2f(u1); b = bf2f_hi(u1); s1 = a * a + b * b;
            a = bf2f(u2); b = bf2f_hi(u2); s2 = a * a + b * b;
            a = bf2f(u3); b = bf2f_hi(u3); s3 = a * a + b * b;
        }
#pragma unroll
        for (int off = 1; off < 64; off <<= 1) {
            s0 += __shfl_xor(s0, off);
            s1 += __shfl_xor(s1, off);
            s2 += __shfl_xor(s2, off);
            s3 += __shfl_xor(s3, off);
        }
        if (lane < 4) {
            float sv = (lane == 0) ? s0 : (lane == 1) ? s1 : (lane == 2) ? s2 : s3;
            int n = row0 + w * 16 + rr + lane;
            if (n < N) inv_norm[n] = 1.0f / fmaxf(sqrtf(sv), 1e-12f);
        }
    }
}

// ---------------------------------------------------------------------------
__global__ void deg_hist_kernel(const int* __restrict__ src, const int* __restrict__ dst,
                                int* __restrict__ cnt_src, int* __restrict__ cnt_dst, int E)
{
    int e = blockIdx.x * blockDim.x + threadIdx.x;
    if (e >= E) return;
    atomicAdd(&cnt_src[src[e]], 1);
    atomicAdd(&cnt_dst[dst[e]], 1);
}

// ---------------------------------------------------------------------------
// CSR scan, phase 1: per-1024-block local exclusive scan of cnt_dst,
// block totals, deg[], zero-degree count.
// ---------------------------------------------------------------------------
__global__ __launch_bounds__(1024) void scan_blocks_kernel(
    const int* __restrict__ cnt_src, const int* __restrict__ cnt_dst,
    int* __restrict__ rowptr, int* __restrict__ deg,
    int* __restrict__ btot, int* __restrict__ zcount, int N)
{
    __shared__ int wtot[16];
    __shared__ int wscan[16];
    int tid = threadIdx.x, lane = tid & 63, wv = tid >> 6;
    int i = blockIdx.x * 1024 + tid;
    int cs = 0, cd = 0;
    if (i < N) { cs = cnt_src[i]; cd = cnt_dst[i]; }
    int x = cd;
#pragma unroll
    for (int off = 1; off < 64; off <<= 1) {
        int y = __shfl_up(x, off);
        if (lane >= off) x += y;
    }
    if (lane == 63) wtot[wv] = x;
    __syncthreads();
    if (wv == 0) {
        int t = (lane < 16) ? wtot[lane] : 0;
#pragma unroll
        for (int off = 1; off < 16; off <<= 1) {
            int y = __shfl_up(t, off);
            if (lane >= off) t += y;
        }
        if (lane < 16) wscan[lane] = t;
    }
    __syncthreads();
    int woff = (wv == 0) ? 0 : wscan[wv - 1];
    if (i < N) {
        rowptr[i] = woff + x - cd;     // block-local exclusive prefix
        deg[i] = cs + cd;
    }
    if (tid == 0) btot[blockIdx.x] = wscan[15];
    int zc = (i < N && (cs + cd) == 0) ? 1 : 0;
#pragma unroll
    for (int off = 1; off < 64; off <<= 1) zc += __shfl_xor(zc, off);
    if (lane == 0 && zc) atomicAdd(zcount, zc);
}

// ---------------------------------------------------------------------------
// CSR scan, phase 2: scan block totals (nb <= 64), emit boff, rowptr[N]=E,
// and flags from zcount.
// ---------------------------------------------------------------------------
__global__ void scan_final_kernel(const int* __restrict__ btot,
                                  int* __restrict__ boff, int* __restrict__ rowptr,
                                  const int* __restrict__ zcount,
                                  const float* __restrict__ fsb,
                                  float* __restrict__ flags, int N, int nb)
{
    int lane = threadIdx.x;   // 64
    int v = (lane < nb) ? btot[lane] : 0;
    int x = v;
#pragma unroll
    for (int off = 1; off < 64; off <<= 1) {
        int y = __shfl_up(x, off);
        if (lane >= off) x += y;
    }
    if (lane < nb) boff[lane] = x - v;
    if (lane == 63) rowptr[N] = x;    // grand total = E
    if (lane == 0) {
        float z = (float)zcount[0];
        float sparsity = z / (float)N;
        flags[0] = (sparsity > 0.3f) ? fsb[0] : 0.f;   // boost value
        flags[1] = fmaxf((float)N - z, 1.f);           // non-zero-deg node count
    }
}

// CSR scan, phase 3: add block offsets.
__global__ void scan_add_kernel(int* __restrict__ rowptr,
                                const int* __restrict__ boff, int N)
{
    int i = blockIdx.x * blockDim.x + threadIdx.x;
    if (i < N) rowptr[i] += boff[i >> 10];
}

// ---------------------------------------------------------------------------
__global__ void scatter_kernel(const int* __restrict__ src, const int* __restrict__ dst,
                               const int* __restrict__ rowptr, int* __restrict__ cursor,
                               int* __restrict__ esrc, int E)
{
    int e = blockIdx.x * blockDim.x + threadIdx.x;
    if (e >= E) return;
    int d = dst[e];
    int pos = rowptr[d] + atomicAdd(&cursor[d], 1);
    esrc[pos] = src[e];
}

// ---------------------------------------------------------------------------
// Fused softmax + aggregation, gather-based, ZERO atomics.
// One wave per dst node, 2 edges per wave (32 lanes/edge), uint4 gathers.
// Lane c (0..31) of each half covers columns 4c..4c+3; head = c>>3.
// Cross-half combine via shfl_xor(.,32) at the end.
// ---------------------------------------------------------------------------
__global__ __launch_bounds__(256) void dst_agg_kernel(
    const unsigned int* __restrict__ kv, const unsigned short* __restrict__ qt,
    const float* __restrict__ h, const float* __restrict__ inv_norm,
    const int* __restrict__ rowptr, const int* __restrict__ esrc,
    const float* __restrict__ flags,
    unsigned int* __restrict__ agg, int N)
{
    int n = (blockIdx.x * blockDim.x + threadIdx.x) >> 6;
    int lane = threadIdx.x & 63;
    if (n >= N) return;
    int half = lane >> 5, c = lane & 31;
    int beg = rowptr[n], end = rowptr[n + 1];
    uint2 qw = *(const uint2*)(qt + (size_t)n * D + c * 4);
    float q0 = bf2f(qw.x), q1 = bf2f_hi(qw.x);
    float q2 = bf2f(qw.y), q3 = bf2f_hi(qw.y);
    float boost = flags[0];
    float hn0 = 0.f, hn1 = 0.f, hn2 = 0.f, hn3 = 0.f, innd = 0.f;
    if (boost != 0.f) {
        float4 hh = *(const float4*)(h + (size_t)n * D + c * 4);
        hn0 = hh.x; hn1 = hh.y; hn2 = hh.z; hn3 = hh.w; innd = inv_norm[n];
    }
    const float SC = 0.17677669529663687f;   // 1/sqrt(32)
    float a0 = 0.f, a1 = 0.f, a2 = 0.f, a3 = 0.f, den = 0.f;
    int i = beg;
    // 2 pairs (4 edges) per iteration: each half handles edges i+half, i+2+half
    for (; i + 3 < end; i += 4) {
        int sA = esrc[i + half];
        int sB = esrc[i + 2 + half];
        uint4 wA = *(const uint4*)(kv + (size_t)sA * D + c * 4);
        uint4 wB = *(const uint4*)(kv + (size_t)sB * D + c * 4);
        float dA = q0 * bf2f(wA.x) + q1 * bf2f(wA.y)
                 + q2 * bf2f(wA.z) + q3 * bf2f(wA.w);
        float dB = q0 * bf2f(wB.x) + q1 * bf2f(wB.y)
                 + q2 * bf2f(wB.z) + q3 * bf2f(wB.w);
        dA += __shfl_xor(dA, 1);  dB += __shfl_xor(dB, 1);
        dA += __shfl_xor(dA, 2);  dB += __shfl_xor(dB, 2);
        dA += __shfl_xor(dA, 4);  dB += __shfl_xor(dB, 4);
        float attA = dA * SC, attB = dB * SC;
        if (boost != 0.f) {   // wave-uniform, off when sparsity <= 0.3
            float4 xA = *(const float4*)(h + (size_t)sA * D + c * 4);
            float4 xB = *(const float4*)(h + (size_t)sB * D + c * 4);
            float fA = hn0 * xA.x + hn1 * xA.y + hn2 * xA.z + hn3 * xA.w;
            float fB = hn0 * xB.x + hn1 * xB.y + hn2 * xB.z + hn3 * xB.w;
#pragma unroll
            for (int off = 1; off < 32; off <<= 1) {
                fA += __shfl_xor(fA, off);
                fB += __shfl_xor(fB, off);
            }
            attA += fA * inv_norm[sA] * innd * boost;
            attB += fB * inv_norm[sB] * innd * boost;
        }
        attA = fminf(fmaxf(attA, -60.f), 60.f);
        attB = fminf(fmaxf(attB, -60.f), 60.f);
        float pA = __expf(attA), pB = __expf(attB);
        den += pA + pB;
        a0 += pA * bf2f_hi(wA.x) + pB * bf2f_hi(wB.x);
        a1 += pA * bf2f_hi(wA.y) + pB * bf2f_hi(wB.y);
        a2 += pA * bf2f_hi(wA.z) + pB * bf2f_hi(wB.z);
        a3 += pA * bf2f_hi(wA.w) + pB * bf2f_hi(wB.w);
    }
    // one remaining pair
    for (; i + 1 < end; i += 2) {
        int sA = esrc[i + half];
        uint4 wA = *(const uint4*)(kv + (size_t)sA * D + c * 4);
        float dA = q0 * bf2f(wA.x) + q1 * bf2f(wA.y)
                 + q2 * bf2f(wA.z) + q3 * bf2f(wA.w);
        dA += __shfl_xor(dA, 1);
        dA += __shfl_xor(dA, 2);
        dA += __shfl_xor(dA, 4);
        float attA = dA * SC;
        if (boost != 0.f) {
            float4 xA = *(const float4*)(h + (size_t)sA * D + c * 4);
            float fA = hn0 * xA.x + hn1 * xA.y + hn2 * xA.z + hn3 * xA.w;
#pragma unroll
            for (int off = 1; off < 32; off <<= 1) fA += __shfl_xor(fA, off);
            attA += fA * inv_norm[sA] * innd * boost;
        }
        attA = fminf(fmaxf(attA, -60.f), 60.f);
        float pA = __expf(attA);
        den += pA;
        a0 += pA * bf2f_hi(wA.x);
        a1 += pA * bf2f_hi(wA.y);
        a2 += pA * bf2f_hi(wA.z);
        a3 += pA * bf2f_hi(wA.w);
    }
    // final single edge: half 0 only
    if (i < end && half == 0) {
        int sA = esrc[i];
        uint4 wA = *(const uint4*)(kv + (size_t)sA * D + c * 4);
        float dA = q0 * bf2f(wA.x) + q1 * bf2f(wA.y)
                 + q2 * bf2f(wA.z) + q3 * bf2f(wA.w);
        dA += __shfl_xor(dA, 1);
        dA += __shfl_xor(dA, 2);
        dA += __shfl_xor(dA, 4);
        float attA = dA * SC;
        if (boost != 0.f) {
            float4 xA = *(const float4*)(h + (size_t)sA * D + c * 4);
            float fA = hn0 * xA.x + hn1 * xA.y + hn2 * xA.z + hn3 * xA.w;
#pragma unroll
            for (int off = 1; off < 32; off <<= 1) fA += __shfl_xor(fA, off);
            attA += fA * inv_norm[sA] * innd * boost;
        }
        attA = fminf(fmaxf(attA, -60.f), 60.f);
        float pA = __expf(attA);
        den += pA;
        a0 += pA * bf2f_hi(wA.x);
        a1 += pA * bf2f_hi(wA.y);
        a2 += pA * bf2f_hi(wA.z);
        a3 += pA * bf2f_hi(wA.w);
    }
    // combine halves
    den += __shfl_xor(den, 32);
    a0  += __shfl_xor(a0, 32);
    a1  += __shfl_xor(a1, 32);
    a2  += __shfl_xor(a2, 32);
    a3  += __shfl_xor(a3, 32);
    if (half == 0) {
        float r = 1.0f / fmaxf(den, 1e-38f);
        uint2 o;
        o.x = (unsigned int)f2bf(a0 * r) | ((unsigned int)f2bf(a1 * r) << 16);
        o.y = (unsigned int)f2bf(a2 * r) | ((unsigned int)f2bf(a3 * r) << 16);
        *(uint2*)(agg + (size_t)n * (D / 2) + c * 2) = o;
    }
}

// ---------------------------------------------------------------------------
// out = LN(agg @ Wa + ba) via MFMA.  64 rows/block, 4 waves; wave w owns
// rows w*16..w*16+15 (LDS os rows are wave-exclusive -> no barrier).
// ---------------------------------------------------------------------------
#define OSTR 132
__global__ __launch_bounds__(256) void out_ln_kernel(
    const unsigned int* __restrict__ agg,      // packed bf16 pairs
    const unsigned short* __restrict__ WaT, const float* __restrict__ ba,
    const float* __restrict__ ln_g, const float* __restrict__ ln_b,
    const int* __restrict__ deg, float* __restrict__ out,
    float* __restrict__ gcpart, int N)
{
    __shared__ unsigned short aB[64 * ASTR];
    __shared__ float os[64][OSTR];
    int row0 = blockIdx.x * 64;
    int tid = threadIdx.x;
    for (int i = tid; i < 64 * 16; i += 256) {
        int r = i >> 4, c8 = (i & 15) << 3;
        int n = row0 + r;
        uint4 v = make_uint4(0u, 0u, 0u, 0u);
        if (n < N) v = *(const uint4*)(agg + (size_t)n * D / 2 + (c8 >> 1));
        *(uint4*)&aB[r * ASTR + c8] = v;
    }
    __syncthreads();
    int lane = tid & 63, w = tid >> 6;
    int m = lane & 15, quad = lane >> 4;

    short8 afrag[4];
    const unsigned short* ab = &aB[(w * 16 + m) * ASTR + quad * 8];
#pragma unroll
    for (int c = 0; c < 4; c++)
        afrag[c] = *(const short8*)(ab + c * 32);

#pragma unroll 1
    for (int t = 0; t < 8; t++) {
        const unsigned short* bb = WaT + ((size_t)(t * 16 + m)) * D + quad * 8;
        short8 b0 = *(const short8*)(bb);
        short8 b1 = *(const short8*)(bb + 32);
        short8 b2 = *(const short8*)(bb + 64);
        short8 b3 = *(const short8*)(bb + 96);
        floatx4 acc = (floatx4){0.f, 0.f, 0.f, 0.f};
        acc = __builtin_amdgcn_mfma_f32_16x16x32_bf16(afrag[0], b0, acc, 0, 0, 0);
        acc = __builtin_amdgcn_mfma_f32_16x16x32_bf16(afrag[1], b1, acc, 0, 0, 0);
        acc = __builtin_amdgcn_mfma_f32_16x16x32_bf16(afrag[2], b2, acc, 0, 0, 0);
        acc = __builtin_amdgcn_mfma_f32_16x16x32_bf16(afrag[3], b3, acc, 0, 0, 0);
        int j = t * 16 + m;
        float bj = ba[j];
#pragma unroll
        for (int r = 0; r < 4; r++)
            os[w * 16 + quad * 4 + r][j] = acc[r] + bj;
    }
    int j2 = lane * 2;
    float g0 = ln_g[j2], g1 = ln_g[j2 + 1];
    float b0 = ln_b[j2], b1 = ln_b[j2 + 1];
    float gcs0 = 0.f, gcs1 = 0.f;
    for (int rr = 0; rr < 16; rr++) {
        int r = w * 16 + rr;
        int n = row0 + r;
        if (n >= N) break;
        float x0 = os[r][j2], x1 = os[r][j2 + 1];
        float s = x0 + x1, s2 = x0 * x0 + x1 * x1;
#pragma unroll
        for (int off = 1; off < 64; off <<= 1) {
            s  += __shfl_xor(s, off);
            s2 += __shfl_xor(s2, off);
        }
        float mu = s * (1.f / 128.f);
        float var = s2 * (1.f / 128.f) - mu * mu;
        float rstd = rsqrtf(fmaxf(var, 0.f) + 1e-5f);
        float y0 = (x0 - mu) * rstd * g0 + b0;
        float y1 = (x1 - mu) * rstd * g1 + b1;
        *(float2*)(out + (size_t)n * D + j2) = make_float2(y0, y1);
        if (deg[n] != 0) { gcs0 += y0; gcs1 += y1; }
    }
    int slot = blockIdx.x & 63;
    if (gcs0 != 0.f || gcs1 != 0.f) {
        atomicAdd(&gcpart[slot * D + j2],     gcs0);
        atomicAdd(&gcpart[slot * D + j2 + 1], gcs1);
    }
}

__global__ void gc_final_kernel(const float* __restrict__ gcpart,
                                const float* __restrict__ flags,
                                float* __restrict__ gc)
{
    int j = threadIdx.x;  // 128
    float s = 0.f;
    for (int i = 0; i < 64; i++) s += gcpart[i * D + j];
    gc[j] = s / flags[1];
}

// ---------------------------------------------------------------------------
__global__ void fixup_kernel(const float* __restrict__ h,
                             const int* __restrict__ deg,
                             const float* __restrict__ gc,
                             float* __restrict__ out, int N)
{
    int n = blockIdx.x * blockDim.x + threadIdx.x;
    if (n >= N) return;
    if (deg[n] != 0) return;
    for (int j = 0; j < D; j += 4) {
        float4 hv = *(const float4*)(h + (size_t)n * D + j);
        float4 gv = *(const float4*)(gc + j);
        float4 o;
        o.x = 0.9f * hv.x + 0.1f * gv.x;
        o.y = 0.9f * hv.y + 0.1f * gv.y;
        o.z = 0.9f * hv.z + 0.1f * gv.z;
        o.w = 0.9f * hv.w + 0.1f * gv.w;
        *(float4*)(out + (size_t)n * D + j) = o;
    }
}

// ---------------------------------------------------------------------------
extern "C" void kernel_launch(void* const* d_in, const int* in_sizes, int n_in,
                              void* d_out, int out_size, void* d_ws, size_t ws_size,
                              hipStream_t stream)
{
    const float* h       = (const float*)d_in[0];
    const int* src_idx   = (const int*)d_in[1];
    const int* dst_idx   = (const int*)d_in[2];
    const float* Wk      = (const float*)d_in[3];
    const float* bk      = (const float*)d_in[4];
    const float* Wq      = (const float*)d_in[5];
    const float* bq      = (const float*)d_in[6];
    const float* Wv      = (const float*)d_in[7];
    const float* bv      = (const float*)d_in[8];
    const float* rk      = (const float*)d_in[9];
    const float* rq      = (const float*)d_in[10];
    const float* rv      = (const float*)d_in[11];
    const float* Wa      = (const float*)d_in[12];
    const float* ba      = (const float*)d_in[13];
    const float* ln_g    = (const float*)d_in[14];
    const float* ln_b    = (const float*)d_in[15];
    const float* fsb     = (const float*)d_in[16];
    float* out           = (float*)d_out;

    int N = in_sizes[0] / D;
    int E = in_sizes[1];
    int nb = (N + 1023) >> 10;   // scan blocks (<= 64)

    // ---- workspace: small control buffers first ---------------------------
    char* p = (char*)d_ws;
    auto alloc = [&](size_t bytes) { char* q = p; p += (bytes + 15) & ~(size_t)15; return q; };

    unsigned short* WpT = (unsigned short*)alloc(3 * D * D * 2);
    unsigned short* WaT = (unsigned short*)alloc(D * D * 2);
    float* bp       = (float*)alloc(3 * D * 4);
    float* gc       = (float*)alloc(D * 4);
    float* flags    = (float*)alloc(2 * 4);
    int*   btot     = (int*)alloc(64 * 4);
    int*   boff     = (int*)alloc(64 * 4);
    float* inv_norm = (float*)alloc((size_t)N * 4);
    int*   rowptr   = (int*)alloc(((size_t)N + 1) * 4);
    int*   deg      = (int*)alloc((size_t)N * 4);
    // zero region: cnt_src, cnt_dst, cursor, zcount, gcpart (contiguous)
    char* z1 = p;
    int*   cnt_src = (int*)alloc((size_t)N * 4);
    int*   cnt_dst = (int*)alloc((size_t)N * 4);
    int*   cursor  = (int*)alloc((size_t)N * 4);
    int*   zcount  = (int*)alloc(4);
    float* gcpart  = (float*)alloc(64 * D * 4);
    size_t z1_bytes = (size_t)(p - z1);
    // big arrays
    unsigned short* qt = (unsigned short*)alloc((size_t)N * D * 2);
    unsigned int*   kv = (unsigned int*)alloc((size_t)N * D * 4);
    int*   esrc        = (int*)alloc((size_t)E * 4);
    unsigned int* agg  = (unsigned int*)alloc((size_t)N * D * 2);

    hipMemsetAsync(z1, 0, z1_bytes, stream);

    prep_weights_kernel<<<dim3(129, 4), 128, 0, stream>>>(Wk, bk, Wq, bq, Wv, bv,
                                                          rk, rq, rv, Wa,
                                                          WpT, WaT, bp);
    gemm_mfma_kernel<<<(N + 63) / 64, 256, 0, stream>>>(h, WpT, bp, qt, kv,
                                                        inv_norm, N);
    deg_hist_kernel<<<(E + 255) / 256, 256, 0, stream>>>(src_idx, dst_idx,
                                                         cnt_src, cnt_dst, E);
    scan_blocks_kernel<<<nb, 1024, 0, stream>>>(cnt_src, cnt_dst, rowptr, deg,
                                                btot, zcount, N);
    scan_final_kernel<<<1, 64, 0, stream>>>(btot, boff, rowptr, zcount, fsb,
                                            flags, N, nb);
    scan_add_kernel<<<(N + 255) / 256, 256, 0, stream>>>(rowptr, boff, N);
    scatter_kernel<<<(E + 255) / 256, 256, 0, stream>>>(src_idx, dst_idx, rowptr,
                                                        cursor, esrc, E);
    dst_agg_kernel<<<(N + 3) / 4, 256, 0, stream>>>(kv, qt, h, inv_norm,
                                                    rowptr, esrc, flags, agg, N);
    out_ln_kernel<<<(N + 63) / 64, 256, 0, stream>>>(agg, WaT, ba, ln_g, ln_b,
                                                     deg, out, gcpart, N);
    gc_final_kernel<<<1, D, 0, stream>>>(gcpart, flags, gc);
    fixup_kernel<<<(N + 255) / 256, 256, 0, stream>>>(h, deg, gc, out, N);
}

// Round 10
// 351.277 us; speedup vs baseline: 4.9541x; 1.0048x over previous
//
#include <hip/hip_runtime.h>

#define D 128
#define NH 4
#define DKH 32

typedef __attribute__((ext_vector_type(8))) short short8;
typedef __attribute__((ext_vector_type(4))) float floatx4;

__device__ __forceinline__ float bf2f(unsigned int u) {
    return __uint_as_float((u & 0xffffu) << 16);
}
__device__ __forceinline__ float bf2f_hi(unsigned int u) {
    return __uint_as_float(u & 0xffff0000u);
}
__device__ __forceinline__ unsigned short f2bf(float f) {
    unsigned int x = __float_as_uint(f);
    x += 0x7fffu + ((x >> 16) & 1u);
    return (unsigned short)(x >> 16);
}

// ---------------------------------------------------------------------------
// Fold rel_{k,q,v} into W,b -> WpT (bf16 transposed); w==3 transposes Wa.
// ---------------------------------------------------------------------------
__global__ void prep_weights_kernel(
    const float* __restrict__ Wk, const float* __restrict__ bk,
    const float* __restrict__ Wq, const float* __restrict__ bq,
    const float* __restrict__ Wv, const float* __restrict__ bv,
    const float* __restrict__ rk, const float* __restrict__ rq,
    const float* __restrict__ rv, const float* __restrict__ Wa,
    unsigned short* __restrict__ WpT, unsigned short* __restrict__ WaT,
    float* __restrict__ bp)
{
    int w = blockIdx.y;
    int j = threadIdx.x;            // output column 0..127
    int i = blockIdx.x;
    if (w == 3) {
        if (i < D) WaT[(size_t)j * D + i] = f2bf(Wa[(size_t)i * D + j]);
        return;
    }
    const float* W   = (w == 0) ? Wk : (w == 1) ? Wq : Wv;
    const float* b   = (w == 0) ? bk : (w == 1) ? bq : bv;
    const float* rel = (w == 0) ? rk : (w == 1) ? rq : rv;
    int h = j >> 5, f = j & 31;
    float acc = 0.f;
    if (i < D) {
        for (int dd = 0; dd < DKH; dd++)
            acc += W[i * D + h * DKH + dd] * rel[h * 1024 + dd * DKH + f];
        WpT[((size_t)(w * D + j)) * D + i] = f2bf(acc);
    } else {
        for (int dd = 0; dd < DKH; dd++)
            acc += b[h * DKH + dd] * rel[h * 1024 + dd * DKH + f];
        bp[w * D + j] = acc;
    }
}

// ---------------------------------------------------------------------------
// MFMA GEMM: [qt | kv] = h @ W'{k,q,v} + b', plus fused row norms.
// 64 rows/block, 4 waves.  K-loop: unroll-2 with double-buffered B frags
// (prefetch t+1 while t computes).  Epilogue writes to LDS (kvb/qtb,
// union-aliased over dead hA); final coalesced full-line uint4 stores.
// Layouts (verified r6): A[m=lane&15][k=quad*8+j], B row = out col,
// C/D col=lane&15, row=quad*4+reg.
// ---------------------------------------------------------------------------
#define ASTR 136
#define KVSTR 130
#define QTSTR 66
__global__ __launch_bounds__(256) void gemm_mfma_kernel(
    const float* __restrict__ h, const unsigned short* __restrict__ WpT,
    const float* __restrict__ bp,
    unsigned short* __restrict__ qt, unsigned int* __restrict__ kv,
    float* __restrict__ inv_norm, int N)
{
    // union: hA (64*ASTR ushort = 17.4 KB) is dead after afrag+norms;
    // kvb (64*KVSTR uint = 33.3 KB) + qtb (64*QTSTR uint = 16.9 KB) = 50.2 KB
    __shared__ unsigned int smem[64 * KVSTR + 64 * QTSTR];
    unsigned short* hA = (unsigned short*)smem;
    unsigned int* kvb = smem;
    unsigned int* qtb = smem + 64 * KVSTR;

    int row0 = blockIdx.x * 64;
    int tid = threadIdx.x;
    for (int i = tid; i < 64 * 32; i += 256) {
        int r = i >> 5, c4 = (i & 31) << 2;
        int n = row0 + r;
        float4 v = make_float4(0.f, 0.f, 0.f, 0.f);
        if (n < N) v = *(const float4*)(h + (size_t)n * D + c4);
        ushort4 bv4;
        bv4.x = f2bf(v.x); bv4.y = f2bf(v.y); bv4.z = f2bf(v.z); bv4.w = f2bf(v.w);
        *(ushort4*)&hA[r * ASTR + c4] = bv4;
    }
    __syncthreads();
    int lane = tid & 63, w = tid >> 6;
    int m = lane & 15, quad = lane >> 4;

    // A fragments + row norms (hA reads complete before the union is reused)
    short8 afrag[4];
    const unsigned short* ab = &hA[(w * 16 + m) * ASTR + quad * 8];
#pragma unroll
    for (int c = 0; c < 4; c++)
        afrag[c] = *(const short8*)(ab + c * 32);

    for (int rr = 0; rr < 16; rr += 4) {
        float s0, s1, s2, s3;
        {
            unsigned int u0 = *(const unsigned int*)&hA[(w * 16 + rr + 0) * ASTR + lane * 2];
            unsigned int u1 = *(const unsigned int*)&hA[(w * 16 + rr + 1) * ASTR + lane * 2];
            unsigned int u2 = *(const unsigned int*)&hA[(w * 16 + rr + 2) * ASTR + lane * 2];
            unsigned int u3 = *(const unsigned int*)&hA[(w * 16 + rr + 3) * ASTR + lane * 2];
            float a, b;
            a = bf2f(u0); b = bf2f_hi(u0); s0 = a * a + b * b;
            a = bf2f(u1); b = bf2f_hi(u1); s1 = a * a + b * b;
            a = bf2f(u2); b = bf2f_hi(u2); s2 = a * a + b * b;
            a = bf2f(u3); b = bf2f_hi(u3); s3 = a * a + b * b;
        }
#pragma unroll
        for (int off = 1; off < 64; off <<= 1) {
            s0 += __shfl_xor(s0, off);
            s1 += __shfl_xor(s1, off);
            s2 += __shfl_xor(s2, off);
            s3 += __shfl_xor(s3, off);
        }
        if (lane < 4) {
            float sv = (lane == 0) ? s0 : (lane == 1) ? s1 : (lane == 2) ? s2 : s3;
            int n = row0 + w * 16 + rr + lane;
            if (n < N) inv_norm[n] = 1.0f / fmaxf(sqrtf(sv), 1e-12f);
        }
    }
    __syncthreads();   // hA dead; kvb/qtb live from here

    const unsigned short* wbase = WpT + (size_t)m * D + quad * 8;

#define LOADB(set, tt)                                                         \
    {                                                                          \
        const unsigned short* kb = wbase + (size_t)(tt) * 16 * D;              \
        const unsigned short* qb = kb + (size_t)D * D;                         \
        const unsigned short* vb = kb + (size_t)2 * D * D;                     \
        set##k0 = *(const short8*)(kb);        set##k1 = *(const short8*)(kb + 32); \
        set##k2 = *(const short8*)(kb + 64);   set##k3 = *(const short8*)(kb + 96); \
        set##q0 = *(const short8*)(qb);        set##q1 = *(const short8*)(qb + 32); \
        set##q2 = *(const short8*)(qb + 64);   set##q3 = *(const short8*)(qb + 96); \
        set##v0 = *(const short8*)(vb);        set##v1 = *(const short8*)(vb + 32); \
        set##v2 = *(const short8*)(vb + 64);   set##v3 = *(const short8*)(vb + 96); \
    }

#define COMPUTE(set, tt)                                                       \
    {                                                                          \
        floatx4 aK = (floatx4){0.f, 0.f, 0.f, 0.f};                            \
        floatx4 aQ = (floatx4){0.f, 0.f, 0.f, 0.f};                            \
        floatx4 aV = (floatx4){0.f, 0.f, 0.f, 0.f};                            \
        aK = __builtin_amdgcn_mfma_f32_16x16x32_bf16(afrag[0], set##k0, aK, 0, 0, 0); \
        aQ = __builtin_amdgcn_mfma_f32_16x16x32_bf16(afrag[0], set##q0, aQ, 0, 0, 0); \
        aV = __builtin_amdgcn_mfma_f32_16x16x32_bf16(afrag[0], set##v0, aV, 0, 0, 0); \
        aK = __builtin_amdgcn_mfma_f32_16x16x32_bf16(afrag[1], set##k1, aK, 0, 0, 0); \
        aQ = __builtin_amdgcn_mfma_f32_16x16x32_bf16(afrag[1], set##q1, aQ, 0, 0, 0); \
        aV = __builtin_amdgcn_mfma_f32_16x16x32_bf16(afrag[1], set##v1, aV, 0, 0, 0); \
        aK = __builtin_amdgcn_mfma_f32_16x16x32_bf16(afrag[2], set##k2, aK, 0, 0, 0); \
        aQ = __builtin_amdgcn_mfma_f32_16x16x32_bf16(afrag[2], set##q2, aQ, 0, 0, 0); \
        aV = __builtin_amdgcn_mfma_f32_16x16x32_bf16(afrag[2], set##v2, aV, 0, 0, 0); \
        aK = __builtin_amdgcn_mfma_f32_16x16x32_bf16(afrag[3], set##k3, aK, 0, 0, 0); \
        aQ = __builtin_amdgcn_mfma_f32_16x16x32_bf16(afrag[3], set##q3, aQ, 0, 0, 0); \
        aV = __builtin_amdgcn_mfma_f32_16x16x32_bf16(afrag[3], set##v3, aV, 0, 0, 0); \
        int j = (tt) * 16 + m;                                                 \
        float bk = bp[j], bq = bp[D + j], bvs = bp[2 * D + j];                 \
        _Pragma("unroll")                                                      \
        for (int r = 0; r < 4; r++) {                                          \
            int row = w * 16 + quad * 4 + r;                                   \
            float kval = aK[r] + bk;                                           \
            float qval = aQ[r] + bq;                                           \
            float vval = aV[r] + bvs;                                          \
            float qpart = __shfl_xor(qval, 1);                                 \
            kvb[row * KVSTR + j] = (unsigned int)f2bf(kval)                    \
                                 | ((unsigned int)f2bf(vval) << 16);           \
            if (!(lane & 1))                                                   \
                qtb[row * QTSTR + (tt) * 8 + (m >> 1)] =                       \
                    (unsigned int)f2bf(qval) | ((unsigned int)f2bf(qpart) << 16); \
        }                                                                      \
    }

    short8 Ak0, Ak1, Ak2, Ak3, Aq0, Aq1, Aq2, Aq3, Av0, Av1, Av2, Av3;
    short8 Bk0, Bk1, Bk2, Bk3, Bq0, Bq1, Bq2, Bq3, Bv0, Bv1, Bv2, Bv3;
    LOADB(A, 0)
#pragma unroll 1
    for (int t = 0; t < 8; t += 2) {
        LOADB(B, t + 1)
        COMPUTE(A, t)
        if (t + 2 < 8) LOADB(A, t + 2)
        COMPUTE(B, t + 1)
    }
    __syncthreads();

    // coalesced full-line stores: kv 64 rows x 512 B, qt 64 rows x 256 B
    for (int i = tid; i < 64 * 32; i += 256) {
        int r = i >> 5, c4 = (i & 31) << 2;
        int n = row0 + r;
        if (n < N) {
            uint4 v = *(const uint4*)&kvb[r * KVSTR + c4];
            *(uint4*)(kv + (size_t)n * D + c4) = v;
        }
    }
    for (int i = tid; i < 64 * 16; i += 256) {
        int r = i >> 4, c4 = (i & 15) << 2;
        int n = row0 + r;
        if (n < N) {
            uint4 v = *(const uint4*)&qtb[r * QTSTR + c4];
            *(uint4*)(qt + (size_t)n * D + c4 * 2) = v;
        }
    }
#undef LOADB
#undef COMPUTE
}

// ---------------------------------------------------------------------------
__global__ void deg_hist_kernel(const int* __restrict__ src, const int* __restrict__ dst,
                                int* __restrict__ cnt_src, int* __restrict__ cnt_dst, int E)
{
    int e = blockIdx.x * blockDim.x + threadIdx.x;
    if (e >= E) return;
    atomicAdd(&cnt_src[src[e]], 1);
    atomicAdd(&cnt_dst[dst[e]], 1);
}

// ---------------------------------------------------------------------------
__global__ __launch_bounds__(1024) void scan_blocks_kernel(
    const int* __restrict__ cnt_src, const int* __restrict__ cnt_dst,
    int* __restrict__ rowptr, int* __restrict__ deg,
    int* __restrict__ btot, int* __restrict__ zcount, int N)
{
    __shared__ int wtot[16];
    __shared__ int wscan[16];
    int tid = threadIdx.x, lane = tid & 63, wv = tid >> 6;
    int i = blockIdx.x * 1024 + tid;
    int cs = 0, cd = 0;
    if (i < N) { cs = cnt_src[i]; cd = cnt_dst[i]; }
    int x = cd;
#pragma unroll
    for (int off = 1; off < 64; off <<= 1) {
        int y = __shfl_up(x, off);
        if (lane >= off) x += y;
    }
    if (lane == 63) wtot[wv] = x;
    __syncthreads();
    if (wv == 0) {
        int t = (lane < 16) ? wtot[lane] : 0;
#pragma unroll
        for (int off = 1; off < 16; off <<= 1) {
            int y = __shfl_up(t, off);
            if (lane >= off) t += y;
        }
        if (lane < 16) wscan[lane] = t;
    }
    __syncthreads();
    int woff = (wv == 0) ? 0 : wscan[wv - 1];
    if (i < N) {
        rowptr[i] = woff + x - cd;
        deg[i] = cs + cd;
    }
    if (tid == 0) btot[blockIdx.x] = wscan[15];
    int zc = (i < N && (cs + cd) == 0) ? 1 : 0;
#pragma unroll
    for (int off = 1; off < 64; off <<= 1) zc += __shfl_xor(zc, off);
    if (lane == 0 && zc) atomicAdd(zcount, zc);
}

// ---------------------------------------------------------------------------
__global__ void scan_final_kernel(const int* __restrict__ btot,
                                  int* __restrict__ boff, int* __restrict__ rowptr,
                                  const int* __restrict__ zcount,
                                  const float* __restrict__ fsb,
                                  float* __restrict__ flags, int N, int nb)
{
    int lane = threadIdx.x;   // 64
    int v = (lane < nb) ? btot[lane] : 0;
    int x = v;
#pragma unroll
    for (int off = 1; off < 64; off <<= 1) {
        int y = __shfl_up(x, off);
        if (lane >= off) x += y;
    }
    if (lane < nb) boff[lane] = x - v;
    if (lane == 63) rowptr[N] = x;    // grand total = E
    if (lane == 0) {
        float z = (float)zcount[0];
        float sparsity = z / (float)N;
        flags[0] = (sparsity > 0.3f) ? fsb[0] : 0.f;
        flags[1] = fmaxf((float)N - z, 1.f);
    }
}

__global__ void scan_add_kernel(int* __restrict__ rowptr,
                                const int* __restrict__ boff, int N)
{
    int i = blockIdx.x * blockDim.x + threadIdx.x;
    if (i < N) rowptr[i] += boff[i >> 10];
}

// ---------------------------------------------------------------------------
__global__ void scatter_kernel(const int* __restrict__ src, const int* __restrict__ dst,
                               const int* __restrict__ rowptr, int* __restrict__ cursor,
                               int* __restrict__ esrc, int E)
{
    int e = blockIdx.x * blockDim.x + threadIdx.x;
    if (e >= E) return;
    int d = dst[e];
    int pos = rowptr[d] + atomicAdd(&cursor[d], 1);
    esrc[pos] = src[e];
}

// ---------------------------------------------------------------------------
// Fused softmax + aggregation, gather-based, ZERO atomics.
// One wave per dst node, 2 edges per wave (32 lanes/edge), uint4 gathers.
// ---------------------------------------------------------------------------
__global__ __launch_bounds__(256) void dst_agg_kernel(
    const unsigned int* __restrict__ kv, const unsigned short* __restrict__ qt,
    const float* __restrict__ h, const float* __restrict__ inv_norm,
    const int* __restrict__ rowptr, const int* __restrict__ esrc,
    const float* __restrict__ flags,
    unsigned int* __restrict__ agg, int N)
{
    int n = (blockIdx.x * blockDim.x + threadIdx.x) >> 6;
    int lane = threadIdx.x & 63;
    if (n >= N) return;
    int half = lane >> 5, c = lane & 31;
    int beg = rowptr[n], end = rowptr[n + 1];
    uint2 qw = *(const uint2*)(qt + (size_t)n * D + c * 4);
    float q0 = bf2f(qw.x), q1 = bf2f_hi(qw.x);
    float q2 = bf2f(qw.y), q3 = bf2f_hi(qw.y);
    float boost = flags[0];
    float hn0 = 0.f, hn1 = 0.f, hn2 = 0.f, hn3 = 0.f, innd = 0.f;
    if (boost != 0.f) {
        float4 hh = *(const float4*)(h + (size_t)n * D + c * 4);
        hn0 = hh.x; hn1 = hh.y; hn2 = hh.z; hn3 = hh.w; innd = inv_norm[n];
    }
    const float SC = 0.17677669529663687f;   // 1/sqrt(32)
    float a0 = 0.f, a1 = 0.f, a2 = 0.f, a3 = 0.f, den = 0.f;
    int i = beg;
    for (; i + 3 < end; i += 4) {
        int sA = esrc[i + half];
        int sB = esrc[i + 2 + half];
        uint4 wA = *(const uint4*)(kv + (size_t)sA * D + c * 4);
        uint4 wB = *(const uint4*)(kv + (size_t)sB * D + c * 4);
        float dA = q0 * bf2f(wA.x) + q1 * bf2f(wA.y)
                 + q2 * bf2f(wA.z) + q3 * bf2f(wA.w);
        float dB = q0 * bf2f(wB.x) + q1 * bf2f(wB.y)
                 + q2 * bf2f(wB.z) + q3 * bf2f(wB.w);
        dA += __shfl_xor(dA, 1);  dB += __shfl_xor(dB, 1);
        dA += __shfl_xor(dA, 2);  dB += __shfl_xor(dB, 2);
        dA += __shfl_xor(dA, 4);  dB += __shfl_xor(dB, 4);
        float attA = dA * SC, attB = dB * SC;
        if (boost != 0.f) {
            float4 xA = *(const float4*)(h + (size_t)sA * D + c * 4);
            float4 xB = *(const float4*)(h + (size_t)sB * D + c * 4);
            float fA = hn0 * xA.x + hn1 * xA.y + hn2 * xA.z + hn3 * xA.w;
            float fB = hn0 * xB.x + hn1 * xB.y + hn2 * xB.z + hn3 * xB.w;
#pragma unroll
            for (int off = 1; off < 32; off <<= 1) {
                fA += __shfl_xor(fA, off);
                fB += __shfl_xor(fB, off);
            }
            attA += fA * inv_norm[sA] * innd * boost;
            attB += fB * inv_norm[sB] * innd * boost;
        }
        attA = fminf(fmaxf(attA, -60.f), 60.f);
        attB = fminf(fmaxf(attB, -60.f), 60.f);
        float pA = __expf(attA), pB = __expf(attB);
        den += pA + pB;
        a0 += pA * bf2f_hi(wA.x) + pB * bf2f_hi(wB.x);
        a1 += pA * bf2f_hi(wA.y) + pB * bf2f_hi(wB.y);
        a2 += pA * bf2f_hi(wA.z) + pB * bf2f_hi(wB.z);
        a3 += pA * bf2f_hi(wA.w) + pB * bf2f_hi(wB.w);
    }
    for (; i + 1 < end; i += 2) {
        int sA = esrc[i + half];
        uint4 wA = *(const uint4*)(kv + (size_t)sA * D + c * 4);
        float dA = q0 * bf2f(wA.x) + q1 * bf2f(wA.y)
                 + q2 * bf2f(wA.z) + q3 * bf2f(wA.w);
        dA += __shfl_xor(dA, 1);
        dA += __shfl_xor(dA, 2);
        dA += __shfl_xor(dA, 4);
        float attA = dA * SC;
        if (boost != 0.f) {
            float4 xA = *(const float4*)(h + (size_t)sA * D + c * 4);
            float fA = hn0 * xA.x + hn1 * xA.y + hn2 * xA.z + hn3 * xA.w;
#pragma unroll
            for (int off = 1; off < 32; off <<= 1) fA += __shfl_xor(fA, off);
            attA += fA * inv_norm[sA] * innd * boost;
        }
        attA = fminf(fmaxf(attA, -60.f), 60.f);
        float pA = __expf(attA);
        den += pA;
        a0 += pA * bf2f_hi(wA.x);
        a1 += pA * bf2f_hi(wA.y);
        a2 += pA * bf2f_hi(wA.z);
        a3 += pA * bf2f_hi(wA.w);
    }
    if (i < end && half == 0) {
        int sA = esrc[i];
        uint4 wA = *(const uint4*)(kv + (size_t)sA * D + c * 4);
        float dA = q0 * bf2f(wA.x) + q1 * bf2f(wA.y)
                 + q2 * bf2f(wA.z) + q3 * bf2f(wA.w);
        dA += __shfl_xor(dA, 1);
        dA += __shfl_xor(dA, 2);
        dA += __shfl_xor(dA, 4);
        float attA = dA * SC;
        if (boost != 0.f) {
            float4 xA = *(const float4*)(h + (size_t)sA * D + c * 4);
            float fA = hn0 * xA.x + hn1 * xA.y + hn2 * xA.z + hn3 * xA.w;
#pragma unroll
            for (int off = 1; off < 32; off <<= 1) fA += __shfl_xor(fA, off);
            attA += fA * inv_norm[sA] * innd * boost;
        }
        attA = fminf(fmaxf(attA, -60.f), 60.f);
        float pA = __expf(attA);
        den += pA;
        a0 += pA * bf2f_hi(wA.x);
        a1 += pA * bf2f_hi(wA.y);
        a2 += pA * bf2f_hi(wA.z);
        a3 += pA * bf2f_hi(wA.w);
    }
    den += __shfl_xor(den, 32);
    a0  += __shfl_xor(a0, 32);
    a1  += __shfl_xor(a1, 32);
    a2  += __shfl_xor(a2, 32);
    a3  += __shfl_xor(a3, 32);
    if (half == 0) {
        float r = 1.0f / fmaxf(den, 1e-38f);
        uint2 o;
        o.x = (unsigned int)f2bf(a0 * r) | ((unsigned int)f2bf(a1 * r) << 16);
        o.y = (unsigned int)f2bf(a2 * r) | ((unsigned int)f2bf(a3 * r) << 16);
        *(uint2*)(agg + (size_t)n * (D / 2) + c * 2) = o;
    }
}

// ---------------------------------------------------------------------------
// out = LN(agg @ Wa + ba) via MFMA.  64 rows/block, 4 waves; B-frag loads
// double-buffered across t; os rows are wave-exclusive (no extra barrier).
// ---------------------------------------------------------------------------
#define OSTR 132
__global__ __launch_bounds__(256) void out_ln_kernel(
    const unsigned int* __restrict__ agg,      // packed bf16 pairs
    const unsigned short* __restrict__ WaT, const float* __restrict__ ba,
    const float* __restrict__ ln_g, const float* __restrict__ ln_b,
    const int* __restrict__ deg, float* __restrict__ out,
    float* __restrict__ gcpart, int N)
{
    __shared__ unsigned short aB[64 * ASTR];
    __shared__ float os[64][OSTR];
    int row0 = blockIdx.x * 64;
    int tid = threadIdx.x;
    for (int i = tid; i < 64 * 16; i += 256) {
        int r = i >> 4, c8 = (i & 15) << 3;
        int n = row0 + r;
        uint4 v = make_uint4(0u, 0u, 0u, 0u);
        if (n < N) v = *(const uint4*)(agg + (size_t)n * D / 2 + (c8 >> 1));
        *(uint4*)&aB[r * ASTR + c8] = v;
    }
    __syncthreads();
    int lane = tid & 63, w = tid >> 6;
    int m = lane & 15, quad = lane >> 4;

    short8 afrag[4];
    const unsigned short* ab = &aB[(w * 16 + m) * ASTR + quad * 8];
#pragma unroll
    for (int c = 0; c < 4; c++)
        afrag[c] = *(const short8*)(ab + c * 32);

    const unsigned short* wbase = WaT + (size_t)m * D + quad * 8;
    short8 A0, A1, A2, A3, B0, B1, B2, B3;
    A0 = *(const short8*)(wbase);
    A1 = *(const short8*)(wbase + 32);
    A2 = *(const short8*)(wbase + 64);
    A3 = *(const short8*)(wbase + 96);
#pragma unroll 1
    for (int t = 0; t < 8; t += 2) {
        const unsigned short* nb = wbase + (size_t)(t + 1) * 16 * D;
        B0 = *(const short8*)(nb);
        B1 = *(const short8*)(nb + 32);
        B2 = *(const short8*)(nb + 64);
        B3 = *(const short8*)(nb + 96);
        {
            floatx4 acc = (floatx4){0.f, 0.f, 0.f, 0.f};
            acc = __builtin_amdgcn_mfma_f32_16x16x32_bf16(afrag[0], A0, acc, 0, 0, 0);
            acc = __builtin_amdgcn_mfma_f32_16x16x32_bf16(afrag[1], A1, acc, 0, 0, 0);
            acc = __builtin_amdgcn_mfma_f32_16x16x32_bf16(afrag[2], A2, acc, 0, 0, 0);
            acc = __builtin_amdgcn_mfma_f32_16x16x32_bf16(afrag[3], A3, acc, 0, 0, 0);
            int j = t * 16 + m;
            float bj = ba[j];
#pragma unroll
            for (int r = 0; r < 4; r++)
                os[w * 16 + quad * 4 + r][j] = acc[r] + bj;
        }
        if (t + 2 < 8) {
            const unsigned short* na = wbase + (size_t)(t + 2) * 16 * D;
            A0 = *(const short8*)(na);
            A1 = *(const short8*)(na + 32);
            A2 = *(const short8*)(na + 64);
            A3 = *(const short8*)(na + 96);
        }
        {
            floatx4 acc = (floatx4){0.f, 0.f, 0.f, 0.f};
            acc = __builtin_amdgcn_mfma_f32_16x16x32_bf16(afrag[0], B0, acc, 0, 0, 0);
            acc = __builtin_amdgcn_mfma_f32_16x16x32_bf16(afrag[1], B1, acc, 0, 0, 0);
            acc = __builtin_amdgcn_mfma_f32_16x16x32_bf16(afrag[2], B2, acc, 0, 0, 0);
            acc = __builtin_amdgcn_mfma_f32_16x16x32_bf16(afrag[3], B3, acc, 0, 0, 0);
            int j = (t + 1) * 16 + m;
            float bj = ba[j];
#pragma unroll
            for (int r = 0; r < 4; r++)
                os[w * 16 + quad * 4 + r][j] = acc[r] + bj;
        }
    }
    int j2 = lane * 2;
    float g0 = ln_g[j2], g1 = ln_g[j2 + 1];
    float b0 = ln_b[j2], b1 = ln_b[j2 + 1];
    float gcs0 = 0.f, gcs1 = 0.f;
    for (int rr = 0; rr < 16; rr++) {
        int r = w * 16 + rr;
        int n = row0 + r;
        if (n >= N) break;
        float x0 = os[r][j2], x1 = os[r][j2 + 1];
        float s = x0 + x1, s2 = x0 * x0 + x1 * x1;
#pragma unroll
        for (int off = 1; off < 64; off <<= 1) {
            s  += __shfl_xor(s, off);
            s2 += __shfl_xor(s2, off);
        }
        float mu = s * (1.f / 128.f);
        float var = s2 * (1.f / 128.f) - mu * mu;
        float rstd = rsqrtf(fmaxf(var, 0.f) + 1e-5f);
        float y0 = (x0 - mu) * rstd * g0 + b0;
        float y1 = (x1 - mu) * rstd * g1 + b1;
        *(float2*)(out + (size_t)n * D + j2) = make_float2(y0, y1);
        if (deg[n] != 0) { gcs0 += y0; gcs1 += y1; }
    }
    int slot = blockIdx.x & 63;
    if (gcs0 != 0.f || gcs1 != 0.f) {
        atomicAdd(&gcpart[slot * D + j2],     gcs0);
        atomicAdd(&gcpart[slot * D + j2 + 1], gcs1);
    }
}

__global__ void gc_final_kernel(const float* __restrict__ gcpart,
                                const float* __restrict__ flags,
                                float* __restrict__ gc)
{
    int j = threadIdx.x;  // 128
    float s = 0.f;
    for (int i = 0; i < 64; i++) s += gcpart[i * D + j];
    gc[j] = s / flags[1];
}

// ---------------------------------------------------------------------------
__global__ void fixup_kernel(const float* __restrict__ h,
                             const int* __restrict__ deg,
                             const float* __restrict__ gc,
                             float* __restrict__ out, int N)
{
    int n = blockIdx.x * blockDim.x + threadIdx.x;
    if (n >= N) return;
    if (deg[n] != 0) return;
    for (int j = 0; j < D; j += 4) {
        float4 hv = *(const float4*)(h + (size_t)n * D + j);
        float4 gv = *(const float4*)(gc + j);
        float4 o;
        o.x = 0.9f * hv.x + 0.1f * gv.x;
        o.y = 0.9f * hv.y + 0.1f * gv.y;
        o.z = 0.9f * hv.z + 0.1f * gv.z;
        o.w = 0.9f * hv.w + 0.1f * gv.w;
        *(float4*)(out + (size_t)n * D + j) = o;
    }
}

// ---------------------------------------------------------------------------
extern "C" void kernel_launch(void* const* d_in, const int* in_sizes, int n_in,
                              void* d_out, int out_size, void* d_ws, size_t ws_size,
                              hipStream_t stream)
{
    const float* h       = (const float*)d_in[0];
    const int* src_idx   = (const int*)d_in[1];
    const int* dst_idx   = (const int*)d_in[2];
    const float* Wk      = (const float*)d_in[3];
    const float* bk      = (const float*)d_in[4];
    const float* Wq      = (const float*)d_in[5];
    const float* bq      = (const float*)d_in[6];
    const float* Wv      = (const float*)d_in[7];
    const float* bv      = (const float*)d_in[8];
    const float* rk      = (const float*)d_in[9];
    const float* rq      = (const float*)d_in[10];
    const float* rv      = (const float*)d_in[11];
    const float* Wa      = (const float*)d_in[12];
    const float* ba      = (const float*)d_in[13];
    const float* ln_g    = (const float*)d_in[14];
    const float* ln_b    = (const float*)d_in[15];
    const float* fsb     = (const float*)d_in[16];
    float* out           = (float*)d_out;

    int N = in_sizes[0] / D;
    int E = in_sizes[1];
    int nb = (N + 1023) >> 10;   // scan blocks (<= 64)

    // ---- workspace: small control buffers first ---------------------------
    char* p = (char*)d_ws;
    auto alloc = [&](size_t bytes) { char* q = p; p += (bytes + 15) & ~(size_t)15; return q; };

    unsigned short* WpT = (unsigned short*)alloc(3 * D * D * 2);
    unsigned short* WaT = (unsigned short*)alloc(D * D * 2);
    float* bp       = (float*)alloc(3 * D * 4);
    float* gc       = (float*)alloc(D * 4);
    float* flags    = (float*)alloc(2 * 4);
    int*   btot     = (int*)alloc(64 * 4);
    int*   boff     = (int*)alloc(64 * 4);
    float* inv_norm = (float*)alloc((size_t)N * 4);
    int*   rowptr   = (int*)alloc(((size_t)N + 1) * 4);
    int*   deg      = (int*)alloc((size_t)N * 4);
    // zero region: cnt_src, cnt_dst, cursor, zcount, gcpart (contiguous)
    char* z1 = p;
    int*   cnt_src = (int*)alloc((size_t)N * 4);
    int*   cnt_dst = (int*)alloc((size_t)N * 4);
    int*   cursor  = (int*)alloc((size_t)N * 4);
    int*   zcount  = (int*)alloc(4);
    float* gcpart  = (float*)alloc(64 * D * 4);
    size_t z1_bytes = (size_t)(p - z1);
    // big arrays
    unsigned short* qt = (unsigned short*)alloc((size_t)N * D * 2);
    unsigned int*   kv = (unsigned int*)alloc((size_t)N * D * 4);
    int*   esrc        = (int*)alloc((size_t)E * 4);
    unsigned int* agg  = (unsigned int*)alloc((size_t)N * D * 2);

    hipMemsetAsync(z1, 0, z1_bytes, stream);

    prep_weights_kernel<<<dim3(129, 4), 128, 0, stream>>>(Wk, bk, Wq, bq, Wv, bv,
                                                          rk, rq, rv, Wa,
                                                          WpT, WaT, bp);
    gemm_mfma_kernel<<<(N + 63) / 64, 256, 0, stream>>>(h, WpT, bp, qt, kv,
                                                        inv_norm, N);
    deg_hist_kernel<<<(E + 255) / 256, 256, 0, stream>>>(src_idx, dst_idx,
                                                         cnt_src, cnt_dst, E);
    scan_blocks_kernel<<<nb, 1024, 0, stream>>>(cnt_src, cnt_dst, rowptr, deg,
                                                btot, zcount, N);
    scan_final_kernel<<<1, 64, 0, stream>>>(btot, boff, rowptr, zcount, fsb,
                                            flags, N, nb);
    scan_add_kernel<<<(N + 255) / 256, 256, 0, stream>>>(rowptr, boff, N);
    scatter_kernel<<<(E + 255) / 256, 256, 0, stream>>>(src_idx, dst_idx, rowptr,
                                                        cursor, esrc, E);
    dst_agg_kernel<<<(N + 3) / 4, 256, 0, stream>>>(kv, qt, h, inv_norm,
                                                    rowptr, esrc, flags, agg, N);
    out_ln_kernel<<<(N + 63) / 64, 256, 0, stream>>>(agg, WaT, ba, ln_g, ln_b,
                                                     deg, out, gcpart, N);
    gc_final_kernel<<<1, D, 0, stream>>>(gcpart, flags, gc);
    fixup_kernel<<<(N + 255) / 256, 256, 0, stream>>>(h, deg, gc, out, N);
}

// Round 11
// 321.465 us; speedup vs baseline: 5.4136x; 1.0927x over previous
//
#include <hip/hip_runtime.h>

#define D 128
#define NH 4
#define DKH 32

typedef __attribute__((ext_vector_type(8))) short short8;
typedef __attribute__((ext_vector_type(4))) float floatx4;

__device__ __forceinline__ float bf2f(unsigned int u) {
    return __uint_as_float((u & 0xffffu) << 16);
}
__device__ __forceinline__ float bf2f_hi(unsigned int u) {
    return __uint_as_float(u & 0xffff0000u);
}
__device__ __forceinline__ unsigned short f2bf(float f) {
    unsigned int x = __float_as_uint(f);
    x += 0x7fffu + ((x >> 16) & 1u);
    return (unsigned short)(x >> 16);
}

// ---------------------------------------------------------------------------
// Fold rel_{k,q,v} into W,b -> WpT (bf16 transposed); w==3 transposes Wa.
// ---------------------------------------------------------------------------
__global__ void prep_weights_kernel(
    const float* __restrict__ Wk, const float* __restrict__ bk,
    const float* __restrict__ Wq, const float* __restrict__ bq,
    const float* __restrict__ Wv, const float* __restrict__ bv,
    const float* __restrict__ rk, const float* __restrict__ rq,
    const float* __restrict__ rv, const float* __restrict__ Wa,
    unsigned short* __restrict__ WpT, unsigned short* __restrict__ WaT,
    float* __restrict__ bp)
{
    int w = blockIdx.y;
    int j = threadIdx.x;            // output column 0..127
    int i = blockIdx.x;
    if (w == 3) {
        if (i < D) WaT[(size_t)j * D + i] = f2bf(Wa[(size_t)i * D + j]);
        return;
    }
    const float* W   = (w == 0) ? Wk : (w == 1) ? Wq : Wv;
    const float* b   = (w == 0) ? bk : (w == 1) ? bq : bv;
    const float* rel = (w == 0) ? rk : (w == 1) ? rq : rv;
    int h = j >> 5, f = j & 31;
    float acc = 0.f;
    if (i < D) {
        for (int dd = 0; dd < DKH; dd++)
            acc += W[i * D + h * DKH + dd] * rel[h * 1024 + dd * DKH + f];
        WpT[((size_t)(w * D + j)) * D + i] = f2bf(acc);
    } else {
        for (int dd = 0; dd < DKH; dd++)
            acc += b[h * DKH + dd] * rel[h * 1024 + dd * DKH + f];
        bp[w * D + j] = acc;
    }
}

// ---------------------------------------------------------------------------
// MFMA GEMM: [qt | kv] = h @ W'{k,q,v} + b', plus fused row norms.
// 64 rows/block, 4 waves.  K-loop in TWO halves (t=0..3, 4..7); each half
// buffers into half-width LDS (kvb+qtb = 25.6 KB total, hA unions in) and
// each wave stores its OWN 16 rows (wave-private -> no extra barriers).
// Occupancy: 6 blocks/CU (was 3 at 50 KB LDS).
// Layouts (verified r6): A[m=lane&15][k=quad*8+j], B row = out col,
// C/D col=lane&15, row=quad*4+reg.
// ---------------------------------------------------------------------------
#define ASTR 136
#define KV2STR 66
#define QT2STR 34
__global__ __launch_bounds__(256) void gemm_mfma_kernel(
    const float* __restrict__ h, const unsigned short* __restrict__ WpT,
    const float* __restrict__ bp,
    unsigned short* __restrict__ qt, unsigned int* __restrict__ kv,
    float* __restrict__ inv_norm, int N)
{
    // union: hA (64*ASTR ushort = 17.4 KB) dead after afrag+norms;
    // kvb (64*66 uint = 16.9 KB) + qtb (64*34 uint = 8.7 KB) = 25.6 KB
    __shared__ unsigned int smem[64 * KV2STR + 64 * QT2STR];
    unsigned short* hA = (unsigned short*)smem;
    unsigned int* kvb = smem;
    unsigned int* qtb = smem + 64 * KV2STR;

    int row0 = blockIdx.x * 64;
    int tid = threadIdx.x;
    for (int i = tid; i < 64 * 32; i += 256) {
        int r = i >> 5, c4 = (i & 31) << 2;
        int n = row0 + r;
        float4 v = make_float4(0.f, 0.f, 0.f, 0.f);
        if (n < N) v = *(const float4*)(h + (size_t)n * D + c4);
        ushort4 bv4;
        bv4.x = f2bf(v.x); bv4.y = f2bf(v.y); bv4.z = f2bf(v.z); bv4.w = f2bf(v.w);
        *(ushort4*)&hA[r * ASTR + c4] = bv4;
    }
    __syncthreads();
    int lane = tid & 63, w = tid >> 6;
    int m = lane & 15, quad = lane >> 4;

    // A fragments + row norms (hA reads complete before the union is reused)
    short8 afrag[4];
    const unsigned short* ab = &hA[(w * 16 + m) * ASTR + quad * 8];
#pragma unroll
    for (int c = 0; c < 4; c++)
        afrag[c] = *(const short8*)(ab + c * 32);

    for (int rr = 0; rr < 16; rr += 4) {
        float s0, s1, s2, s3;
        {
            unsigned int u0 = *(const unsigned int*)&hA[(w * 16 + rr + 0) * ASTR + lane * 2];
            unsigned int u1 = *(const unsigned int*)&hA[(w * 16 + rr + 1) * ASTR + lane * 2];
            unsigned int u2 = *(const unsigned int*)&hA[(w * 16 + rr + 2) * ASTR + lane * 2];
            unsigned int u3 = *(const unsigned int*)&hA[(w * 16 + rr + 3) * ASTR + lane * 2];
            float a, b;
            a = bf2f(u0); b = bf2f_hi(u0); s0 = a * a + b * b;
            a = bf2f(u1); b = bf2f_hi(u1); s1 = a * a + b * b;
            a = bf2f(u2); b = bf2f_hi(u2); s2 = a * a + b * b;
            a = bf2f(u3); b = bf2f_hi(u3); s3 = a * a + b * b;
        }
#pragma unroll
        for (int off = 1; off < 64; off <<= 1) {
            s0 += __shfl_xor(s0, off);
            s1 += __shfl_xor(s1, off);
            s2 += __shfl_xor(s2, off);
            s3 += __shfl_xor(s3, off);
        }
        if (lane < 4) {
            float sv = (lane == 0) ? s0 : (lane == 1) ? s1 : (lane == 2) ? s2 : s3;
            int n = row0 + w * 16 + rr + lane;
            if (n < N) inv_norm[n] = 1.0f / fmaxf(sqrtf(sv), 1e-12f);
        }
    }
    __syncthreads();   // hA dead; kvb/qtb live from here (wave-private rows)

    const unsigned short* wbase = WpT + (size_t)m * D + quad * 8;

#define LOADB(set, tt)                                                         \
    {                                                                          \
        const unsigned short* kb = wbase + (size_t)(tt) * 16 * D;              \
        const unsigned short* qb = kb + (size_t)D * D;                         \
        const unsigned short* vb = kb + (size_t)2 * D * D;                     \
        set##k0 = *(const short8*)(kb);        set##k1 = *(const short8*)(kb + 32); \
        set##k2 = *(const short8*)(kb + 64);   set##k3 = *(const short8*)(kb + 96); \
        set##q0 = *(const short8*)(qb);        set##q1 = *(const short8*)(qb + 32); \
        set##q2 = *(const short8*)(qb + 64);   set##q3 = *(const short8*)(qb + 96); \
        set##v0 = *(const short8*)(vb);        set##v1 = *(const short8*)(vb + 32); \
        set##v2 = *(const short8*)(vb + 64);   set##v3 = *(const short8*)(vb + 96); \
    }

#define COMPUTE(set, tt, t0)                                                   \
    {                                                                          \
        floatx4 aK = (floatx4){0.f, 0.f, 0.f, 0.f};                            \
        floatx4 aQ = (floatx4){0.f, 0.f, 0.f, 0.f};                            \
        floatx4 aV = (floatx4){0.f, 0.f, 0.f, 0.f};                            \
        aK = __builtin_amdgcn_mfma_f32_16x16x32_bf16(afrag[0], set##k0, aK, 0, 0, 0); \
        aQ = __builtin_amdgcn_mfma_f32_16x16x32_bf16(afrag[0], set##q0, aQ, 0, 0, 0); \
        aV = __builtin_amdgcn_mfma_f32_16x16x32_bf16(afrag[0], set##v0, aV, 0, 0, 0); \
        aK = __builtin_amdgcn_mfma_f32_16x16x32_bf16(afrag[1], set##k1, aK, 0, 0, 0); \
        aQ = __builtin_amdgcn_mfma_f32_16x16x32_bf16(afrag[1], set##q1, aQ, 0, 0, 0); \
        aV = __builtin_amdgcn_mfma_f32_16x16x32_bf16(afrag[1], set##v1, aV, 0, 0, 0); \
        aK = __builtin_amdgcn_mfma_f32_16x16x32_bf16(afrag[2], set##k2, aK, 0, 0, 0); \
        aQ = __builtin_amdgcn_mfma_f32_16x16x32_bf16(afrag[2], set##q2, aQ, 0, 0, 0); \
        aV = __builtin_amdgcn_mfma_f32_16x16x32_bf16(afrag[2], set##v2, aV, 0, 0, 0); \
        aK = __builtin_amdgcn_mfma_f32_16x16x32_bf16(afrag[3], set##k3, aK, 0, 0, 0); \
        aQ = __builtin_amdgcn_mfma_f32_16x16x32_bf16(afrag[3], set##q3, aQ, 0, 0, 0); \
        aV = __builtin_amdgcn_mfma_f32_16x16x32_bf16(afrag[3], set##v3, aV, 0, 0, 0); \
        int j = (tt) * 16 + m;                                                 \
        int jj = ((tt) - (t0)) * 16 + m;                                       \
        float bk = bp[j], bq = bp[D + j], bvs = bp[2 * D + j];                 \
        _Pragma("unroll")                                                      \
        for (int r = 0; r < 4; r++) {                                          \
            int row = w * 16 + quad * 4 + r;                                   \
            float kval = aK[r] + bk;                                           \
            float qval = aQ[r] + bq;                                           \
            float vval = aV[r] + bvs;                                          \
            float qpart = __shfl_xor(qval, 1);                                 \
            kvb[row * KV2STR + jj] = (unsigned int)f2bf(kval)                  \
                                   | ((unsigned int)f2bf(vval) << 16);         \
            if (!(lane & 1))                                                   \
                qtb[row * QT2STR + ((tt) - (t0)) * 8 + (m >> 1)] =             \
                    (unsigned int)f2bf(qval) | ((unsigned int)f2bf(qpart) << 16); \
        }                                                                      \
    }

    short8 Ak0, Ak1, Ak2, Ak3, Aq0, Aq1, Aq2, Aq3, Av0, Av1, Av2, Av3;
    short8 Bk0, Bk1, Bk2, Bk3, Bq0, Bq1, Bq2, Bq3, Bv0, Bv1, Bv2, Bv3;

#pragma unroll 1
    for (int ht = 0; ht < 2; ht++) {
        int t0 = ht * 4;
        LOADB(A, t0)
        LOADB(B, t0 + 1)
        COMPUTE(A, t0, t0)
        LOADB(A, t0 + 2)
        COMPUTE(B, t0 + 1, t0)
        LOADB(B, t0 + 3)
        COMPUTE(A, t0 + 2, t0)
        COMPUTE(B, t0 + 3, t0)
        // wave-private stores: this wave's 16 rows, this half's 64 kv cols
#pragma unroll
        for (int it = 0; it < 4; it++) {
            int idx = it * 64 + lane;
            int r = idx >> 4, c4 = (idx & 15) << 2;
            int n = row0 + w * 16 + r;
            if (n < N)
                *(uint4*)(kv + (size_t)n * D + t0 * 16 + c4) =
                    *(const uint4*)&kvb[(w * 16 + r) * KV2STR + c4];
        }
#pragma unroll
        for (int it = 0; it < 2; it++) {
            int idx = it * 64 + lane;
            int r = idx >> 3, c4 = (idx & 7) << 2;
            int n = row0 + w * 16 + r;
            if (n < N)
                *(uint4*)((unsigned int*)qt + (size_t)n * (D / 2) + t0 * 8 + c4) =
                    *(const uint4*)&qtb[(w * 16 + r) * QT2STR + c4];
        }
    }
#undef LOADB
#undef COMPUTE
}

// ---------------------------------------------------------------------------
// Histogram: src presence via plain byte store (benign race; deg only ever
// tested != 0), dst incidence via atomicAdd (CSR sizes need exact counts).
// ---------------------------------------------------------------------------
__global__ void deg_hist_kernel(const int* __restrict__ src, const int* __restrict__ dst,
                                unsigned char* __restrict__ sflag,
                                int* __restrict__ cnt_dst, int E)
{
    int e = blockIdx.x * blockDim.x + threadIdx.x;
    if (e >= E) return;
    sflag[src[e]] = 1;
    atomicAdd(&cnt_dst[dst[e]], 1);
}

// ---------------------------------------------------------------------------
__global__ __launch_bounds__(1024) void scan_blocks_kernel(
    const unsigned char* __restrict__ sflag, const int* __restrict__ cnt_dst,
    int* __restrict__ rowptr, int* __restrict__ deg,
    int* __restrict__ btot, int* __restrict__ zcount, int N)
{
    __shared__ int wtot[16];
    __shared__ int wscan[16];
    int tid = threadIdx.x, lane = tid & 63, wv = tid >> 6;
    int i = blockIdx.x * 1024 + tid;
    int cs = 0, cd = 0;
    if (i < N) { cs = sflag[i]; cd = cnt_dst[i]; }
    int x = cd;
#pragma unroll
    for (int off = 1; off < 64; off <<= 1) {
        int y = __shfl_up(x, off);
        if (lane >= off) x += y;
    }
    if (lane == 63) wtot[wv] = x;
    __syncthreads();
    if (wv == 0) {
        int t = (lane < 16) ? wtot[lane] : 0;
#pragma unroll
        for (int off = 1; off < 16; off <<= 1) {
            int y = __shfl_up(t, off);
            if (lane >= off) t += y;
        }
        if (lane < 16) wscan[lane] = t;
    }
    __syncthreads();
    int woff = (wv == 0) ? 0 : wscan[wv - 1];
    if (i < N) {
        rowptr[i] = woff + x - cd;
        deg[i] = (cs | (cd > 0)) ? 1 : 0;   // 0/1 indicator; only ever tested != 0
    }
    if (tid == 0) btot[blockIdx.x] = wscan[15];
    int zc = (i < N && cs == 0 && cd == 0) ? 1 : 0;
#pragma unroll
    for (int off = 1; off < 64; off <<= 1) zc += __shfl_xor(zc, off);
    if (lane == 0 && zc) atomicAdd(zcount, zc);
}

// ---------------------------------------------------------------------------
__global__ void scan_final_kernel(const int* __restrict__ btot,
                                  int* __restrict__ boff, int* __restrict__ rowptr,
                                  const int* __restrict__ zcount,
                                  const float* __restrict__ fsb,
                                  float* __restrict__ flags, int N, int nb)
{
    int lane = threadIdx.x;   // 64
    int v = (lane < nb) ? btot[lane] : 0;
    int x = v;
#pragma unroll
    for (int off = 1; off < 64; off <<= 1) {
        int y = __shfl_up(x, off);
        if (lane >= off) x += y;
    }
    if (lane < nb) boff[lane] = x - v;
    if (lane == 63) rowptr[N] = x;    // grand total = E
    if (lane == 0) {
        float z = (float)zcount[0];
        float sparsity = z / (float)N;
        flags[0] = (sparsity > 0.3f) ? fsb[0] : 0.f;
        flags[1] = fmaxf((float)N - z, 1.f);
    }
}

__global__ void scan_add_kernel(int* __restrict__ rowptr,
                                const int* __restrict__ boff, int N)
{
    int i = blockIdx.x * blockDim.x + threadIdx.x;
    if (i < N) rowptr[i] += boff[i >> 10];
}

// ---------------------------------------------------------------------------
__global__ void scatter_kernel(const int* __restrict__ src, const int* __restrict__ dst,
                               const int* __restrict__ rowptr, int* __restrict__ cursor,
                               int* __restrict__ esrc, int E)
{
    int e = blockIdx.x * blockDim.x + threadIdx.x;
    if (e >= E) return;
    int d = dst[e];
    int pos = rowptr[d] + atomicAdd(&cursor[d], 1);
    esrc[pos] = src[e];
}

// ---------------------------------------------------------------------------
// Fused softmax + aggregation, gather-based, ZERO atomics.
// One wave per dst node, 2 edges per wave (32 lanes/edge), uint4 gathers.
// ---------------------------------------------------------------------------
__global__ __launch_bounds__(256) void dst_agg_kernel(
    const unsigned int* __restrict__ kv, const unsigned short* __restrict__ qt,
    const float* __restrict__ h, const float* __restrict__ inv_norm,
    const int* __restrict__ rowptr, const int* __restrict__ esrc,
    const float* __restrict__ flags,
    unsigned int* __restrict__ agg, int N)
{
    int n = (blockIdx.x * blockDim.x + threadIdx.x) >> 6;
    int lane = threadIdx.x & 63;
    if (n >= N) return;
    int half = lane >> 5, c = lane & 31;
    int beg = rowptr[n], end = rowptr[n + 1];
    uint2 qw = *(const uint2*)(qt + (size_t)n * D + c * 4);
    float q0 = bf2f(qw.x), q1 = bf2f_hi(qw.x);
    float q2 = bf2f(qw.y), q3 = bf2f_hi(qw.y);
    float boost = flags[0];
    float hn0 = 0.f, hn1 = 0.f, hn2 = 0.f, hn3 = 0.f, innd = 0.f;
    if (boost != 0.f) {
        float4 hh = *(const float4*)(h + (size_t)n * D + c * 4);
        hn0 = hh.x; hn1 = hh.y; hn2 = hh.z; hn3 = hh.w; innd = inv_norm[n];
    }
    const float SC = 0.17677669529663687f;   // 1/sqrt(32)
    float a0 = 0.f, a1 = 0.f, a2 = 0.f, a3 = 0.f, den = 0.f;
    int i = beg;
    for (; i + 3 < end; i += 4) {
        int sA = esrc[i + half];
        int sB = esrc[i + 2 + half];
        uint4 wA = *(const uint4*)(kv + (size_t)sA * D + c * 4);
        uint4 wB = *(const uint4*)(kv + (size_t)sB * D + c * 4);
        float dA = q0 * bf2f(wA.x) + q1 * bf2f_hi(wA.x)
                 + q2 * bf2f(wA.y) + q3 * bf2f_hi(wA.y);
        dA = q0 * bf2f(wA.x) + q1 * bf2f(wA.y)
           + q2 * bf2f(wA.z) + q3 * bf2f(wA.w);
        float dB = q0 * bf2f(wB.x) + q1 * bf2f(wB.y)
                 + q2 * bf2f(wB.z) + q3 * bf2f(wB.w);
        dA += __shfl_xor(dA, 1);  dB += __shfl_xor(dB, 1);
        dA += __shfl_xor(dA, 2);  dB += __shfl_xor(dB, 2);
        dA += __shfl_xor(dA, 4);  dB += __shfl_xor(dB, 4);
        float attA = dA * SC, attB = dB * SC;
        if (boost != 0.f) {
            float4 xA = *(const float4*)(h + (size_t)sA * D + c * 4);
            float4 xB = *(const float4*)(h + (size_t)sB * D + c * 4);
            float fA = hn0 * xA.x + hn1 * xA.y + hn2 * xA.z + hn3 * xA.w;
            float fB = hn0 * xB.x + hn1 * xB.y + hn2 * xB.z + hn3 * xB.w;
#pragma unroll
            for (int off = 1; off < 32; off <<= 1) {
                fA += __shfl_xor(fA, off);
                fB += __shfl_xor(fB, off);
            }
            attA += fA * inv_norm[sA] * innd * boost;
            attB += fB * inv_norm[sB] * innd * boost;
        }
        attA = fminf(fmaxf(attA, -60.f), 60.f);
        attB = fminf(fmaxf(attB, -60.f), 60.f);
        float pA = __expf(attA), pB = __expf(attB);
        den += pA + pB;
        a0 += pA * bf2f_hi(wA.x) + pB * bf2f_hi(wB.x);
        a1 += pA * bf2f_hi(wA.y) + pB * bf2f_hi(wB.y);
        a2 += pA * bf2f_hi(wA.z) + pB * bf2f_hi(wB.z);
        a3 += pA * bf2f_hi(wA.w) + pB * bf2f_hi(wB.w);
    }
    for (; i + 1 < end; i += 2) {
        int sA = esrc[i + half];
        uint4 wA = *(const uint4*)(kv + (size_t)sA * D + c * 4);
        float dA = q0 * bf2f(wA.x) + q1 * bf2f(wA.y)
                 + q2 * bf2f(wA.z) + q3 * bf2f(wA.w);
        dA += __shfl_xor(dA, 1);
        dA += __shfl_xor(dA, 2);
        dA += __shfl_xor(dA, 4);
        float attA = dA * SC;
        if (boost != 0.f) {
            float4 xA = *(const float4*)(h + (size_t)sA * D + c * 4);
            float fA = hn0 * xA.x + hn1 * xA.y + hn2 * xA.z + hn3 * xA.w;
#pragma unroll
            for (int off = 1; off < 32; off <<= 1) fA += __shfl_xor(fA, off);
            attA += fA * inv_norm[sA] * innd * boost;
        }
        attA = fminf(fmaxf(attA, -60.f), 60.f);
        float pA = __expf(attA);
        den += pA;
        a0 += pA * bf2f_hi(wA.x);
        a1 += pA * bf2f_hi(wA.y);
        a2 += pA * bf2f_hi(wA.z);
        a3 += pA * bf2f_hi(wA.w);
    }
    if (i < end && half == 0) {
        int sA = esrc[i];
        uint4 wA = *(const uint4*)(kv + (size_t)sA * D + c * 4);
        float dA = q0 * bf2f(wA.x) + q1 * bf2f(wA.y)
                 + q2 * bf2f(wA.z) + q3 * bf2f(wA.w);
        dA += __shfl_xor(dA, 1);
        dA += __shfl_xor(dA, 2);
        dA += __shfl_xor(dA, 4);
        float attA = dA * SC;
        if (boost != 0.f) {
            float4 xA = *(const float4*)(h + (size_t)sA * D + c * 4);
            float fA = hn0 * xA.x + hn1 * xA.y + hn2 * xA.z + hn3 * xA.w;
#pragma unroll
            for (int off = 1; off < 32; off <<= 1) fA += __shfl_xor(fA, off);
            attA += fA * inv_norm[sA] * innd * boost;
        }
        attA = fminf(fmaxf(attA, -60.f), 60.f);
        float pA = __expf(attA);
        den += pA;
        a0 += pA * bf2f_hi(wA.x);
        a1 += pA * bf2f_hi(wA.y);
        a2 += pA * bf2f_hi(wA.z);
        a3 += pA * bf2f_hi(wA.w);
    }
    den += __shfl_xor(den, 32);
    a0  += __shfl_xor(a0, 32);
    a1  += __shfl_xor(a1, 32);
    a2  += __shfl_xor(a2, 32);
    a3  += __shfl_xor(a3, 32);
    if (half == 0) {
        float r = 1.0f / fmaxf(den, 1e-38f);
        uint2 o;
        o.x = (unsigned int)f2bf(a0 * r) | ((unsigned int)f2bf(a1 * r) << 16);
        o.y = (unsigned int)f2bf(a2 * r) | ((unsigned int)f2bf(a3 * r) << 16);
        *(uint2*)(agg + (size_t)n * (D / 2) + c * 2) = o;
    }
}

// ---------------------------------------------------------------------------
// out = LN(agg @ Wa + ba) via MFMA.  64 rows/block, 4 waves; pre-LN values
// stored as bf16 ALIASED over aB (same stride, wave-private rows -> legal
// without barrier).  LDS 17.4 KB -> 8 blocks/CU.
// ---------------------------------------------------------------------------
__global__ __launch_bounds__(256) void out_ln_kernel(
    const unsigned int* __restrict__ agg,      // packed bf16 pairs
    const unsigned short* __restrict__ WaT, const float* __restrict__ ba,
    const float* __restrict__ ln_g, const float* __restrict__ ln_b,
    const int* __restrict__ deg, float* __restrict__ out,
    float* __restrict__ gcpart, int N)
{
    __shared__ unsigned short aB[64 * ASTR];
    unsigned short* os = aB;   // alias: wave w reads/writes only rows w*16..+15
    int row0 = blockIdx.x * 64;
    int tid = threadIdx.x;
    for (int i = tid; i < 64 * 16; i += 256) {
        int r = i >> 4, c8 = (i & 15) << 3;
        int n = row0 + r;
        uint4 v = make_uint4(0u, 0u, 0u, 0u);
        if (n < N) v = *(const uint4*)(agg + (size_t)n * D / 2 + (c8 >> 1));
        *(uint4*)&aB[r * ASTR + c8] = v;
    }
    __syncthreads();
    int lane = tid & 63, w = tid >> 6;
    int m = lane & 15, quad = lane >> 4;

    short8 afrag[4];
    const unsigned short* ab = &aB[(w * 16 + m) * ASTR + quad * 8];
#pragma unroll
    for (int c = 0; c < 4; c++)
        afrag[c] = *(const short8*)(ab + c * 32);

    const unsigned short* wbase = WaT + (size_t)m * D + quad * 8;
    short8 A0, A1, A2, A3, B0, B1, B2, B3;
    A0 = *(const short8*)(wbase);
    A1 = *(const short8*)(wbase + 32);
    A2 = *(const short8*)(wbase + 64);
    A3 = *(const short8*)(wbase + 96);
#pragma unroll 1
    for (int t = 0; t < 8; t += 2) {
        const unsigned short* nb = wbase + (size_t)(t + 1) * 16 * D;
        B0 = *(const short8*)(nb);
        B1 = *(const short8*)(nb + 32);
        B2 = *(const short8*)(nb + 64);
        B3 = *(const short8*)(nb + 96);
        {
            floatx4 acc = (floatx4){0.f, 0.f, 0.f, 0.f};
            acc = __builtin_amdgcn_mfma_f32_16x16x32_bf16(afrag[0], A0, acc, 0, 0, 0);
            acc = __builtin_amdgcn_mfma_f32_16x16x32_bf16(afrag[1], A1, acc, 0, 0, 0);
            acc = __builtin_amdgcn_mfma_f32_16x16x32_bf16(afrag[2], A2, acc, 0, 0, 0);
            acc = __builtin_amdgcn_mfma_f32_16x16x32_bf16(afrag[3], A3, acc, 0, 0, 0);
            int j = t * 16 + m;
            float bj = ba[j];
#pragma unroll
            for (int r = 0; r < 4; r++)
                os[(w * 16 + quad * 4 + r) * ASTR + j] = f2bf(acc[r] + bj);
        }
        if (t + 2 < 8) {
            const unsigned short* na = wbase + (size_t)(t + 2) * 16 * D;
            A0 = *(const short8*)(na);
            A1 = *(const short8*)(na + 32);
            A2 = *(const short8*)(na + 64);
            A3 = *(const short8*)(na + 96);
        }
        {
            floatx4 acc = (floatx4){0.f, 0.f, 0.f, 0.f};
            acc = __builtin_amdgcn_mfma_f32_16x16x32_bf16(afrag[0], B0, acc, 0, 0, 0);
            acc = __builtin_amdgcn_mfma_f32_16x16x32_bf16(afrag[1], B1, acc, 0, 0, 0);
            acc = __builtin_amdgcn_mfma_f32_16x16x32_bf16(afrag[2], B2, acc, 0, 0, 0);
            acc = __builtin_amdgcn_mfma_f32_16x16x32_bf16(afrag[3], B3, acc, 0, 0, 0);
            int j = (t + 1) * 16 + m;
            float bj = ba[j];
#pragma unroll
            for (int r = 0; r < 4; r++)
                os[(w * 16 + quad * 4 + r) * ASTR + j] = f2bf(acc[r] + bj);
        }
    }
    int j2 = lane * 2;
    float g0 = ln_g[j2], g1 = ln_g[j2 + 1];
    float b0 = ln_b[j2], b1 = ln_b[j2 + 1];
    float gcs0 = 0.f, gcs1 = 0.f;
    for (int rr = 0; rr < 16; rr++) {
        int r = w * 16 + rr;
        int n = row0 + r;
        if (n >= N) break;
        unsigned int u = *(const unsigned int*)&os[r * ASTR + j2];
        float x0 = bf2f(u), x1 = bf2f_hi(u);
        float s = x0 + x1, s2 = x0 * x0 + x1 * x1;
#pragma unroll
        for (int off = 1; off < 64; off <<= 1) {
            s  += __shfl_xor(s, off);
            s2 += __shfl_xor(s2, off);
        }
        float mu = s * (1.f / 128.f);
        float var = s2 * (1.f / 128.f) - mu * mu;
        float rstd = rsqrtf(fmaxf(var, 0.f) + 1e-5f);
        float y0 = (x0 - mu) * rstd * g0 + b0;
        float y1 = (x1 - mu) * rstd * g1 + b1;
        *(float2*)(out + (size_t)n * D + j2) = make_float2(y0, y1);
        if (deg[n] != 0) { gcs0 += y0; gcs1 += y1; }
    }
    int slot = blockIdx.x & 63;
    if (gcs0 != 0.f || gcs1 != 0.f) {
        atomicAdd(&gcpart[slot * D + j2],     gcs0);
        atomicAdd(&gcpart[slot * D + j2 + 1], gcs1);
    }
}

__global__ void gc_final_kernel(const float* __restrict__ gcpart,
                                const float* __restrict__ flags,
                                float* __restrict__ gc)
{
    int j = threadIdx.x;  // 128
    float s = 0.f;
    for (int i = 0; i < 64; i++) s += gcpart[i * D + j];
    gc[j] = s / flags[1];
}

// ---------------------------------------------------------------------------
__global__ void fixup_kernel(const float* __restrict__ h,
                             const int* __restrict__ deg,
                             const float* __restrict__ gc,
                             float* __restrict__ out, int N)
{
    int n = blockIdx.x * blockDim.x + threadIdx.x;
    if (n >= N) return;
    if (deg[n] != 0) return;
    for (int j = 0; j < D; j += 4) {
        float4 hv = *(const float4*)(h + (size_t)n * D + j);
        float4 gv = *(const float4*)(gc + j);
        float4 o;
        o.x = 0.9f * hv.x + 0.1f * gv.x;
        o.y = 0.9f * hv.y + 0.1f * gv.y;
        o.z = 0.9f * hv.z + 0.1f * gv.z;
        o.w = 0.9f * hv.w + 0.1f * gv.w;
        *(float4*)(out + (size_t)n * D + j) = o;
    }
}

// ---------------------------------------------------------------------------
extern "C" void kernel_launch(void* const* d_in, const int* in_sizes, int n_in,
                              void* d_out, int out_size, void* d_ws, size_t ws_size,
                              hipStream_t stream)
{
    const float* h       = (const float*)d_in[0];
    const int* src_idx   = (const int*)d_in[1];
    const int* dst_idx   = (const int*)d_in[2];
    const float* Wk      = (const float*)d_in[3];
    const float* bk      = (const float*)d_in[4];
    const float* Wq      = (const float*)d_in[5];
    const float* bq      = (const float*)d_in[6];
    const float* Wv      = (const float*)d_in[7];
    const float* bv      = (const float*)d_in[8];
    const float* rk      = (const float*)d_in[9];
    const float* rq      = (const float*)d_in[10];
    const float* rv      = (const float*)d_in[11];
    const float* Wa      = (const float*)d_in[12];
    const float* ba      = (const float*)d_in[13];
    const float* ln_g    = (const float*)d_in[14];
    const float* ln_b    = (const float*)d_in[15];
    const float* fsb     = (const float*)d_in[16];
    float* out           = (float*)d_out;

    int N = in_sizes[0] / D;
    int E = in_sizes[1];
    int nb = (N + 1023) >> 10;   // scan blocks (<= 64)

    // ---- workspace: small control buffers first ---------------------------
    char* p = (char*)d_ws;
    auto alloc = [&](size_t bytes) { char* q = p; p += (bytes + 15) & ~(size_t)15; return q; };

    unsigned short* WpT = (unsigned short*)alloc(3 * D * D * 2);
    unsigned short* WaT = (unsigned short*)alloc(D * D * 2);
    float* bp       = (float*)alloc(3 * D * 4);
    float* gc       = (float*)alloc(D * 4);
    float* flags    = (float*)alloc(2 * 4);
    int*   btot     = (int*)alloc(64 * 4);
    int*   boff     = (int*)alloc(64 * 4);
    float* inv_norm = (float*)alloc((size_t)N * 4);
    int*   rowptr   = (int*)alloc(((size_t)N + 1) * 4);
    int*   deg      = (int*)alloc((size_t)N * 4);
    // zero region: sflag, cnt_dst, cursor, zcount, gcpart (contiguous)
    char* z1 = p;
    unsigned char* sflag = (unsigned char*)alloc((size_t)N);
    int*   cnt_dst = (int*)alloc((size_t)N * 4);
    int*   cursor  = (int*)alloc((size_t)N * 4);
    int*   zcount  = (int*)alloc(4);
    float* gcpart  = (float*)alloc(64 * D * 4);
    size_t z1_bytes = (size_t)(p - z1);
    // big arrays
    unsigned short* qt = (unsigned short*)alloc((size_t)N * D * 2);
    unsigned int*   kv = (unsigned int*)alloc((size_t)N * D * 4);
    int*   esrc        = (int*)alloc((size_t)E * 4);
    unsigned int* agg  = (unsigned int*)alloc((size_t)N * D * 2);

    hipMemsetAsync(z1, 0, z1_bytes, stream);

    prep_weights_kernel<<<dim3(129, 4), 128, 0, stream>>>(Wk, bk, Wq, bq, Wv, bv,
                                                          rk, rq, rv, Wa,
                                                          WpT, WaT, bp);
    gemm_mfma_kernel<<<(N + 63) / 64, 256, 0, stream>>>(h, WpT, bp, qt, kv,
                                                        inv_norm, N);
    deg_hist_kernel<<<(E + 255) / 256, 256, 0, stream>>>(src_idx, dst_idx,
                                                         sflag, cnt_dst, E);
    scan_blocks_kernel<<<nb, 1024, 0, stream>>>(sflag, cnt_dst, rowptr, deg,
                                                btot, zcount, N);
    scan_final_kernel<<<1, 64, 0, stream>>>(btot, boff, rowptr, zcount, fsb,
                                            flags, N, nb);
    scan_add_kernel<<<(N + 255) / 256, 256, 0, stream>>>(rowptr, boff, N);
    scatter_kernel<<<(E + 255) / 256, 256, 0, stream>>>(src_idx, dst_idx, rowptr,
                                                        cursor, esrc, E);
    dst_agg_kernel<<<(N + 3) / 4, 256, 0, stream>>>(kv, qt, h, inv_norm,
                                                    rowptr, esrc, flags, agg, N);
    out_ln_kernel<<<(N + 63) / 64, 256, 0, stream>>>(agg, WaT, ba, ln_g, ln_b,
                                                     deg, out, gcpart, N);
    gc_final_kernel<<<1, D, 0, stream>>>(gcpart, flags, gc);
    fixup_kernel<<<(N + 255) / 256, 256, 0, stream>>>(h, deg, gc, out, N);
}